// Round 1
// 616.012 us; speedup vs baseline: 1.2943x; 1.2943x over previous
//
#include <hip/hip_runtime.h>
#include <hip/hip_bf16.h>

typedef __attribute__((ext_vector_type(8))) short bf16x8;
typedef __attribute__((ext_vector_type(4))) float f32x4;

__device__ __forceinline__ unsigned short f2bf(float f) {
    unsigned u = __float_as_uint(f);
    return (unsigned short)((u + 0x7FFF + ((u >> 16) & 1)) >> 16);  // RNE
}
__device__ __forceinline__ unsigned pack2(float a, float b) {
    return (unsigned)f2bf(a) | ((unsigned)f2bf(b) << 16);
}

// ---------------------------------------------------------------------------
// Stage A: _x = x @ W_down + b_down    [N,256]@[256,64] -> [N,64]  (unchanged)
// ---------------------------------------------------------------------------
#define KD_NODES 8
__global__ __launch_bounds__(256) void k_down(
    const float* __restrict__ x, const float* __restrict__ Wd,
    const float* __restrict__ bd, float* __restrict__ xp, int N)
{
    __shared__ float xs[KD_NODES][256];
    __shared__ float4 Ws[64 * 64];
    int n0 = blockIdx.x * KD_NODES;
    int tid = threadIdx.x;

    for (int t = tid; t < KD_NODES * 256; t += 256) {
        int rr = t >> 8, kk = t & 255;
        int n = n0 + rr;
        xs[rr][kk] = (n < N) ? x[(size_t)n * 256 + kk] : 0.f;
    }
    for (int t = tid; t < 64 * 64; t += 256) {
        int pb = t >> 6, c = t & 63;
        float4 w;
        w.x = Wd[(4 * pb + 0) * 64 + c];
        w.y = Wd[(4 * pb + 1) * 64 + c];
        w.z = Wd[(4 * pb + 2) * 64 + c];
        w.w = Wd[(4 * pb + 3) * 64 + c];
        Ws[t] = w;
    }
    __syncthreads();

    int c = tid & 63;
    int r0 = (tid >> 6) * 2;
    float a0 = bd[c], a1 = a0;
    for (int pb = 0; pb < 64; pb++) {
        float4 w = Ws[pb * 64 + c];
        const float4 x0 = *(const float4*)&xs[r0][pb * 4];
        const float4 x1 = *(const float4*)&xs[r0 + 1][pb * 4];
        a0 += x0.x * w.x + x0.y * w.y + x0.z * w.z + x0.w * w.w;
        a1 += x1.x * w.x + x1.y * w.y + x1.z * w.z + x1.w * w.w;
    }
    int n = n0 + r0;
    if (n < N)     xp[(size_t)n * 64 + c]       = a0;
    if (n + 1 < N) xp[(size_t)(n + 1) * 64 + c] = a1;
}

// ---------------------------------------------------------------------------
// Stage B: CSR build + per-node gather (unchanged)
// ---------------------------------------------------------------------------
__global__ __launch_bounds__(256) void k_hist(
    const int* __restrict__ iidx, int* __restrict__ counts, int E)
{
    int e = blockIdx.x * 256 + threadIdx.x;
    if (e < E) atomicAdd(&counts[iidx[e]], 1);
}

__global__ __launch_bounds__(1024) void k_scan(
    const int* __restrict__ counts, int* __restrict__ rowptr,
    int* __restrict__ cursor, int N)
{
    __shared__ int part[1024];
    int t = threadIdx.x;
    int chunk = (N + 1023) / 1024;
    int beg = t * chunk;
    int end = min(beg + chunk, N);
    int s = 0;
    for (int i = beg; i < end; i++) s += counts[i];
    part[t] = s;
    __syncthreads();
    for (int off = 1; off < 1024; off <<= 1) {
        int v = (t >= off) ? part[t - off] : 0;
        __syncthreads();
        part[t] += v;
        __syncthreads();
    }
    int run = (t == 0) ? 0 : part[t - 1];
    for (int i = beg; i < end; i++) {
        rowptr[i] = run;
        cursor[i] = run;
        run += counts[i];
    }
    if (t == 1023) rowptr[N] = part[1023];
}

__global__ __launch_bounds__(256) void k_scatter_ids(
    const int* __restrict__ iidx, int* __restrict__ cursor,
    int* __restrict__ edge_id, int E)
{
    int e = blockIdx.x * 256 + threadIdx.x;
    if (e < E) {
        int pos = atomicAdd(&cursor[iidx[e]], 1);
        edge_id[pos] = e;
    }
}

__global__ __launch_bounds__(256) void k_gather(
    const float* __restrict__ xp, const float* __restrict__ rbf,
    const float* __restrict__ factor, const float* __restrict__ sph0,
    const float* __restrict__ sph1, const int* __restrict__ jidx,
    const int* __restrict__ rowptr, const int* __restrict__ edge_id,
    float* __restrict__ agg0, float* __restrict__ agg1,
    float* __restrict__ aggh, int N)
{
    int n = blockIdx.x * 4 + (threadIdx.x >> 6);
    if (n >= N) return;
    int p = threadIdx.x & 63;
    int beg = rowptr[n], end = rowptr[n + 1];

    float a0 = 0.f;
    float a1x = 0.f, a1y = 0.f, a1z = 0.f;
    float h0 = 0.f, h1 = 0.f, h2 = 0.f, h3 = 0.f, h4 = 0.f;

    int k = beg;
    for (; k + 3 < end; k += 4) {
        int e0 = edge_id[k], e1 = edge_id[k + 1];
        int e2 = edge_id[k + 2], e3 = edge_id[k + 3];
        int j0 = jidx[e0], j1 = jidx[e1], j2 = jidx[e2], j3 = jidx[e3];
        float f0 = factor[e0], f1 = factor[e1], f2 = factor[e2], f3 = factor[e3];
        float x0 = xp[(size_t)j0 * 64 + p], r0 = rbf[(size_t)e0 * 64 + p];
        float x1 = xp[(size_t)j1 * 64 + p], r1 = rbf[(size_t)e1 * 64 + p];
        float x2 = xp[(size_t)j2 * 64 + p], r2 = rbf[(size_t)e2 * 64 + p];
        float x3 = xp[(size_t)j3 * 64 + p], r3 = rbf[(size_t)e3 * 64 + p];
        float v0 = x0 * r0 * f0, v1 = x1 * r1 * f1;
        float v2 = x2 * r2 * f2, v3 = x3 * r3 * f3;
        a0 += (v0 + v1) + (v2 + v3);
        a1x += v0 * sph1[e0 * 3 + 0] + v1 * sph1[e1 * 3 + 0]
             + v2 * sph1[e2 * 3 + 0] + v3 * sph1[e3 * 3 + 0];
        a1y += v0 * sph1[e0 * 3 + 1] + v1 * sph1[e1 * 3 + 1]
             + v2 * sph1[e2 * 3 + 1] + v3 * sph1[e3 * 3 + 1];
        a1z += v0 * sph1[e0 * 3 + 2] + v1 * sph1[e1 * 3 + 2]
             + v2 * sph1[e2 * 3 + 2] + v3 * sph1[e3 * 3 + 2];
        h0  += v0 * sph0[e0 * 5 + 0] + v1 * sph0[e1 * 5 + 0]
             + v2 * sph0[e2 * 5 + 0] + v3 * sph0[e3 * 5 + 0];
        h1  += v0 * sph0[e0 * 5 + 1] + v1 * sph0[e1 * 5 + 1]
             + v2 * sph0[e2 * 5 + 1] + v3 * sph0[e3 * 5 + 1];
        h2  += v0 * sph0[e0 * 5 + 2] + v1 * sph0[e1 * 5 + 2]
             + v2 * sph0[e2 * 5 + 2] + v3 * sph0[e3 * 5 + 2];
        h3  += v0 * sph0[e0 * 5 + 3] + v1 * sph0[e1 * 5 + 3]
             + v2 * sph0[e2 * 5 + 3] + v3 * sph0[e3 * 5 + 3];
        h4  += v0 * sph0[e0 * 5 + 4] + v1 * sph0[e1 * 5 + 4]
             + v2 * sph0[e2 * 5 + 4] + v3 * sph0[e3 * 5 + 4];
    }
    for (; k < end; k++) {
        int e0 = edge_id[k];
        int j0 = jidx[e0];
        float f0 = factor[e0];
        float v0 = xp[(size_t)j0 * 64 + p] * rbf[(size_t)e0 * 64 + p] * f0;
        a0 += v0;
        a1x += v0 * sph1[e0 * 3 + 0];
        a1y += v0 * sph1[e0 * 3 + 1];
        a1z += v0 * sph1[e0 * 3 + 2];
        h0  += v0 * sph0[e0 * 5 + 0];
        h1  += v0 * sph0[e0 * 5 + 1];
        h2  += v0 * sph0[e0 * 5 + 2];
        h3  += v0 * sph0[e0 * 5 + 3];
        h4  += v0 * sph0[e0 * 5 + 4];
    }

    agg0[(size_t)n * 64 + p] = a0;
    agg1[((size_t)n * 3 + 0) * 64 + p] = a1x;
    agg1[((size_t)n * 3 + 1) * 64 + p] = a1y;
    agg1[((size_t)n * 3 + 2) * 64 + p] = a1z;
    aggh[((size_t)n * 5 + 0) * 64 + p] = h0;
    aggh[((size_t)n * 5 + 1) * 64 + p] = h1;
    aggh[((size_t)n * 5 + 2) * 64 + p] = h2;
    aggh[((size_t)n * 5 + 3) * 64 + p] = h3;
    aggh[((size_t)n * 5 + 4) * 64 + p] = h4;
}

// ---------------------------------------------------------------------------
// Pre-swizzle Wn1/Wn2 (f32, row-major [K][256]) into bf16 MFMA B-fragment
// order (unchanged, used by k_final).
// ---------------------------------------------------------------------------
__global__ __launch_bounds__(256) void k_swz(
    const float* __restrict__ W, unsigned short* __restrict__ Bsw, int K)
{
    int idx = blockIdx.x * 256 + threadIdx.x;
    int total = (K >> 5) * 1024;            // (K/32) * 16 ct * 64 lanes
    if (idx >= total) return;
    int lane = idx & 63;
    int ct = (idx >> 6) & 15;
    int ks = idx >> 10;
    int col = ct * 16 + (lane & 15);
    int kbase = (ks << 5) + ((lane >> 4) << 3);
    const float* p = &W[(size_t)kbase * 256 + col];
    uint4 o;
    o.x = pack2(p[0 * 256], p[1 * 256]);
    o.y = pack2(p[2 * 256], p[3 * 256]);
    o.z = pack2(p[4 * 256], p[5 * 256]);
    o.w = pack2(p[6 * 256], p[7 * 256]);
    *(uint4*)&Bsw[(size_t)idx * 8] = o;
}

// ---------------------------------------------------------------------------
// R6: generalized split swizzle for the up-projection weights [K][C] ->
// hi/lo bf16 B-fragments (hi = bf16(w), lo = bf16(w - hi)). Same fragment
// layout as k_swz: B[(ks*(C/16)+ct)*64+lane][j] = W[ks*32+(lane>>4)*8+j][ct*16+(lane&15)].
// ---------------------------------------------------------------------------
__global__ __launch_bounds__(256) void k_swz_split(
    const float* __restrict__ W, unsigned short* __restrict__ Bh,
    unsigned short* __restrict__ Bl, int K, int C)
{
    int idx = blockIdx.x * 256 + threadIdx.x;
    int ct_n = C >> 4;
    int total = (K >> 5) * ct_n * 64;
    if (idx >= total) return;
    int per_ks = ct_n * 64;
    int ks = idx / per_ks;
    int rem = idx - ks * per_ks;
    int ct = rem >> 6;
    int lane = rem & 63;
    int col = ct * 16 + (lane & 15);
    int kbase = (ks << 5) + ((lane >> 4) << 3);
    const float* p = &W[(size_t)kbase * C + col];
    unsigned short hs[8], ls[8];
#pragma unroll
    for (int j = 0; j < 8; j++) {
        float wv = p[(size_t)j * C];
        unsigned short h = f2bf(wv);
        float fh = __uint_as_float((unsigned)h << 16);
        hs[j] = h;
        ls[j] = f2bf(wv - fh);
    }
    uint4 oh, ol;
    oh.x = (unsigned)hs[0] | ((unsigned)hs[1] << 16);
    oh.y = (unsigned)hs[2] | ((unsigned)hs[3] << 16);
    oh.z = (unsigned)hs[4] | ((unsigned)hs[5] << 16);
    oh.w = (unsigned)hs[6] | ((unsigned)hs[7] << 16);
    ol.x = (unsigned)ls[0] | ((unsigned)ls[1] << 16);
    ol.y = (unsigned)ls[2] | ((unsigned)ls[3] << 16);
    ol.z = (unsigned)ls[4] | ((unsigned)ls[5] << 16);
    ol.w = (unsigned)ls[6] | ((unsigned)ls[7] << 16);
    *(uint4*)&Bh[(size_t)idx * 8] = oh;
    *(uint4*)&Bl[(size_t)idx * 8] = ol;
}

// ---------------------------------------------------------------------------
// Stage C1 (R6 rewrite): node features via MFMA with hi/lo bf16 split
// (fp32-equivalent accuracy: a*b ~= ah*bh + ah*bl + al*bh, al*bl ~ 2^-16).
// 16 nodes/block, 4 waves; wave w owns output cols [w*32, w*32+32).
// 9 A-tiles [16][64] (a0, 3x a1, 5x ah) staged hi/lo in LDS with +8 pad
// (2-way bank aliasing = free, m136). B-frags read directly from the
// L2-resident pre-split-swizzled weights.
// LDS 45.5 KB -> 3 blocks/CU (12 waves/CU).
// ---------------------------------------------------------------------------
__global__ __launch_bounds__(256, 3) void k_node(
    const float* __restrict__ xp, const float* __restrict__ agg0,
    const float* __restrict__ agg1, const float* __restrict__ aggh,
    const unsigned short* __restrict__ Wu0h, const unsigned short* __restrict__ Wu0l,
    const unsigned short* __restrict__ Wu1h, const unsigned short* __restrict__ Wu1l,
    const unsigned short* __restrict__ Wuhh, const unsigned short* __restrict__ Wuhl,
    const float* __restrict__ bu0, float* __restrict__ node, int N)
{
    __shared__ float xs[16 * 64];
    __shared__ __align__(16) unsigned short Ahi[9 * 16 * 72];
    __shared__ __align__(16) unsigned short Alo[9 * 16 * 72];

    int n0 = blockIdx.x * 16;
    int tid = threadIdx.x;
    int lane = tid & 63;
    int w = tid >> 6;          // wave -> col group
    int lcol = lane & 15;
    int quad = lane >> 4;
    int kq = quad * 8;

    // stage xp tile
    for (int t = tid; t < 16 * 64; t += 256) {
        int n = n0 + (t >> 6);
        xs[t] = (n < N) ? xp[(size_t)n * 64 + (t & 63)] : 0.f;
    }
    __syncthreads();

    // build 9 hi/lo A-tiles: m=0: xs*agg0; m=1..3: xs*agg1[c]; m=4..8: xs*aggh[c]
    for (int t = tid; t < 9 * 1024; t += 256) {
        int m = t >> 10;               // uniform per 256-thread iteration
        int rem = t & 1023;
        int r = rem >> 6, c = rem & 63;
        int n = n0 + r;
        float v = 0.f;
        if (n < N) {
            float xv = xs[rem];
            if (m == 0)      v = xv * agg0[(size_t)n * 64 + c];
            else if (m < 4)  v = xv * agg1[((size_t)n * 3 + (m - 1)) * 64 + c];
            else             v = xv * aggh[((size_t)n * 5 + (m - 4)) * 64 + c];
        }
        unsigned short h = f2bf(v);
        float fh = __uint_as_float((unsigned)h << 16);
        Ahi[(m * 16 + r) * 72 + c] = h;
        Alo[(m * 16 + r) * 72 + c] = f2bf(v - fh);
    }
    __syncthreads();

    // ---- G0: l0 = a0 @ Wu0 + bu0 ----
    {
        bf16x8 bh[2][2], bl[2][2];
#pragma unroll
        for (int ks = 0; ks < 2; ks++)
#pragma unroll
            for (int t = 0; t < 2; t++) {
                size_t bi = ((size_t)((ks * 8 + w * 2 + t) * 64 + lane)) * 8;
                bh[ks][t] = *(const bf16x8*)&Wu0h[bi];
                bl[ks][t] = *(const bf16x8*)&Wu0l[bi];
            }
        f32x4 acc[2];
        acc[0] = (f32x4){0.f, 0.f, 0.f, 0.f};
        acc[1] = (f32x4){0.f, 0.f, 0.f, 0.f};
#pragma unroll
        for (int ks = 0; ks < 2; ks++) {
            bf16x8 ah = *(const bf16x8*)&Ahi[lcol * 72 + ks * 32 + kq];
            bf16x8 al = *(const bf16x8*)&Alo[lcol * 72 + ks * 32 + kq];
#pragma unroll
            for (int t = 0; t < 2; t++) {
                acc[t] = __builtin_amdgcn_mfma_f32_16x16x32_bf16(ah, bh[ks][t], acc[t], 0, 0, 0);
                acc[t] = __builtin_amdgcn_mfma_f32_16x16x32_bf16(ah, bl[ks][t], acc[t], 0, 0, 0);
                acc[t] = __builtin_amdgcn_mfma_f32_16x16x32_bf16(al, bh[ks][t], acc[t], 0, 0, 0);
            }
        }
#pragma unroll
        for (int t = 0; t < 2; t++) {
            int col = w * 32 + t * 16 + lcol;
            float bb = bu0[col];
#pragma unroll
            for (int q = 0; q < 4; q++) {
                int n = n0 + quad * 4 + q;
                if (n < N) node[(size_t)n * 384 + col] = acc[t][q] + bb;
            }
        }
    }

    // ---- G1: l1 = sum_c ((a1_c @ Wu1))^2 ----
    {
        bf16x8 bh[2][2], bl[2][2];
#pragma unroll
        for (int ks = 0; ks < 2; ks++)
#pragma unroll
            for (int t = 0; t < 2; t++) {
                size_t bi = ((size_t)((ks * 8 + w * 2 + t) * 64 + lane)) * 8;
                bh[ks][t] = *(const bf16x8*)&Wu1h[bi];
                bl[ks][t] = *(const bf16x8*)&Wu1l[bi];
            }
        f32x4 S[2];
        S[0] = (f32x4){0.f, 0.f, 0.f, 0.f};
        S[1] = (f32x4){0.f, 0.f, 0.f, 0.f};
#pragma unroll
        for (int c = 0; c < 3; c++) {
            f32x4 d[2];
            d[0] = (f32x4){0.f, 0.f, 0.f, 0.f};
            d[1] = (f32x4){0.f, 0.f, 0.f, 0.f};
            int abase = (1 + c) * (16 * 72);
#pragma unroll
            for (int ks = 0; ks < 2; ks++) {
                bf16x8 ah = *(const bf16x8*)&Ahi[abase + lcol * 72 + ks * 32 + kq];
                bf16x8 al = *(const bf16x8*)&Alo[abase + lcol * 72 + ks * 32 + kq];
#pragma unroll
                for (int t = 0; t < 2; t++) {
                    d[t] = __builtin_amdgcn_mfma_f32_16x16x32_bf16(ah, bh[ks][t], d[t], 0, 0, 0);
                    d[t] = __builtin_amdgcn_mfma_f32_16x16x32_bf16(ah, bl[ks][t], d[t], 0, 0, 0);
                    d[t] = __builtin_amdgcn_mfma_f32_16x16x32_bf16(al, bh[ks][t], d[t], 0, 0, 0);
                }
            }
            S[0] += d[0] * d[0];
            S[1] += d[1] * d[1];
        }
#pragma unroll
        for (int t = 0; t < 2; t++) {
            int col = w * 32 + t * 16 + lcol;
#pragma unroll
            for (int q = 0; q < 4; q++) {
                int n = n0 + quad * 4 + q;
                if (n < N) node[(size_t)n * 384 + 128 + col] = S[t][q];
            }
        }
    }

    // ---- G2: lh = sum_c ((ah_c @ Wuh))^2 ----
    {
        bf16x8 bh[2][2], bl[2][2];
#pragma unroll
        for (int ks = 0; ks < 2; ks++)
#pragma unroll
            for (int t = 0; t < 2; t++) {
                size_t bi = ((size_t)((ks * 8 + w * 2 + t) * 64 + lane)) * 8;
                bh[ks][t] = *(const bf16x8*)&Wuhh[bi];
                bl[ks][t] = *(const bf16x8*)&Wuhl[bi];
            }
        f32x4 S[2];
        S[0] = (f32x4){0.f, 0.f, 0.f, 0.f};
        S[1] = (f32x4){0.f, 0.f, 0.f, 0.f};
#pragma unroll
        for (int c = 0; c < 5; c++) {
            f32x4 d[2];
            d[0] = (f32x4){0.f, 0.f, 0.f, 0.f};
            d[1] = (f32x4){0.f, 0.f, 0.f, 0.f};
            int abase = (4 + c) * (16 * 72);
#pragma unroll
            for (int ks = 0; ks < 2; ks++) {
                bf16x8 ah = *(const bf16x8*)&Ahi[abase + lcol * 72 + ks * 32 + kq];
                bf16x8 al = *(const bf16x8*)&Alo[abase + lcol * 72 + ks * 32 + kq];
#pragma unroll
                for (int t = 0; t < 2; t++) {
                    d[t] = __builtin_amdgcn_mfma_f32_16x16x32_bf16(ah, bh[ks][t], d[t], 0, 0, 0);
                    d[t] = __builtin_amdgcn_mfma_f32_16x16x32_bf16(ah, bl[ks][t], d[t], 0, 0, 0);
                    d[t] = __builtin_amdgcn_mfma_f32_16x16x32_bf16(al, bh[ks][t], d[t], 0, 0, 0);
                }
            }
            S[0] += d[0] * d[0];
            S[1] += d[1] * d[1];
        }
#pragma unroll
        for (int t = 0; t < 2; t++) {
            int col = w * 32 + t * 16 + lcol;
#pragma unroll
            for (int q = 0; q < 4; q++) {
                int n = n0 + quad * 4 + q;
                if (n < N) node[(size_t)n * 384 + 256 + col] = S[t][q];
            }
        }
    }
}

// ---------------------------------------------------------------------------
// Stage C2: bf16 MFMA fused GEMM1+LN+SiLU+GEMM2 (unchanged, proven)
// ---------------------------------------------------------------------------
__global__ __launch_bounds__(256, 4) void k_final(
    const float* __restrict__ node, const unsigned short* __restrict__ Bsw1,
    const float* __restrict__ bn1, const float* __restrict__ lng,
    const float* __restrict__ lnb, const unsigned short* __restrict__ Bsw2,
    const float* __restrict__ bn2, const float* __restrict__ x,
    float* __restrict__ out, int N)
{
    __shared__ unsigned short Abf[32 * 392];   // GEMM1 A [32][384+8]; reused as GEMM2 A [32][256+8]
    __shared__ float red[32][33];
    __shared__ float red2[32][33];
    __shared__ float mstat[32][2];

    int n0 = blockIdx.x * 32;
    int tid = threadIdx.x;
    int lane = tid & 63;
    int w = tid >> 6;
    int rt = w & 1;
    int cg = w >> 1;
    int lcol = lane & 15;
    int quad = lane >> 4;
    int arow = rt * 16 + lcol;       // A-frag row this lane reads
    int kq = quad * 8;               // A/B-frag k sub-offset

    // ---- stage node tile as bf16 -> Abf[32][392] ----
    for (int i = tid; i < 32 * 192; i += 256) {
        int r = i / 192, c2 = i - r * 192;
        int n = n0 + r;
        float2 v;
        if (n < N) v = *(const float2*)&node[(size_t)n * 384 + 2 * c2];
        else { v.x = 0.f; v.y = 0.f; }
        *(unsigned*)&Abf[r * 392 + 2 * c2] = pack2(v.x, v.y);
    }
    __syncthreads();

    // ---- GEMM1: T = node @ Wn1 ----
    f32x4 acc[8];
#pragma unroll
    for (int t = 0; t < 8; t++) acc[t] = (f32x4){0.f, 0.f, 0.f, 0.f};
    for (int ks = 0; ks < 12; ks++) {
        bf16x8 a = *(const bf16x8*)&Abf[arow * 392 + ks * 32 + kq];
        const bf16x8* bp =
            (const bf16x8*)&Bsw1[(size_t)(((ks * 16 + cg * 8) * 64) + lane) * 8];
#pragma unroll
        for (int t = 0; t < 8; t++)
            acc[t] = __builtin_amdgcn_mfma_f32_16x16x32_bf16(a, bp[t * 64], acc[t], 0, 0, 0);
    }

    // ---- per-row LN stats from accumulators (D layout: row=rt*16+quad*4+q, col=ct*16+lcol)
    float bias[8];
#pragma unroll
    for (int t = 0; t < 8; t++) bias[t] = bn1[cg * 128 + t * 16 + lcol];
#pragma unroll
    for (int q = 0; q < 4; q++) {
        float s = 0.f, s2 = 0.f;
#pragma unroll
        for (int t = 0; t < 8; t++) {
            float v = acc[t][q] + bias[t];
            s += v; s2 += v * v;
        }
        int row = rt * 16 + quad * 4 + q;
        red[row][cg * 16 + lcol] = s;
        red2[row][cg * 16 + lcol] = s2;
    }
    __syncthreads();
    if (tid < 32) {
        float s = 0.f, s2 = 0.f;
#pragma unroll
        for (int u = 0; u < 32; u++) { s += red[tid][u]; s2 += red2[tid][u]; }
        float m = s * (1.f / 256.f);
        float var = s2 * (1.f / 256.f) - m * m;
        mstat[tid][0] = m;
        mstat[tid][1] = rsqrtf(var + 1e-5f);
    }
    __syncthreads();

    // ---- LN + SiLU, write h as bf16 GEMM2 A-tile [32][264] ----
#pragma unroll
    for (int t = 0; t < 8; t++) {
        int col = cg * 128 + t * 16 + lcol;
        float gg = lng[col], bb = lnb[col];
#pragma unroll
        for (int q = 0; q < 4; q++) {
            int row = rt * 16 + quad * 4 + q;
            float z = (acc[t][q] + bias[t] - mstat[row][0]) * mstat[row][1] * gg + bb;
            float h = z / (1.f + __expf(-z));
            Abf[row * 264 + col] = f2bf(h);
        }
    }
    __syncthreads();

    // ---- GEMM2: out = h @ Wn2 + bn2 + x ----
    f32x4 o[8];
#pragma unroll
    for (int t = 0; t < 8; t++) o[t] = (f32x4){0.f, 0.f, 0.f, 0.f};
    for (int ks = 0; ks < 8; ks++) {
        bf16x8 a = *(const bf16x8*)&Abf[arow * 264 + ks * 32 + kq];
        const bf16x8* bp =
            (const bf16x8*)&Bsw2[(size_t)(((ks * 16 + cg * 8) * 64) + lane) * 8];
#pragma unroll
        for (int t = 0; t < 8; t++)
            o[t] = __builtin_amdgcn_mfma_f32_16x16x32_bf16(a, bp[t * 64], o[t], 0, 0, 0);
    }
#pragma unroll
    for (int t = 0; t < 8; t++) {
        int col = cg * 128 + t * 16 + lcol;
        float ob = bn2[col];
#pragma unroll
        for (int q = 0; q < 4; q++) {
            int row = rt * 16 + quad * 4 + q;
            int n = n0 + row;
            if (n < N)
                out[(size_t)n * 256 + col] = o[t][q] + ob + x[(size_t)n * 256 + col];
        }
    }
}

// ---------------------------------------------------------------------------
extern "C" void kernel_launch(void* const* d_in, const int* in_sizes, int n_in,
                              void* d_out, int out_size, void* d_ws, size_t ws_size,
                              hipStream_t stream)
{
    const float* x      = (const float*)d_in[0];
    const float* rbf    = (const float*)d_in[1];
    const float* factor = (const float*)d_in[2];
    const float* sph0   = (const float*)d_in[3];
    const float* sph1   = (const float*)d_in[4];
    const float* Wd     = (const float*)d_in[5];
    const float* bd     = (const float*)d_in[6];
    const float* Wu0    = (const float*)d_in[7];
    const float* bu0    = (const float*)d_in[8];
    const float* Wu1    = (const float*)d_in[9];
    const float* Wuh    = (const float*)d_in[10];
    const float* Wn1    = (const float*)d_in[11];
    const float* bn1    = (const float*)d_in[12];
    const float* lng    = (const float*)d_in[13];
    const float* lnb    = (const float*)d_in[14];
    const float* Wn2    = (const float*)d_in[15];
    const float* bn2    = (const float*)d_in[16];
    const int*   jidx   = (const int*)d_in[17];
    const int*   iidx   = (const int*)d_in[18];
    float* out = (float*)d_out;

    int N = in_sizes[0] / 256;
    int E = in_sizes[17];

    float* ws   = (float*)d_ws;
    float* xp   = ws;                        // [N,64]
    float* agg0 = xp   + (size_t)N * 64;     // [N,64]
    float* agg1 = agg0 + (size_t)N * 64;     // [N,3,64]
    float* aggh = agg1 + (size_t)N * 192;    // [N,5,64]
    float* node = aggh + (size_t)N * 320;    // [N,384]
    // swizzled bf16 weights after node (one-time conversion per launch)
    unsigned short* Bsw1 = (unsigned short*)(node + (size_t)N * 384); // 12*16*64*8
    unsigned short* Bsw2 = Bsw1 + 12 * 16 * 64 * 8;                    // 8*16*64*8
    // R6: hi/lo split-swizzled up-projection weights (each 64*128)
    unsigned short* Wu0h_s = Bsw2 + 8 * 16 * 64 * 8;
    unsigned short* Wu0l_s = Wu0h_s + 64 * 128;
    unsigned short* Wu1h_s = Wu0l_s + 64 * 128;
    unsigned short* Wu1l_s = Wu1h_s + 64 * 128;
    unsigned short* Wuhh_s = Wu1l_s + 64 * 128;
    unsigned short* Wuhl_s = Wuhh_s + 64 * 128;

    // CSR scratch aliased onto the node buffer (dead before k_node writes it).
    int* counts  = (int*)node;               // [N]
    int* rowptr  = counts + (N + 1);         // [N+1]
    int* cursor  = rowptr + (N + 1);         // [N]
    int* edge_id = cursor + (N + 1);         // [E]

    hipMemsetAsync(counts, 0, (size_t)(N + 1) * sizeof(int), stream);

    k_swz<<<dim3(48), dim3(256), 0, stream>>>(Wn1, Bsw1, 384);
    k_swz<<<dim3(32), dim3(256), 0, stream>>>(Wn2, Bsw2, 256);
    k_swz_split<<<dim3(4), dim3(256), 0, stream>>>(Wu0, Wu0h_s, Wu0l_s, 64, 128);
    k_swz_split<<<dim3(4), dim3(256), 0, stream>>>(Wu1, Wu1h_s, Wu1l_s, 64, 128);
    k_swz_split<<<dim3(4), dim3(256), 0, stream>>>(Wuh, Wuhh_s, Wuhl_s, 64, 128);
    k_down<<<dim3((N + KD_NODES - 1) / KD_NODES), dim3(256), 0, stream>>>(
        x, Wd, bd, xp, N);
    k_hist<<<dim3((E + 255) / 256), dim3(256), 0, stream>>>(iidx, counts, E);
    k_scan<<<dim3(1), dim3(1024), 0, stream>>>(counts, rowptr, cursor, N);
    k_scatter_ids<<<dim3((E + 255) / 256), dim3(256), 0, stream>>>(
        iidx, cursor, edge_id, E);
    k_gather<<<dim3((N + 3) / 4), dim3(256), 0, stream>>>(
        xp, rbf, factor, sph0, sph1, jidx, rowptr, edge_id,
        agg0, agg1, aggh, N);
    k_node<<<dim3((N + 15) / 16), dim3(256), 0, stream>>>(
        xp, agg0, agg1, aggh, Wu0h_s, Wu0l_s, Wu1h_s, Wu1l_s, Wuhh_s, Wuhl_s,
        bu0, node, N);
    k_final<<<dim3((N + 31) / 32), dim3(256), 0, stream>>>(
        node, Bsw1, bn1, lng, lnb, Bsw2, bn2, x, out, N);
}

// Round 2
// 570.095 us; speedup vs baseline: 1.3985x; 1.0805x over previous
//
#include <hip/hip_runtime.h>
#include <hip/hip_bf16.h>

typedef __attribute__((ext_vector_type(8))) short bf16x8;
typedef __attribute__((ext_vector_type(4))) float f32x4;

__device__ __forceinline__ unsigned short f2bf(float f) {
    unsigned u = __float_as_uint(f);
    return (unsigned short)((u + 0x7FFF + ((u >> 16) & 1)) >> 16);  // RNE
}
__device__ __forceinline__ unsigned pack2(float a, float b) {
    return (unsigned)f2bf(a) | ((unsigned)f2bf(b) << 16);
}
// register broadcast: lane k (uniform) -> all lanes, result in SGPR
__device__ __forceinline__ int RLi(float v, int k) {
    return __builtin_amdgcn_readlane(__float_as_int(v), k);
}
__device__ __forceinline__ float RLf(float v, int k) {
    return __uint_as_float((unsigned)__builtin_amdgcn_readlane(__float_as_int(v), k));
}

// ---------------------------------------------------------------------------
// Stage A: _x = x @ W_down + b_down    [N,256]@[256,64] -> [N,64]  (unchanged)
// ---------------------------------------------------------------------------
#define KD_NODES 8
__global__ __launch_bounds__(256) void k_down(
    const float* __restrict__ x, const float* __restrict__ Wd,
    const float* __restrict__ bd, float* __restrict__ xp, int N)
{
    __shared__ float xs[KD_NODES][256];
    __shared__ float4 Ws[64 * 64];
    int n0 = blockIdx.x * KD_NODES;
    int tid = threadIdx.x;

    for (int t = tid; t < KD_NODES * 256; t += 256) {
        int rr = t >> 8, kk = t & 255;
        int n = n0 + rr;
        xs[rr][kk] = (n < N) ? x[(size_t)n * 256 + kk] : 0.f;
    }
    for (int t = tid; t < 64 * 64; t += 256) {
        int pb = t >> 6, c = t & 63;
        float4 w;
        w.x = Wd[(4 * pb + 0) * 64 + c];
        w.y = Wd[(4 * pb + 1) * 64 + c];
        w.z = Wd[(4 * pb + 2) * 64 + c];
        w.w = Wd[(4 * pb + 3) * 64 + c];
        Ws[t] = w;
    }
    __syncthreads();

    int c = tid & 63;
    int r0 = (tid >> 6) * 2;
    float a0 = bd[c], a1 = a0;
    for (int pb = 0; pb < 64; pb++) {
        float4 w = Ws[pb * 64 + c];
        const float4 x0 = *(const float4*)&xs[r0][pb * 4];
        const float4 x1 = *(const float4*)&xs[r0 + 1][pb * 4];
        a0 += x0.x * w.x + x0.y * w.y + x0.z * w.z + x0.w * w.w;
        a1 += x1.x * w.x + x1.y * w.y + x1.z * w.z + x1.w * w.w;
    }
    int n = n0 + r0;
    if (n < N)     xp[(size_t)n * 64 + c]       = a0;
    if (n + 1 < N) xp[(size_t)(n + 1) * 64 + c] = a1;
}

// ---------------------------------------------------------------------------
// Stage B: CSR build. R7: scatter also packs per-edge record into CSR order:
// 12 floats/edge {e, j, factor, s1x, s1y, s1z, h0..h4, pad} so k_gather does
// coalesced float4 staging + readlane broadcast instead of 44 broadcast VMEM
// loads per 4 edges.
// ---------------------------------------------------------------------------
__global__ __launch_bounds__(256) void k_hist(
    const int* __restrict__ iidx, int* __restrict__ counts, int E)
{
    int e = blockIdx.x * 256 + threadIdx.x;
    if (e < E) atomicAdd(&counts[iidx[e]], 1);
}

__global__ __launch_bounds__(1024) void k_scan(
    const int* __restrict__ counts, int* __restrict__ rowptr,
    int* __restrict__ cursor, int N)
{
    __shared__ int part[1024];
    int t = threadIdx.x;
    int chunk = (N + 1023) / 1024;
    int beg = t * chunk;
    int end = min(beg + chunk, N);
    int s = 0;
    for (int i = beg; i < end; i++) s += counts[i];
    part[t] = s;
    __syncthreads();
    for (int off = 1; off < 1024; off <<= 1) {
        int v = (t >= off) ? part[t - off] : 0;
        __syncthreads();
        part[t] += v;
        __syncthreads();
    }
    int run = (t == 0) ? 0 : part[t - 1];
    for (int i = beg; i < end; i++) {
        rowptr[i] = run;
        cursor[i] = run;
        run += counts[i];
    }
    if (t == 1023) rowptr[N] = part[1023];
}

__global__ __launch_bounds__(256) void k_scatter_pack(
    const int* __restrict__ iidx, const int* __restrict__ jidx,
    const float* __restrict__ factor, const float* __restrict__ sph0,
    const float* __restrict__ sph1, int* __restrict__ cursor,
    float* __restrict__ packed, int E)
{
    int e = blockIdx.x * 256 + threadIdx.x;
    if (e >= E) return;
    int pos = atomicAdd(&cursor[iidx[e]], 1);
    float4 w0, w1, w2;
    w0.x = __int_as_float(e);
    w0.y = __int_as_float(jidx[e]);
    w0.z = factor[e];
    w0.w = sph1[e * 3 + 0];
    w1.x = sph1[e * 3 + 1];
    w1.y = sph1[e * 3 + 2];
    w1.z = sph0[e * 5 + 0];
    w1.w = sph0[e * 5 + 1];
    w2.x = sph0[e * 5 + 2];
    w2.y = sph0[e * 5 + 3];
    w2.z = sph0[e * 5 + 4];
    w2.w = 0.f;
    float4* q = (float4*)&packed[(size_t)pos * 12];
    q[0] = w0; q[1] = w1; q[2] = w2;
}

// ---------------------------------------------------------------------------
// R7 k_gather: one wave per node. Stage up to 64 CSR-ordered packed records
// with 3 coalesced float4 loads/lane, then per edge broadcast the 11 fields
// via v_readlane (e/j land in SGPRs -> scalar addressing for xp/rbf rows).
// 4-edge groups keep 8 row-loads in flight.
// ---------------------------------------------------------------------------
__global__ __launch_bounds__(256) void k_gather(
    const float* __restrict__ xp, const float* __restrict__ rbf,
    const float* __restrict__ packed, const int* __restrict__ rowptr,
    float* __restrict__ agg0, float* __restrict__ agg1,
    float* __restrict__ aggh, int N)
{
    int n = blockIdx.x * 4 + (threadIdx.x >> 6);
    if (n >= N) return;
    int p = threadIdx.x & 63;
    int beg = rowptr[n], end = rowptr[n + 1];

    float a0 = 0.f;
    float a1x = 0.f, a1y = 0.f, a1z = 0.f;
    float h0 = 0.f, h1 = 0.f, h2 = 0.f, h3 = 0.f, h4 = 0.f;

    for (int base = beg; base < end; base += 64) {
        int m = end - base;
        if (m > 64) m = 64;
        float4 w0 = {0.f, 0.f, 0.f, 0.f};
        float4 w1 = {0.f, 0.f, 0.f, 0.f};
        float4 w2 = {0.f, 0.f, 0.f, 0.f};
        if (base + p < end) {
            const float4* q = (const float4*)&packed[(size_t)(base + p) * 12];
            w0 = q[0]; w1 = q[1]; w2 = q[2];
        }
        int k = 0;
        for (; k + 3 < m; k += 4) {
            int e0 = RLi(w0.x, k),     e1 = RLi(w0.x, k + 1);
            int e2 = RLi(w0.x, k + 2), e3 = RLi(w0.x, k + 3);
            int j0 = RLi(w0.y, k),     j1 = RLi(w0.y, k + 1);
            int j2 = RLi(w0.y, k + 2), j3 = RLi(w0.y, k + 3);
            float x0 = xp[(size_t)j0 * 64 + p], r0 = rbf[(size_t)e0 * 64 + p];
            float x1 = xp[(size_t)j1 * 64 + p], r1 = rbf[(size_t)e1 * 64 + p];
            float x2 = xp[(size_t)j2 * 64 + p], r2 = rbf[(size_t)e2 * 64 + p];
            float x3 = xp[(size_t)j3 * 64 + p], r3 = rbf[(size_t)e3 * 64 + p];
            float f0 = RLf(w0.z, k),     f1 = RLf(w0.z, k + 1);
            float f2 = RLf(w0.z, k + 2), f3 = RLf(w0.z, k + 3);
            float v0 = x0 * r0 * f0, v1 = x1 * r1 * f1;
            float v2 = x2 * r2 * f2, v3 = x3 * r3 * f3;
            a0 += (v0 + v1) + (v2 + v3);
            a1x += v0 * RLf(w0.w, k)     + v1 * RLf(w0.w, k + 1)
                 + v2 * RLf(w0.w, k + 2) + v3 * RLf(w0.w, k + 3);
            a1y += v0 * RLf(w1.x, k)     + v1 * RLf(w1.x, k + 1)
                 + v2 * RLf(w1.x, k + 2) + v3 * RLf(w1.x, k + 3);
            a1z += v0 * RLf(w1.y, k)     + v1 * RLf(w1.y, k + 1)
                 + v2 * RLf(w1.y, k + 2) + v3 * RLf(w1.y, k + 3);
            h0  += v0 * RLf(w1.z, k)     + v1 * RLf(w1.z, k + 1)
                 + v2 * RLf(w1.z, k + 2) + v3 * RLf(w1.z, k + 3);
            h1  += v0 * RLf(w1.w, k)     + v1 * RLf(w1.w, k + 1)
                 + v2 * RLf(w1.w, k + 2) + v3 * RLf(w1.w, k + 3);
            h2  += v0 * RLf(w2.x, k)     + v1 * RLf(w2.x, k + 1)
                 + v2 * RLf(w2.x, k + 2) + v3 * RLf(w2.x, k + 3);
            h3  += v0 * RLf(w2.y, k)     + v1 * RLf(w2.y, k + 1)
                 + v2 * RLf(w2.y, k + 2) + v3 * RLf(w2.y, k + 3);
            h4  += v0 * RLf(w2.z, k)     + v1 * RLf(w2.z, k + 1)
                 + v2 * RLf(w2.z, k + 2) + v3 * RLf(w2.z, k + 3);
        }
        for (; k < m; k++) {
            int e0 = RLi(w0.x, k);
            int j0 = RLi(w0.y, k);
            float f0 = RLf(w0.z, k);
            float v0 = xp[(size_t)j0 * 64 + p] * rbf[(size_t)e0 * 64 + p] * f0;
            a0 += v0;
            a1x += v0 * RLf(w0.w, k);
            a1y += v0 * RLf(w1.x, k);
            a1z += v0 * RLf(w1.y, k);
            h0  += v0 * RLf(w1.z, k);
            h1  += v0 * RLf(w1.w, k);
            h2  += v0 * RLf(w2.x, k);
            h3  += v0 * RLf(w2.y, k);
            h4  += v0 * RLf(w2.z, k);
        }
    }

    agg0[(size_t)n * 64 + p] = a0;
    agg1[((size_t)n * 3 + 0) * 64 + p] = a1x;
    agg1[((size_t)n * 3 + 1) * 64 + p] = a1y;
    agg1[((size_t)n * 3 + 2) * 64 + p] = a1z;
    aggh[((size_t)n * 5 + 0) * 64 + p] = h0;
    aggh[((size_t)n * 5 + 1) * 64 + p] = h1;
    aggh[((size_t)n * 5 + 2) * 64 + p] = h2;
    aggh[((size_t)n * 5 + 3) * 64 + p] = h3;
    aggh[((size_t)n * 5 + 4) * 64 + p] = h4;
}

// ---------------------------------------------------------------------------
// Pre-swizzle Wn1/Wn2 (f32, row-major [K][256]) into bf16 MFMA B-fragment
// order (unchanged, used by k_final).
// ---------------------------------------------------------------------------
__global__ __launch_bounds__(256) void k_swz(
    const float* __restrict__ W, unsigned short* __restrict__ Bsw, int K)
{
    int idx = blockIdx.x * 256 + threadIdx.x;
    int total = (K >> 5) * 1024;            // (K/32) * 16 ct * 64 lanes
    if (idx >= total) return;
    int lane = idx & 63;
    int ct = (idx >> 6) & 15;
    int ks = idx >> 10;
    int col = ct * 16 + (lane & 15);
    int kbase = (ks << 5) + ((lane >> 4) << 3);
    const float* p = &W[(size_t)kbase * 256 + col];
    uint4 o;
    o.x = pack2(p[0 * 256], p[1 * 256]);
    o.y = pack2(p[2 * 256], p[3 * 256]);
    o.z = pack2(p[4 * 256], p[5 * 256]);
    o.w = pack2(p[6 * 256], p[7 * 256]);
    *(uint4*)&Bsw[(size_t)idx * 8] = o;
}

// ---------------------------------------------------------------------------
// Generalized split swizzle for the up-projection weights [K][C] ->
// hi/lo bf16 B-fragments (hi = bf16(w), lo = bf16(w - hi)).
// ---------------------------------------------------------------------------
__global__ __launch_bounds__(256) void k_swz_split(
    const float* __restrict__ W, unsigned short* __restrict__ Bh,
    unsigned short* __restrict__ Bl, int K, int C)
{
    int idx = blockIdx.x * 256 + threadIdx.x;
    int ct_n = C >> 4;
    int total = (K >> 5) * ct_n * 64;
    if (idx >= total) return;
    int per_ks = ct_n * 64;
    int ks = idx / per_ks;
    int rem = idx - ks * per_ks;
    int ct = rem >> 6;
    int lane = rem & 63;
    int col = ct * 16 + (lane & 15);
    int kbase = (ks << 5) + ((lane >> 4) << 3);
    const float* p = &W[(size_t)kbase * C + col];
    unsigned short hs[8], ls[8];
#pragma unroll
    for (int j = 0; j < 8; j++) {
        float wv = p[(size_t)j * C];
        unsigned short h = f2bf(wv);
        float fh = __uint_as_float((unsigned)h << 16);
        hs[j] = h;
        ls[j] = f2bf(wv - fh);
    }
    uint4 oh, ol;
    oh.x = (unsigned)hs[0] | ((unsigned)hs[1] << 16);
    oh.y = (unsigned)hs[2] | ((unsigned)hs[3] << 16);
    oh.z = (unsigned)hs[4] | ((unsigned)hs[5] << 16);
    oh.w = (unsigned)hs[6] | ((unsigned)hs[7] << 16);
    ol.x = (unsigned)ls[0] | ((unsigned)ls[1] << 16);
    ol.y = (unsigned)ls[2] | ((unsigned)ls[3] << 16);
    ol.z = (unsigned)ls[4] | ((unsigned)ls[5] << 16);
    ol.w = (unsigned)ls[6] | ((unsigned)ls[7] << 16);
    *(uint4*)&Bh[(size_t)idx * 8] = oh;
    *(uint4*)&Bl[(size_t)idx * 8] = ol;
}

// ---------------------------------------------------------------------------
// Stage C1: node features via MFMA with hi/lo bf16 split (unchanged, proven)
// ---------------------------------------------------------------------------
__global__ __launch_bounds__(256, 3) void k_node(
    const float* __restrict__ xp, const float* __restrict__ agg0,
    const float* __restrict__ agg1, const float* __restrict__ aggh,
    const unsigned short* __restrict__ Wu0h, const unsigned short* __restrict__ Wu0l,
    const unsigned short* __restrict__ Wu1h, const unsigned short* __restrict__ Wu1l,
    const unsigned short* __restrict__ Wuhh, const unsigned short* __restrict__ Wuhl,
    const float* __restrict__ bu0, float* __restrict__ node, int N)
{
    __shared__ float xs[16 * 64];
    __shared__ __align__(16) unsigned short Ahi[9 * 16 * 72];
    __shared__ __align__(16) unsigned short Alo[9 * 16 * 72];

    int n0 = blockIdx.x * 16;
    int tid = threadIdx.x;
    int lane = tid & 63;
    int w = tid >> 6;          // wave -> col group
    int lcol = lane & 15;
    int quad = lane >> 4;
    int kq = quad * 8;

    // stage xp tile
    for (int t = tid; t < 16 * 64; t += 256) {
        int n = n0 + (t >> 6);
        xs[t] = (n < N) ? xp[(size_t)n * 64 + (t & 63)] : 0.f;
    }
    __syncthreads();

    // build 9 hi/lo A-tiles: m=0: xs*agg0; m=1..3: xs*agg1[c]; m=4..8: xs*aggh[c]
    for (int t = tid; t < 9 * 1024; t += 256) {
        int m = t >> 10;               // uniform per 256-thread iteration
        int rem = t & 1023;
        int r = rem >> 6, c = rem & 63;
        int n = n0 + r;
        float v = 0.f;
        if (n < N) {
            float xv = xs[rem];
            if (m == 0)      v = xv * agg0[(size_t)n * 64 + c];
            else if (m < 4)  v = xv * agg1[((size_t)n * 3 + (m - 1)) * 64 + c];
            else             v = xv * aggh[((size_t)n * 5 + (m - 4)) * 64 + c];
        }
        unsigned short h = f2bf(v);
        float fh = __uint_as_float((unsigned)h << 16);
        Ahi[(m * 16 + r) * 72 + c] = h;
        Alo[(m * 16 + r) * 72 + c] = f2bf(v - fh);
    }
    __syncthreads();

    // ---- G0: l0 = a0 @ Wu0 + bu0 ----
    {
        bf16x8 bh[2][2], bl[2][2];
#pragma unroll
        for (int ks = 0; ks < 2; ks++)
#pragma unroll
            for (int t = 0; t < 2; t++) {
                size_t bi = ((size_t)((ks * 8 + w * 2 + t) * 64 + lane)) * 8;
                bh[ks][t] = *(const bf16x8*)&Wu0h[bi];
                bl[ks][t] = *(const bf16x8*)&Wu0l[bi];
            }
        f32x4 acc[2];
        acc[0] = (f32x4){0.f, 0.f, 0.f, 0.f};
        acc[1] = (f32x4){0.f, 0.f, 0.f, 0.f};
#pragma unroll
        for (int ks = 0; ks < 2; ks++) {
            bf16x8 ah = *(const bf16x8*)&Ahi[lcol * 72 + ks * 32 + kq];
            bf16x8 al = *(const bf16x8*)&Alo[lcol * 72 + ks * 32 + kq];
#pragma unroll
            for (int t = 0; t < 2; t++) {
                acc[t] = __builtin_amdgcn_mfma_f32_16x16x32_bf16(ah, bh[ks][t], acc[t], 0, 0, 0);
                acc[t] = __builtin_amdgcn_mfma_f32_16x16x32_bf16(ah, bl[ks][t], acc[t], 0, 0, 0);
                acc[t] = __builtin_amdgcn_mfma_f32_16x16x32_bf16(al, bh[ks][t], acc[t], 0, 0, 0);
            }
        }
#pragma unroll
        for (int t = 0; t < 2; t++) {
            int col = w * 32 + t * 16 + lcol;
            float bb = bu0[col];
#pragma unroll
            for (int q = 0; q < 4; q++) {
                int n = n0 + quad * 4 + q;
                if (n < N) node[(size_t)n * 384 + col] = acc[t][q] + bb;
            }
        }
    }

    // ---- G1: l1 = sum_c ((a1_c @ Wu1))^2 ----
    {
        bf16x8 bh[2][2], bl[2][2];
#pragma unroll
        for (int ks = 0; ks < 2; ks++)
#pragma unroll
            for (int t = 0; t < 2; t++) {
                size_t bi = ((size_t)((ks * 8 + w * 2 + t) * 64 + lane)) * 8;
                bh[ks][t] = *(const bf16x8*)&Wu1h[bi];
                bl[ks][t] = *(const bf16x8*)&Wu1l[bi];
            }
        f32x4 S[2];
        S[0] = (f32x4){0.f, 0.f, 0.f, 0.f};
        S[1] = (f32x4){0.f, 0.f, 0.f, 0.f};
#pragma unroll
        for (int c = 0; c < 3; c++) {
            f32x4 d[2];
            d[0] = (f32x4){0.f, 0.f, 0.f, 0.f};
            d[1] = (f32x4){0.f, 0.f, 0.f, 0.f};
            int abase = (1 + c) * (16 * 72);
#pragma unroll
            for (int ks = 0; ks < 2; ks++) {
                bf16x8 ah = *(const bf16x8*)&Ahi[abase + lcol * 72 + ks * 32 + kq];
                bf16x8 al = *(const bf16x8*)&Alo[abase + lcol * 72 + ks * 32 + kq];
#pragma unroll
                for (int t = 0; t < 2; t++) {
                    d[t] = __builtin_amdgcn_mfma_f32_16x16x32_bf16(ah, bh[ks][t], d[t], 0, 0, 0);
                    d[t] = __builtin_amdgcn_mfma_f32_16x16x32_bf16(ah, bl[ks][t], d[t], 0, 0, 0);
                    d[t] = __builtin_amdgcn_mfma_f32_16x16x32_bf16(al, bh[ks][t], d[t], 0, 0, 0);
                }
            }
            S[0] += d[0] * d[0];
            S[1] += d[1] * d[1];
        }
#pragma unroll
        for (int t = 0; t < 2; t++) {
            int col = w * 32 + t * 16 + lcol;
#pragma unroll
            for (int q = 0; q < 4; q++) {
                int n = n0 + quad * 4 + q;
                if (n < N) node[(size_t)n * 384 + 128 + col] = S[t][q];
            }
        }
    }

    // ---- G2: lh = sum_c ((ah_c @ Wuh))^2 ----
    {
        bf16x8 bh[2][2], bl[2][2];
#pragma unroll
        for (int ks = 0; ks < 2; ks++)
#pragma unroll
            for (int t = 0; t < 2; t++) {
                size_t bi = ((size_t)((ks * 8 + w * 2 + t) * 64 + lane)) * 8;
                bh[ks][t] = *(const bf16x8*)&Wuhh[bi];
                bl[ks][t] = *(const bf16x8*)&Wuhl[bi];
            }
        f32x4 S[2];
        S[0] = (f32x4){0.f, 0.f, 0.f, 0.f};
        S[1] = (f32x4){0.f, 0.f, 0.f, 0.f};
#pragma unroll
        for (int c = 0; c < 5; c++) {
            f32x4 d[2];
            d[0] = (f32x4){0.f, 0.f, 0.f, 0.f};
            d[1] = (f32x4){0.f, 0.f, 0.f, 0.f};
            int abase = (4 + c) * (16 * 72);
#pragma unroll
            for (int ks = 0; ks < 2; ks++) {
                bf16x8 ah = *(const bf16x8*)&Ahi[abase + lcol * 72 + ks * 32 + kq];
                bf16x8 al = *(const bf16x8*)&Alo[abase + lcol * 72 + ks * 32 + kq];
#pragma unroll
                for (int t = 0; t < 2; t++) {
                    d[t] = __builtin_amdgcn_mfma_f32_16x16x32_bf16(ah, bh[ks][t], d[t], 0, 0, 0);
                    d[t] = __builtin_amdgcn_mfma_f32_16x16x32_bf16(ah, bl[ks][t], d[t], 0, 0, 0);
                    d[t] = __builtin_amdgcn_mfma_f32_16x16x32_bf16(al, bh[ks][t], d[t], 0, 0, 0);
                }
            }
            S[0] += d[0] * d[0];
            S[1] += d[1] * d[1];
        }
#pragma unroll
        for (int t = 0; t < 2; t++) {
            int col = w * 32 + t * 16 + lcol;
#pragma unroll
            for (int q = 0; q < 4; q++) {
                int n = n0 + quad * 4 + q;
                if (n < N) node[(size_t)n * 384 + 256 + col] = S[t][q];
            }
        }
    }
}

// ---------------------------------------------------------------------------
// Stage C2: bf16 MFMA fused GEMM1+LN+SiLU+GEMM2 (unchanged, proven)
// ---------------------------------------------------------------------------
__global__ __launch_bounds__(256, 4) void k_final(
    const float* __restrict__ node, const unsigned short* __restrict__ Bsw1,
    const float* __restrict__ bn1, const float* __restrict__ lng,
    const float* __restrict__ lnb, const unsigned short* __restrict__ Bsw2,
    const float* __restrict__ bn2, const float* __restrict__ x,
    float* __restrict__ out, int N)
{
    __shared__ unsigned short Abf[32 * 392];   // GEMM1 A [32][384+8]; reused as GEMM2 A [32][256+8]
    __shared__ float red[32][33];
    __shared__ float red2[32][33];
    __shared__ float mstat[32][2];

    int n0 = blockIdx.x * 32;
    int tid = threadIdx.x;
    int lane = tid & 63;
    int w = tid >> 6;
    int rt = w & 1;
    int cg = w >> 1;
    int lcol = lane & 15;
    int quad = lane >> 4;
    int arow = rt * 16 + lcol;       // A-frag row this lane reads
    int kq = quad * 8;               // A/B-frag k sub-offset

    // ---- stage node tile as bf16 -> Abf[32][392] ----
    for (int i = tid; i < 32 * 192; i += 256) {
        int r = i / 192, c2 = i - r * 192;
        int n = n0 + r;
        float2 v;
        if (n < N) v = *(const float2*)&node[(size_t)n * 384 + 2 * c2];
        else { v.x = 0.f; v.y = 0.f; }
        *(unsigned*)&Abf[r * 392 + 2 * c2] = pack2(v.x, v.y);
    }
    __syncthreads();

    // ---- GEMM1: T = node @ Wn1 ----
    f32x4 acc[8];
#pragma unroll
    for (int t = 0; t < 8; t++) acc[t] = (f32x4){0.f, 0.f, 0.f, 0.f};
    for (int ks = 0; ks < 12; ks++) {
        bf16x8 a = *(const bf16x8*)&Abf[arow * 392 + ks * 32 + kq];
        const bf16x8* bp =
            (const bf16x8*)&Bsw1[(size_t)(((ks * 16 + cg * 8) * 64) + lane) * 8];
#pragma unroll
        for (int t = 0; t < 8; t++)
            acc[t] = __builtin_amdgcn_mfma_f32_16x16x32_bf16(a, bp[t * 64], acc[t], 0, 0, 0);
    }

    // ---- per-row LN stats from accumulators ----
    float bias[8];
#pragma unroll
    for (int t = 0; t < 8; t++) bias[t] = bn1[cg * 128 + t * 16 + lcol];
#pragma unroll
    for (int q = 0; q < 4; q++) {
        float s = 0.f, s2 = 0.f;
#pragma unroll
        for (int t = 0; t < 8; t++) {
            float v = acc[t][q] + bias[t];
            s += v; s2 += v * v;
        }
        int row = rt * 16 + quad * 4 + q;
        red[row][cg * 16 + lcol] = s;
        red2[row][cg * 16 + lcol] = s2;
    }
    __syncthreads();
    if (tid < 32) {
        float s = 0.f, s2 = 0.f;
#pragma unroll
        for (int u = 0; u < 32; u++) { s += red[tid][u]; s2 += red2[tid][u]; }
        float m = s * (1.f / 256.f);
        float var = s2 * (1.f / 256.f) - m * m;
        mstat[tid][0] = m;
        mstat[tid][1] = rsqrtf(var + 1e-5f);
    }
    __syncthreads();

    // ---- LN + SiLU, write h as bf16 GEMM2 A-tile [32][264] ----
#pragma unroll
    for (int t = 0; t < 8; t++) {
        int col = cg * 128 + t * 16 + lcol;
        float gg = lng[col], bb = lnb[col];
#pragma unroll
        for (int q = 0; q < 4; q++) {
            int row = rt * 16 + quad * 4 + q;
            float z = (acc[t][q] + bias[t] - mstat[row][0]) * mstat[row][1] * gg + bb;
            float h = z / (1.f + __expf(-z));
            Abf[row * 264 + col] = f2bf(h);
        }
    }
    __syncthreads();

    // ---- GEMM2: out = h @ Wn2 + bn2 + x ----
    f32x4 o[8];
#pragma unroll
    for (int t = 0; t < 8; t++) o[t] = (f32x4){0.f, 0.f, 0.f, 0.f};
    for (int ks = 0; ks < 8; ks++) {
        bf16x8 a = *(const bf16x8*)&Abf[arow * 264 + ks * 32 + kq];
        const bf16x8* bp =
            (const bf16x8*)&Bsw2[(size_t)(((ks * 16 + cg * 8) * 64) + lane) * 8];
#pragma unroll
        for (int t = 0; t < 8; t++)
            o[t] = __builtin_amdgcn_mfma_f32_16x16x32_bf16(a, bp[t * 64], o[t], 0, 0, 0);
    }
#pragma unroll
    for (int t = 0; t < 8; t++) {
        int col = cg * 128 + t * 16 + lcol;
        float ob = bn2[col];
#pragma unroll
        for (int q = 0; q < 4; q++) {
            int row = rt * 16 + quad * 4 + q;
            int n = n0 + row;
            if (n < N)
                out[(size_t)n * 256 + col] = o[t][q] + ob + x[(size_t)n * 256 + col];
        }
    }
}

// ---------------------------------------------------------------------------
extern "C" void kernel_launch(void* const* d_in, const int* in_sizes, int n_in,
                              void* d_out, int out_size, void* d_ws, size_t ws_size,
                              hipStream_t stream)
{
    const float* x      = (const float*)d_in[0];
    const float* rbf    = (const float*)d_in[1];
    const float* factor = (const float*)d_in[2];
    const float* sph0   = (const float*)d_in[3];
    const float* sph1   = (const float*)d_in[4];
    const float* Wd     = (const float*)d_in[5];
    const float* bd     = (const float*)d_in[6];
    const float* Wu0    = (const float*)d_in[7];
    const float* bu0    = (const float*)d_in[8];
    const float* Wu1    = (const float*)d_in[9];
    const float* Wuh    = (const float*)d_in[10];
    const float* Wn1    = (const float*)d_in[11];
    const float* bn1    = (const float*)d_in[12];
    const float* lng    = (const float*)d_in[13];
    const float* lnb    = (const float*)d_in[14];
    const float* Wn2    = (const float*)d_in[15];
    const float* bn2    = (const float*)d_in[16];
    const int*   jidx   = (const int*)d_in[17];
    const int*   iidx   = (const int*)d_in[18];
    float* out = (float*)d_out;

    int N = in_sizes[0] / 256;
    int E = in_sizes[17];

    float* ws   = (float*)d_ws;
    float* xp   = ws;                        // [N,64]
    float* agg0 = xp   + (size_t)N * 64;     // [N,64]
    float* agg1 = agg0 + (size_t)N * 64;     // [N,3,64]
    float* aggh = agg1 + (size_t)N * 192;    // [N,5,64]
    float* node = aggh + (size_t)N * 320;    // [N,384]
    // swizzled bf16 weights after node (one-time conversion per launch)
    unsigned short* Bsw1 = (unsigned short*)(node + (size_t)N * 384); // 12*16*64*8
    unsigned short* Bsw2 = Bsw1 + 12 * 16 * 64 * 8;                    // 8*16*64*8
    // hi/lo split-swizzled up-projection weights (each 64*128)
    unsigned short* Wu0h_s = Bsw2 + 8 * 16 * 64 * 8;
    unsigned short* Wu0l_s = Wu0h_s + 64 * 128;
    unsigned short* Wu1h_s = Wu0l_s + 64 * 128;
    unsigned short* Wu1l_s = Wu1h_s + 64 * 128;
    unsigned short* Wuhh_s = Wu1l_s + 64 * 128;
    unsigned short* Wuhl_s = Wuhh_s + 64 * 128;

    // CSR scratch + packed edge records aliased onto the node buffer (dead
    // before k_node writes it). node = N*384 floats = 9.6M floats @ N=25k;
    // scratch uses 3*(N+1) ints (~75k words), packed (12*E floats = 6M) is
    // placed 131072 floats in -> comfortably past scratch, well within node.
    int* counts  = (int*)node;               // [N]
    int* rowptr  = counts + (N + 1);         // [N+1]
    int* cursor  = rowptr + (N + 1);         // [N]
    float* packed = node + 131072;           // [E,12] CSR-ordered edge records

    hipMemsetAsync(counts, 0, (size_t)(N + 1) * sizeof(int), stream);

    k_swz<<<dim3(48), dim3(256), 0, stream>>>(Wn1, Bsw1, 384);
    k_swz<<<dim3(32), dim3(256), 0, stream>>>(Wn2, Bsw2, 256);
    k_swz_split<<<dim3(4), dim3(256), 0, stream>>>(Wu0, Wu0h_s, Wu0l_s, 64, 128);
    k_swz_split<<<dim3(4), dim3(256), 0, stream>>>(Wu1, Wu1h_s, Wu1l_s, 64, 128);
    k_swz_split<<<dim3(4), dim3(256), 0, stream>>>(Wuh, Wuhh_s, Wuhl_s, 64, 128);
    k_down<<<dim3((N + KD_NODES - 1) / KD_NODES), dim3(256), 0, stream>>>(
        x, Wd, bd, xp, N);
    k_hist<<<dim3((E + 255) / 256), dim3(256), 0, stream>>>(iidx, counts, E);
    k_scan<<<dim3(1), dim3(1024), 0, stream>>>(counts, rowptr, cursor, N);
    k_scatter_pack<<<dim3((E + 255) / 256), dim3(256), 0, stream>>>(
        iidx, jidx, factor, sph0, sph1, cursor, packed, E);
    k_gather<<<dim3((N + 3) / 4), dim3(256), 0, stream>>>(
        xp, rbf, packed, rowptr, agg0, agg1, aggh, N);
    k_node<<<dim3((N + 15) / 16), dim3(256), 0, stream>>>(
        xp, agg0, agg1, aggh, Wu0h_s, Wu0l_s, Wu1h_s, Wu1l_s, Wuhh_s, Wuhl_s,
        bu0, node, N);
    k_final<<<dim3((N + 31) / 32), dim3(256), 0, stream>>>(
        node, Bsw1, bn1, lng, lnb, Bsw2, bn2, x, out, N);
}

// Round 3
// 509.925 us; speedup vs baseline: 1.5636x; 1.1180x over previous
//
#include <hip/hip_runtime.h>
#include <hip/hip_bf16.h>

typedef __attribute__((ext_vector_type(8))) short bf16x8;
typedef __attribute__((ext_vector_type(4))) float f32x4;

__device__ __forceinline__ unsigned short f2bf(float f) {
    unsigned u = __float_as_uint(f);
    return (unsigned short)((u + 0x7FFF + ((u >> 16) & 1)) >> 16);  // RNE
}
__device__ __forceinline__ unsigned pack2(float a, float b) {
    return (unsigned)f2bf(a) | ((unsigned)f2bf(b) << 16);
}
__device__ __forceinline__ float ubf(unsigned short h) {
    return __uint_as_float((unsigned)h << 16);
}
// register broadcast: lane k (uniform) -> all lanes, result in SGPR
__device__ __forceinline__ int RLi(float v, int k) {
    return __builtin_amdgcn_readlane(__float_as_int(v), k);
}
__device__ __forceinline__ float RLf(float v, int k) {
    return __uint_as_float((unsigned)__builtin_amdgcn_readlane(__float_as_int(v), k));
}

// ---------------------------------------------------------------------------
// Stage A (R8 rewrite): _x = x @ W_down + b_down via hi/lo split bf16 MFMA.
// 32 nodes/block, 4 waves; wave w: row-tile rt=w&1, cols cg*32..cg*32+31.
// A-tile [32][264] hi/lo in LDS (pad -> 2-way alias, free). B-frags direct
// from L2-resident pre-split-swizzled Wd. LDS 33.8 KB -> 4 blocks/CU.
// ---------------------------------------------------------------------------
__global__ __launch_bounds__(256, 4) void k_down(
    const float* __restrict__ x, const unsigned short* __restrict__ Wdh,
    const unsigned short* __restrict__ Wdl, const float* __restrict__ bd,
    float* __restrict__ xp, int N)
{
    __shared__ __align__(16) unsigned short Ahi[32 * 264];
    __shared__ __align__(16) unsigned short Alo[32 * 264];

    int n0 = blockIdx.x * 32;
    int tid = threadIdx.x;
    int lane = tid & 63;
    int w = tid >> 6;
    int rt = w & 1;
    int cg = w >> 1;
    int lcol = lane & 15;
    int quad = lane >> 4;
    int kq = quad * 8;

    // stage x tile as hi/lo bf16 (each thread: 8 float4s)
    for (int t = tid; t < 32 * 64; t += 256) {
        int r = t >> 6, c4 = t & 63;
        int n = n0 + r;
        float4 v = {0.f, 0.f, 0.f, 0.f};
        if (n < N) v = *(const float4*)&x[(size_t)n * 256 + c4 * 4];
        unsigned short hx = f2bf(v.x), hy = f2bf(v.y);
        unsigned short hz = f2bf(v.z), hw = f2bf(v.w);
        uint2 oh, ol;
        oh.x = (unsigned)hx | ((unsigned)hy << 16);
        oh.y = (unsigned)hz | ((unsigned)hw << 16);
        ol.x = (unsigned)f2bf(v.x - ubf(hx)) | ((unsigned)f2bf(v.y - ubf(hy)) << 16);
        ol.y = (unsigned)f2bf(v.z - ubf(hz)) | ((unsigned)f2bf(v.w - ubf(hw)) << 16);
        *(uint2*)&Ahi[r * 264 + c4 * 4] = oh;
        *(uint2*)&Alo[r * 264 + c4 * 4] = ol;
    }
    __syncthreads();

    int arow = rt * 16 + lcol;
    f32x4 acc[2];
    acc[0] = (f32x4){0.f, 0.f, 0.f, 0.f};
    acc[1] = (f32x4){0.f, 0.f, 0.f, 0.f};
#pragma unroll
    for (int ks = 0; ks < 8; ks++) {
        bf16x8 ah = *(const bf16x8*)&Ahi[arow * 264 + ks * 32 + kq];
        bf16x8 al = *(const bf16x8*)&Alo[arow * 264 + ks * 32 + kq];
#pragma unroll
        for (int t = 0; t < 2; t++) {
            int ct = cg * 2 + t;
            size_t bi = ((size_t)((ks * 4 + ct) * 64 + lane)) * 8;
            bf16x8 bh = *(const bf16x8*)&Wdh[bi];
            bf16x8 bl = *(const bf16x8*)&Wdl[bi];
            acc[t] = __builtin_amdgcn_mfma_f32_16x16x32_bf16(ah, bh, acc[t], 0, 0, 0);
            acc[t] = __builtin_amdgcn_mfma_f32_16x16x32_bf16(ah, bl, acc[t], 0, 0, 0);
            acc[t] = __builtin_amdgcn_mfma_f32_16x16x32_bf16(al, bh, acc[t], 0, 0, 0);
        }
    }
#pragma unroll
    for (int t = 0; t < 2; t++) {
        int col = cg * 32 + t * 16 + lcol;
        float bb = bd[col];
#pragma unroll
        for (int q = 0; q < 4; q++) {
            int row = rt * 16 + quad * 4 + q;
            int n = n0 + row;
            if (n < N) xp[(size_t)n * 64 + col] = acc[t][q] + bb;
        }
    }
}

// ---------------------------------------------------------------------------
// Stage B: CSR build; scatter packs per-edge record into CSR order:
// 12 floats/edge {e, j, factor, s1x, s1y, s1z, h0..h4, pad}.
// ---------------------------------------------------------------------------
__global__ __launch_bounds__(256) void k_hist(
    const int* __restrict__ iidx, int* __restrict__ counts, int E)
{
    int e = blockIdx.x * 256 + threadIdx.x;
    if (e < E) atomicAdd(&counts[iidx[e]], 1);
}

__global__ __launch_bounds__(1024) void k_scan(
    const int* __restrict__ counts, int* __restrict__ rowptr,
    int* __restrict__ cursor, int N)
{
    __shared__ int part[1024];
    int t = threadIdx.x;
    int chunk = (N + 1023) / 1024;
    int beg = t * chunk;
    int end = min(beg + chunk, N);
    int s = 0;
    for (int i = beg; i < end; i++) s += counts[i];
    part[t] = s;
    __syncthreads();
    for (int off = 1; off < 1024; off <<= 1) {
        int v = (t >= off) ? part[t - off] : 0;
        __syncthreads();
        part[t] += v;
        __syncthreads();
    }
    int run = (t == 0) ? 0 : part[t - 1];
    for (int i = beg; i < end; i++) {
        rowptr[i] = run;
        cursor[i] = run;
        run += counts[i];
    }
    if (t == 1023) rowptr[N] = part[1023];
}

__global__ __launch_bounds__(256) void k_scatter_pack(
    const int* __restrict__ iidx, const int* __restrict__ jidx,
    const float* __restrict__ factor, const float* __restrict__ sph0,
    const float* __restrict__ sph1, int* __restrict__ cursor,
    float* __restrict__ packed, int E)
{
    int e = blockIdx.x * 256 + threadIdx.x;
    if (e >= E) return;
    int pos = atomicAdd(&cursor[iidx[e]], 1);
    float4 w0, w1, w2;
    w0.x = __int_as_float(e);
    w0.y = __int_as_float(jidx[e]);
    w0.z = factor[e];
    w0.w = sph1[e * 3 + 0];
    w1.x = sph1[e * 3 + 1];
    w1.y = sph1[e * 3 + 2];
    w1.z = sph0[e * 5 + 0];
    w1.w = sph0[e * 5 + 1];
    w2.x = sph0[e * 5 + 2];
    w2.y = sph0[e * 5 + 3];
    w2.z = sph0[e * 5 + 4];
    w2.w = 0.f;
    float4* q = (float4*)&packed[(size_t)pos * 12];
    q[0] = w0; q[1] = w1; q[2] = w2;
}

// ---------------------------------------------------------------------------
// k_gather: one wave per node; coalesced packed-record staging + readlane
// broadcast (proven R7).
// ---------------------------------------------------------------------------
__global__ __launch_bounds__(256) void k_gather(
    const float* __restrict__ xp, const float* __restrict__ rbf,
    const float* __restrict__ packed, const int* __restrict__ rowptr,
    float* __restrict__ agg0, float* __restrict__ agg1,
    float* __restrict__ aggh, int N)
{
    int n = blockIdx.x * 4 + (threadIdx.x >> 6);
    if (n >= N) return;
    int p = threadIdx.x & 63;
    int beg = rowptr[n], end = rowptr[n + 1];

    float a0 = 0.f;
    float a1x = 0.f, a1y = 0.f, a1z = 0.f;
    float h0 = 0.f, h1 = 0.f, h2 = 0.f, h3 = 0.f, h4 = 0.f;

    for (int base = beg; base < end; base += 64) {
        int m = end - base;
        if (m > 64) m = 64;
        float4 w0 = {0.f, 0.f, 0.f, 0.f};
        float4 w1 = {0.f, 0.f, 0.f, 0.f};
        float4 w2 = {0.f, 0.f, 0.f, 0.f};
        if (base + p < end) {
            const float4* q = (const float4*)&packed[(size_t)(base + p) * 12];
            w0 = q[0]; w1 = q[1]; w2 = q[2];
        }
        int k = 0;
        for (; k + 3 < m; k += 4) {
            int e0 = RLi(w0.x, k),     e1 = RLi(w0.x, k + 1);
            int e2 = RLi(w0.x, k + 2), e3 = RLi(w0.x, k + 3);
            int j0 = RLi(w0.y, k),     j1 = RLi(w0.y, k + 1);
            int j2 = RLi(w0.y, k + 2), j3 = RLi(w0.y, k + 3);
            float x0 = xp[(size_t)j0 * 64 + p], r0 = rbf[(size_t)e0 * 64 + p];
            float x1 = xp[(size_t)j1 * 64 + p], r1 = rbf[(size_t)e1 * 64 + p];
            float x2 = xp[(size_t)j2 * 64 + p], r2 = rbf[(size_t)e2 * 64 + p];
            float x3 = xp[(size_t)j3 * 64 + p], r3 = rbf[(size_t)e3 * 64 + p];
            float f0 = RLf(w0.z, k),     f1 = RLf(w0.z, k + 1);
            float f2 = RLf(w0.z, k + 2), f3 = RLf(w0.z, k + 3);
            float v0 = x0 * r0 * f0, v1 = x1 * r1 * f1;
            float v2 = x2 * r2 * f2, v3 = x3 * r3 * f3;
            a0 += (v0 + v1) + (v2 + v3);
            a1x += v0 * RLf(w0.w, k)     + v1 * RLf(w0.w, k + 1)
                 + v2 * RLf(w0.w, k + 2) + v3 * RLf(w0.w, k + 3);
            a1y += v0 * RLf(w1.x, k)     + v1 * RLf(w1.x, k + 1)
                 + v2 * RLf(w1.x, k + 2) + v3 * RLf(w1.x, k + 3);
            a1z += v0 * RLf(w1.y, k)     + v1 * RLf(w1.y, k + 1)
                 + v2 * RLf(w1.y, k + 2) + v3 * RLf(w1.y, k + 3);
            h0  += v0 * RLf(w1.z, k)     + v1 * RLf(w1.z, k + 1)
                 + v2 * RLf(w1.z, k + 2) + v3 * RLf(w1.z, k + 3);
            h1  += v0 * RLf(w1.w, k)     + v1 * RLf(w1.w, k + 1)
                 + v2 * RLf(w1.w, k + 2) + v3 * RLf(w1.w, k + 3);
            h2  += v0 * RLf(w2.x, k)     + v1 * RLf(w2.x, k + 1)
                 + v2 * RLf(w2.x, k + 2) + v3 * RLf(w2.x, k + 3);
            h3  += v0 * RLf(w2.y, k)     + v1 * RLf(w2.y, k + 1)
                 + v2 * RLf(w2.y, k + 2) + v3 * RLf(w2.y, k + 3);
            h4  += v0 * RLf(w2.z, k)     + v1 * RLf(w2.z, k + 1)
                 + v2 * RLf(w2.z, k + 2) + v3 * RLf(w2.z, k + 3);
        }
        for (; k < m; k++) {
            int e0 = RLi(w0.x, k);
            int j0 = RLi(w0.y, k);
            float f0 = RLf(w0.z, k);
            float v0 = xp[(size_t)j0 * 64 + p] * rbf[(size_t)e0 * 64 + p] * f0;
            a0 += v0;
            a1x += v0 * RLf(w0.w, k);
            a1y += v0 * RLf(w1.x, k);
            a1z += v0 * RLf(w1.y, k);
            h0  += v0 * RLf(w1.z, k);
            h1  += v0 * RLf(w1.w, k);
            h2  += v0 * RLf(w2.x, k);
            h3  += v0 * RLf(w2.y, k);
            h4  += v0 * RLf(w2.z, k);
        }
    }

    agg0[(size_t)n * 64 + p] = a0;
    agg1[((size_t)n * 3 + 0) * 64 + p] = a1x;
    agg1[((size_t)n * 3 + 1) * 64 + p] = a1y;
    agg1[((size_t)n * 3 + 2) * 64 + p] = a1z;
    aggh[((size_t)n * 5 + 0) * 64 + p] = h0;
    aggh[((size_t)n * 5 + 1) * 64 + p] = h1;
    aggh[((size_t)n * 5 + 2) * 64 + p] = h2;
    aggh[((size_t)n * 5 + 3) * 64 + p] = h3;
    aggh[((size_t)n * 5 + 4) * 64 + p] = h4;
}

// ---------------------------------------------------------------------------
// Pre-swizzle Wn1/Wn2 (f32, row-major [K][256]) into bf16 MFMA B-fragment
// order (used by k_final).
// ---------------------------------------------------------------------------
__global__ __launch_bounds__(256) void k_swz(
    const float* __restrict__ W, unsigned short* __restrict__ Bsw, int K)
{
    int idx = blockIdx.x * 256 + threadIdx.x;
    int total = (K >> 5) * 1024;            // (K/32) * 16 ct * 64 lanes
    if (idx >= total) return;
    int lane = idx & 63;
    int ct = (idx >> 6) & 15;
    int ks = idx >> 10;
    int col = ct * 16 + (lane & 15);
    int kbase = (ks << 5) + ((lane >> 4) << 3);
    const float* p = &W[(size_t)kbase * 256 + col];
    uint4 o;
    o.x = pack2(p[0 * 256], p[1 * 256]);
    o.y = pack2(p[2 * 256], p[3 * 256]);
    o.z = pack2(p[4 * 256], p[5 * 256]);
    o.w = pack2(p[6 * 256], p[7 * 256]);
    *(uint4*)&Bsw[(size_t)idx * 8] = o;
}

// ---------------------------------------------------------------------------
// Generalized split swizzle for weights [K][C] -> hi/lo bf16 B-fragments
// (hi = bf16(w), lo = bf16(w - hi)).
// ---------------------------------------------------------------------------
__global__ __launch_bounds__(256) void k_swz_split(
    const float* __restrict__ W, unsigned short* __restrict__ Bh,
    unsigned short* __restrict__ Bl, int K, int C)
{
    int idx = blockIdx.x * 256 + threadIdx.x;
    int ct_n = C >> 4;
    int total = (K >> 5) * ct_n * 64;
    if (idx >= total) return;
    int per_ks = ct_n * 64;
    int ks = idx / per_ks;
    int rem = idx - ks * per_ks;
    int ct = rem >> 6;
    int lane = rem & 63;
    int col = ct * 16 + (lane & 15);
    int kbase = (ks << 5) + ((lane >> 4) << 3);
    const float* p = &W[(size_t)kbase * C + col];
    unsigned short hs[8], ls[8];
#pragma unroll
    for (int j = 0; j < 8; j++) {
        float wv = p[(size_t)j * C];
        unsigned short h = f2bf(wv);
        float fh = __uint_as_float((unsigned)h << 16);
        hs[j] = h;
        ls[j] = f2bf(wv - fh);
    }
    uint4 oh, ol;
    oh.x = (unsigned)hs[0] | ((unsigned)hs[1] << 16);
    oh.y = (unsigned)hs[2] | ((unsigned)hs[3] << 16);
    oh.z = (unsigned)hs[4] | ((unsigned)hs[5] << 16);
    oh.w = (unsigned)hs[6] | ((unsigned)hs[7] << 16);
    ol.x = (unsigned)ls[0] | ((unsigned)ls[1] << 16);
    ol.y = (unsigned)ls[2] | ((unsigned)ls[3] << 16);
    ol.z = (unsigned)ls[4] | ((unsigned)ls[5] << 16);
    ol.w = (unsigned)ls[6] | ((unsigned)ls[7] << 16);
    *(uint4*)&Bh[(size_t)idx * 8] = oh;
    *(uint4*)&Bl[(size_t)idx * 8] = ol;
}

// ---------------------------------------------------------------------------
// Stage C1: node features via MFMA with hi/lo bf16 split (unchanged, proven)
// ---------------------------------------------------------------------------
__global__ __launch_bounds__(256, 3) void k_node(
    const float* __restrict__ xp, const float* __restrict__ agg0,
    const float* __restrict__ agg1, const float* __restrict__ aggh,
    const unsigned short* __restrict__ Wu0h, const unsigned short* __restrict__ Wu0l,
    const unsigned short* __restrict__ Wu1h, const unsigned short* __restrict__ Wu1l,
    const unsigned short* __restrict__ Wuhh, const unsigned short* __restrict__ Wuhl,
    const float* __restrict__ bu0, float* __restrict__ node, int N)
{
    __shared__ float xs[16 * 64];
    __shared__ __align__(16) unsigned short Ahi[9 * 16 * 72];
    __shared__ __align__(16) unsigned short Alo[9 * 16 * 72];

    int n0 = blockIdx.x * 16;
    int tid = threadIdx.x;
    int lane = tid & 63;
    int w = tid >> 6;          // wave -> col group
    int lcol = lane & 15;
    int quad = lane >> 4;
    int kq = quad * 8;

    // stage xp tile
    for (int t = tid; t < 16 * 64; t += 256) {
        int n = n0 + (t >> 6);
        xs[t] = (n < N) ? xp[(size_t)n * 64 + (t & 63)] : 0.f;
    }
    __syncthreads();

    // build 9 hi/lo A-tiles: m=0: xs*agg0; m=1..3: xs*agg1[c]; m=4..8: xs*aggh[c]
    for (int t = tid; t < 9 * 1024; t += 256) {
        int m = t >> 10;               // uniform per 256-thread iteration
        int rem = t & 1023;
        int r = rem >> 6, c = rem & 63;
        int n = n0 + r;
        float v = 0.f;
        if (n < N) {
            float xv = xs[rem];
            if (m == 0)      v = xv * agg0[(size_t)n * 64 + c];
            else if (m < 4)  v = xv * agg1[((size_t)n * 3 + (m - 1)) * 64 + c];
            else             v = xv * aggh[((size_t)n * 5 + (m - 4)) * 64 + c];
        }
        unsigned short h = f2bf(v);
        float fh = __uint_as_float((unsigned)h << 16);
        Ahi[(m * 16 + r) * 72 + c] = h;
        Alo[(m * 16 + r) * 72 + c] = f2bf(v - fh);
    }
    __syncthreads();

    // ---- G0: l0 = a0 @ Wu0 + bu0 ----
    {
        bf16x8 bh[2][2], bl[2][2];
#pragma unroll
        for (int ks = 0; ks < 2; ks++)
#pragma unroll
            for (int t = 0; t < 2; t++) {
                size_t bi = ((size_t)((ks * 8 + w * 2 + t) * 64 + lane)) * 8;
                bh[ks][t] = *(const bf16x8*)&Wu0h[bi];
                bl[ks][t] = *(const bf16x8*)&Wu0l[bi];
            }
        f32x4 acc[2];
        acc[0] = (f32x4){0.f, 0.f, 0.f, 0.f};
        acc[1] = (f32x4){0.f, 0.f, 0.f, 0.f};
#pragma unroll
        for (int ks = 0; ks < 2; ks++) {
            bf16x8 ah = *(const bf16x8*)&Ahi[lcol * 72 + ks * 32 + kq];
            bf16x8 al = *(const bf16x8*)&Alo[lcol * 72 + ks * 32 + kq];
#pragma unroll
            for (int t = 0; t < 2; t++) {
                acc[t] = __builtin_amdgcn_mfma_f32_16x16x32_bf16(ah, bh[ks][t], acc[t], 0, 0, 0);
                acc[t] = __builtin_amdgcn_mfma_f32_16x16x32_bf16(ah, bl[ks][t], acc[t], 0, 0, 0);
                acc[t] = __builtin_amdgcn_mfma_f32_16x16x32_bf16(al, bh[ks][t], acc[t], 0, 0, 0);
            }
        }
#pragma unroll
        for (int t = 0; t < 2; t++) {
            int col = w * 32 + t * 16 + lcol;
            float bb = bu0[col];
#pragma unroll
            for (int q = 0; q < 4; q++) {
                int n = n0 + quad * 4 + q;
                if (n < N) node[(size_t)n * 384 + col] = acc[t][q] + bb;
            }
        }
    }

    // ---- G1: l1 = sum_c ((a1_c @ Wu1))^2 ----
    {
        bf16x8 bh[2][2], bl[2][2];
#pragma unroll
        for (int ks = 0; ks < 2; ks++)
#pragma unroll
            for (int t = 0; t < 2; t++) {
                size_t bi = ((size_t)((ks * 8 + w * 2 + t) * 64 + lane)) * 8;
                bh[ks][t] = *(const bf16x8*)&Wu1h[bi];
                bl[ks][t] = *(const bf16x8*)&Wu1l[bi];
            }
        f32x4 S[2];
        S[0] = (f32x4){0.f, 0.f, 0.f, 0.f};
        S[1] = (f32x4){0.f, 0.f, 0.f, 0.f};
#pragma unroll
        for (int c = 0; c < 3; c++) {
            f32x4 d[2];
            d[0] = (f32x4){0.f, 0.f, 0.f, 0.f};
            d[1] = (f32x4){0.f, 0.f, 0.f, 0.f};
            int abase = (1 + c) * (16 * 72);
#pragma unroll
            for (int ks = 0; ks < 2; ks++) {
                bf16x8 ah = *(const bf16x8*)&Ahi[abase + lcol * 72 + ks * 32 + kq];
                bf16x8 al = *(const bf16x8*)&Alo[abase + lcol * 72 + ks * 32 + kq];
#pragma unroll
                for (int t = 0; t < 2; t++) {
                    d[t] = __builtin_amdgcn_mfma_f32_16x16x32_bf16(ah, bh[ks][t], d[t], 0, 0, 0);
                    d[t] = __builtin_amdgcn_mfma_f32_16x16x32_bf16(ah, bl[ks][t], d[t], 0, 0, 0);
                    d[t] = __builtin_amdgcn_mfma_f32_16x16x32_bf16(al, bh[ks][t], d[t], 0, 0, 0);
                }
            }
            S[0] += d[0] * d[0];
            S[1] += d[1] * d[1];
        }
#pragma unroll
        for (int t = 0; t < 2; t++) {
            int col = w * 32 + t * 16 + lcol;
#pragma unroll
            for (int q = 0; q < 4; q++) {
                int n = n0 + quad * 4 + q;
                if (n < N) node[(size_t)n * 384 + 128 + col] = S[t][q];
            }
        }
    }

    // ---- G2: lh = sum_c ((ah_c @ Wuh))^2 ----
    {
        bf16x8 bh[2][2], bl[2][2];
#pragma unroll
        for (int ks = 0; ks < 2; ks++)
#pragma unroll
            for (int t = 0; t < 2; t++) {
                size_t bi = ((size_t)((ks * 8 + w * 2 + t) * 64 + lane)) * 8;
                bh[ks][t] = *(const bf16x8*)&Wuhh[bi];
                bl[ks][t] = *(const bf16x8*)&Wuhl[bi];
            }
        f32x4 S[2];
        S[0] = (f32x4){0.f, 0.f, 0.f, 0.f};
        S[1] = (f32x4){0.f, 0.f, 0.f, 0.f};
#pragma unroll
        for (int c = 0; c < 5; c++) {
            f32x4 d[2];
            d[0] = (f32x4){0.f, 0.f, 0.f, 0.f};
            d[1] = (f32x4){0.f, 0.f, 0.f, 0.f};
            int abase = (4 + c) * (16 * 72);
#pragma unroll
            for (int ks = 0; ks < 2; ks++) {
                bf16x8 ah = *(const bf16x8*)&Ahi[abase + lcol * 72 + ks * 32 + kq];
                bf16x8 al = *(const bf16x8*)&Alo[abase + lcol * 72 + ks * 32 + kq];
#pragma unroll
                for (int t = 0; t < 2; t++) {
                    d[t] = __builtin_amdgcn_mfma_f32_16x16x32_bf16(ah, bh[ks][t], d[t], 0, 0, 0);
                    d[t] = __builtin_amdgcn_mfma_f32_16x16x32_bf16(ah, bl[ks][t], d[t], 0, 0, 0);
                    d[t] = __builtin_amdgcn_mfma_f32_16x16x32_bf16(al, bh[ks][t], d[t], 0, 0, 0);
                }
            }
            S[0] += d[0] * d[0];
            S[1] += d[1] * d[1];
        }
#pragma unroll
        for (int t = 0; t < 2; t++) {
            int col = w * 32 + t * 16 + lcol;
#pragma unroll
            for (int q = 0; q < 4; q++) {
                int n = n0 + quad * 4 + q;
                if (n < N) node[(size_t)n * 384 + 256 + col] = S[t][q];
            }
        }
    }
}

// ---------------------------------------------------------------------------
// Stage C2: bf16 MFMA fused GEMM1+LN+SiLU+GEMM2 (unchanged, proven)
// ---------------------------------------------------------------------------
__global__ __launch_bounds__(256, 4) void k_final(
    const float* __restrict__ node, const unsigned short* __restrict__ Bsw1,
    const float* __restrict__ bn1, const float* __restrict__ lng,
    const float* __restrict__ lnb, const unsigned short* __restrict__ Bsw2,
    const float* __restrict__ bn2, const float* __restrict__ x,
    float* __restrict__ out, int N)
{
    __shared__ unsigned short Abf[32 * 392];   // GEMM1 A [32][384+8]; reused as GEMM2 A [32][256+8]
    __shared__ float red[32][33];
    __shared__ float red2[32][33];
    __shared__ float mstat[32][2];

    int n0 = blockIdx.x * 32;
    int tid = threadIdx.x;
    int lane = tid & 63;
    int w = tid >> 6;
    int rt = w & 1;
    int cg = w >> 1;
    int lcol = lane & 15;
    int quad = lane >> 4;
    int arow = rt * 16 + lcol;       // A-frag row this lane reads
    int kq = quad * 8;               // A/B-frag k sub-offset

    // ---- stage node tile as bf16 -> Abf[32][392] ----
    for (int i = tid; i < 32 * 192; i += 256) {
        int r = i / 192, c2 = i - r * 192;
        int n = n0 + r;
        float2 v;
        if (n < N) v = *(const float2*)&node[(size_t)n * 384 + 2 * c2];
        else { v.x = 0.f; v.y = 0.f; }
        *(unsigned*)&Abf[r * 392 + 2 * c2] = pack2(v.x, v.y);
    }
    __syncthreads();

    // ---- GEMM1: T = node @ Wn1 ----
    f32x4 acc[8];
#pragma unroll
    for (int t = 0; t < 8; t++) acc[t] = (f32x4){0.f, 0.f, 0.f, 0.f};
    for (int ks = 0; ks < 12; ks++) {
        bf16x8 a = *(const bf16x8*)&Abf[arow * 392 + ks * 32 + kq];
        const bf16x8* bp =
            (const bf16x8*)&Bsw1[(size_t)(((ks * 16 + cg * 8) * 64) + lane) * 8];
#pragma unroll
        for (int t = 0; t < 8; t++)
            acc[t] = __builtin_amdgcn_mfma_f32_16x16x32_bf16(a, bp[t * 64], acc[t], 0, 0, 0);
    }

    // ---- per-row LN stats from accumulators ----
    float bias[8];
#pragma unroll
    for (int t = 0; t < 8; t++) bias[t] = bn1[cg * 128 + t * 16 + lcol];
#pragma unroll
    for (int q = 0; q < 4; q++) {
        float s = 0.f, s2 = 0.f;
#pragma unroll
        for (int t = 0; t < 8; t++) {
            float v = acc[t][q] + bias[t];
            s += v; s2 += v * v;
        }
        int row = rt * 16 + quad * 4 + q;
        red[row][cg * 16 + lcol] = s;
        red2[row][cg * 16 + lcol] = s2;
    }
    __syncthreads();
    if (tid < 32) {
        float s = 0.f, s2 = 0.f;
#pragma unroll
        for (int u = 0; u < 32; u++) { s += red[tid][u]; s2 += red2[tid][u]; }
        float m = s * (1.f / 256.f);
        float var = s2 * (1.f / 256.f) - m * m;
        mstat[tid][0] = m;
        mstat[tid][1] = rsqrtf(var + 1e-5f);
    }
    __syncthreads();

    // ---- LN + SiLU, write h as bf16 GEMM2 A-tile [32][264] ----
#pragma unroll
    for (int t = 0; t < 8; t++) {
        int col = cg * 128 + t * 16 + lcol;
        float gg = lng[col], bb = lnb[col];
#pragma unroll
        for (int q = 0; q < 4; q++) {
            int row = rt * 16 + quad * 4 + q;
            float z = (acc[t][q] + bias[t] - mstat[row][0]) * mstat[row][1] * gg + bb;
            float h = z / (1.f + __expf(-z));
            Abf[row * 264 + col] = f2bf(h);
        }
    }
    __syncthreads();

    // ---- GEMM2: out = h @ Wn2 + bn2 + x ----
    f32x4 o[8];
#pragma unroll
    for (int t = 0; t < 8; t++) o[t] = (f32x4){0.f, 0.f, 0.f, 0.f};
    for (int ks = 0; ks < 8; ks++) {
        bf16x8 a = *(const bf16x8*)&Abf[arow * 264 + ks * 32 + kq];
        const bf16x8* bp =
            (const bf16x8*)&Bsw2[(size_t)(((ks * 16 + cg * 8) * 64) + lane) * 8];
#pragma unroll
        for (int t = 0; t < 8; t++)
            o[t] = __builtin_amdgcn_mfma_f32_16x16x32_bf16(a, bp[t * 64], o[t], 0, 0, 0);
    }
#pragma unroll
    for (int t = 0; t < 8; t++) {
        int col = cg * 128 + t * 16 + lcol;
        float ob = bn2[col];
#pragma unroll
        for (int q = 0; q < 4; q++) {
            int row = rt * 16 + quad * 4 + q;
            int n = n0 + row;
            if (n < N)
                out[(size_t)n * 256 + col] = o[t][q] + ob + x[(size_t)n * 256 + col];
        }
    }
}

// ---------------------------------------------------------------------------
extern "C" void kernel_launch(void* const* d_in, const int* in_sizes, int n_in,
                              void* d_out, int out_size, void* d_ws, size_t ws_size,
                              hipStream_t stream)
{
    const float* x      = (const float*)d_in[0];
    const float* rbf    = (const float*)d_in[1];
    const float* factor = (const float*)d_in[2];
    const float* sph0   = (const float*)d_in[3];
    const float* sph1   = (const float*)d_in[4];
    const float* Wd     = (const float*)d_in[5];
    const float* bd     = (const float*)d_in[6];
    const float* Wu0    = (const float*)d_in[7];
    const float* bu0    = (const float*)d_in[8];
    const float* Wu1    = (const float*)d_in[9];
    const float* Wuh    = (const float*)d_in[10];
    const float* Wn1    = (const float*)d_in[11];
    const float* bn1    = (const float*)d_in[12];
    const float* lng    = (const float*)d_in[13];
    const float* lnb    = (const float*)d_in[14];
    const float* Wn2    = (const float*)d_in[15];
    const float* bn2    = (const float*)d_in[16];
    const int*   jidx   = (const int*)d_in[17];
    const int*   iidx   = (const int*)d_in[18];
    float* out = (float*)d_out;

    int N = in_sizes[0] / 256;
    int E = in_sizes[17];

    float* ws   = (float*)d_ws;
    float* xp   = ws;                        // [N,64]
    float* agg0 = xp   + (size_t)N * 64;     // [N,64]
    float* agg1 = agg0 + (size_t)N * 64;     // [N,3,64]
    float* aggh = agg1 + (size_t)N * 192;    // [N,5,64]
    float* node = aggh + (size_t)N * 320;    // [N,384]
    // swizzled bf16 weights after node (one-time conversion per launch)
    unsigned short* Bsw1 = (unsigned short*)(node + (size_t)N * 384); // 12*16*64*8
    unsigned short* Bsw2 = Bsw1 + 12 * 16 * 64 * 8;                    // 8*16*64*8
    // hi/lo split-swizzled up-projection weights (each 64*128)
    unsigned short* Wu0h_s = Bsw2 + 8 * 16 * 64 * 8;
    unsigned short* Wu0l_s = Wu0h_s + 64 * 128;
    unsigned short* Wu1h_s = Wu0l_s + 64 * 128;
    unsigned short* Wu1l_s = Wu1h_s + 64 * 128;
    unsigned short* Wuhh_s = Wu1l_s + 64 * 128;
    unsigned short* Wuhl_s = Wuhh_s + 64 * 128;
    // R8: hi/lo split-swizzled W_down [256,64] (each 256*64)
    unsigned short* Wdh_s  = Wuhl_s + 64 * 128;
    unsigned short* Wdl_s  = Wdh_s + 256 * 64;

    // CSR scratch + packed edge records aliased onto the node buffer (dead
    // before k_node writes it).
    int* counts  = (int*)node;               // [N]
    int* rowptr  = counts + (N + 1);         // [N+1]
    int* cursor  = rowptr + (N + 1);         // [N]
    float* packed = node + 131072;           // [E,12] CSR-ordered edge records

    hipMemsetAsync(counts, 0, (size_t)(N + 1) * sizeof(int), stream);

    k_swz<<<dim3(48), dim3(256), 0, stream>>>(Wn1, Bsw1, 384);
    k_swz<<<dim3(32), dim3(256), 0, stream>>>(Wn2, Bsw2, 256);
    k_swz_split<<<dim3(4), dim3(256), 0, stream>>>(Wu0, Wu0h_s, Wu0l_s, 64, 128);
    k_swz_split<<<dim3(4), dim3(256), 0, stream>>>(Wu1, Wu1h_s, Wu1l_s, 64, 128);
    k_swz_split<<<dim3(4), dim3(256), 0, stream>>>(Wuh, Wuhh_s, Wuhl_s, 64, 128);
    k_swz_split<<<dim3(8), dim3(256), 0, stream>>>(Wd, Wdh_s, Wdl_s, 256, 64);
    k_down<<<dim3((N + 31) / 32), dim3(256), 0, stream>>>(
        x, Wdh_s, Wdl_s, bd, xp, N);
    k_hist<<<dim3((E + 255) / 256), dim3(256), 0, stream>>>(iidx, counts, E);
    k_scan<<<dim3(1), dim3(1024), 0, stream>>>(counts, rowptr, cursor, N);
    k_scatter_pack<<<dim3((E + 255) / 256), dim3(256), 0, stream>>>(
        iidx, jidx, factor, sph0, sph1, cursor, packed, E);
    k_gather<<<dim3((N + 3) / 4), dim3(256), 0, stream>>>(
        xp, rbf, packed, rowptr, agg0, agg1, aggh, N);
    k_node<<<dim3((N + 15) / 16), dim3(256), 0, stream>>>(
        xp, agg0, agg1, aggh, Wu0h_s, Wu0l_s, Wu1h_s, Wu1l_s, Wuhh_s, Wuhl_s,
        bu0, node, N);
    k_final<<<dim3((N + 31) / 32), dim3(256), 0, stream>>>(
        node, Bsw1, bn1, lng, lnb, Bsw2, bn2, x, out, N);
}

// Round 5
// 496.141 us; speedup vs baseline: 1.6070x; 1.0278x over previous
//
#include <hip/hip_runtime.h>
#include <hip/hip_bf16.h>

typedef __attribute__((ext_vector_type(8))) short bf16x8;
typedef __attribute__((ext_vector_type(4))) float f32x4;

__device__ __forceinline__ unsigned short f2bf(float f) {
    unsigned u = __float_as_uint(f);
    return (unsigned short)((u + 0x7FFF + ((u >> 16) & 1)) >> 16);  // RNE
}
__device__ __forceinline__ unsigned pack2(float a, float b) {
    return (unsigned)f2bf(a) | ((unsigned)f2bf(b) << 16);
}
__device__ __forceinline__ float ubf(unsigned short h) {
    return __uint_as_float((unsigned)h << 16);
}
// register broadcast: lane k (uniform) -> all lanes, result in SGPR
__device__ __forceinline__ int RLi(float v, int k) {
    return __builtin_amdgcn_readlane(__float_as_int(v), k);
}
__device__ __forceinline__ float RLf(float v, int k) {
    return __uint_as_float((unsigned)__builtin_amdgcn_readlane(__float_as_int(v), k));
}

// ---------------------------------------------------------------------------
// k_prep: all one-time weight swizzles + counts zeroing in ONE launch.
// blocks 0-47: Wn1 swz; 48-79: Wn2 swz; 80-83: Wu0 split; 84-87: Wu1 split;
// 88-91: Wuh split; 92-99: Wd split; 100-124: zero counts.
// All writes disjoint; pure input->output. (Proven-safe consolidation of the
// R3 swz launches + memset.)
// ---------------------------------------------------------------------------
__device__ void swz_body(const float* __restrict__ W,
                         unsigned short* __restrict__ Bsw, int K, int idx)
{
    int total = (K >> 5) * 1024;            // (K/32) * 16 ct * 64 lanes
    if (idx >= total) return;
    int lane = idx & 63;
    int ct = (idx >> 6) & 15;
    int ks = idx >> 10;
    int col = ct * 16 + (lane & 15);
    int kbase = (ks << 5) + ((lane >> 4) << 3);
    const float* p = &W[(size_t)kbase * 256 + col];
    uint4 o;
    o.x = pack2(p[0 * 256], p[1 * 256]);
    o.y = pack2(p[2 * 256], p[3 * 256]);
    o.z = pack2(p[4 * 256], p[5 * 256]);
    o.w = pack2(p[6 * 256], p[7 * 256]);
    *(uint4*)&Bsw[(size_t)idx * 8] = o;
}

__device__ void swz_split_body(const float* __restrict__ W,
                               unsigned short* __restrict__ Bh,
                               unsigned short* __restrict__ Bl,
                               int K, int C, int idx)
{
    int ct_n = C >> 4;
    int total = (K >> 5) * ct_n * 64;
    if (idx >= total) return;
    int per_ks = ct_n * 64;
    int ks = idx / per_ks;
    int rem = idx - ks * per_ks;
    int ct = rem >> 6;
    int lane = rem & 63;
    int col = ct * 16 + (lane & 15);
    int kbase = (ks << 5) + ((lane >> 4) << 3);
    const float* p = &W[(size_t)kbase * C + col];
    unsigned short hs[8], ls[8];
#pragma unroll
    for (int j = 0; j < 8; j++) {
        float wv = p[(size_t)j * C];
        unsigned short h = f2bf(wv);
        hs[j] = h;
        ls[j] = f2bf(wv - ubf(h));
    }
    uint4 oh, ol;
    oh.x = (unsigned)hs[0] | ((unsigned)hs[1] << 16);
    oh.y = (unsigned)hs[2] | ((unsigned)hs[3] << 16);
    oh.z = (unsigned)hs[4] | ((unsigned)hs[5] << 16);
    oh.w = (unsigned)hs[6] | ((unsigned)hs[7] << 16);
    ol.x = (unsigned)ls[0] | ((unsigned)ls[1] << 16);
    ol.y = (unsigned)ls[2] | ((unsigned)ls[3] << 16);
    ol.z = (unsigned)ls[4] | ((unsigned)ls[5] << 16);
    ol.w = (unsigned)ls[6] | ((unsigned)ls[7] << 16);
    *(uint4*)&Bh[(size_t)idx * 8] = oh;
    *(uint4*)&Bl[(size_t)idx * 8] = ol;
}

__global__ __launch_bounds__(256) void k_prep(
    const float* __restrict__ Wn1, unsigned short* __restrict__ Bsw1,
    const float* __restrict__ Wn2, unsigned short* __restrict__ Bsw2,
    const float* __restrict__ Wu0, unsigned short* __restrict__ Wu0h, unsigned short* __restrict__ Wu0l,
    const float* __restrict__ Wu1, unsigned short* __restrict__ Wu1h, unsigned short* __restrict__ Wu1l,
    const float* __restrict__ Wuh, unsigned short* __restrict__ Wuhh, unsigned short* __restrict__ Wuhl,
    const float* __restrict__ Wd, unsigned short* __restrict__ Wdh, unsigned short* __restrict__ Wdl,
    int* __restrict__ counts, int N)
{
    int b = blockIdx.x;
    int tid = threadIdx.x;
    if (b < 48)       swz_body(Wn1, Bsw1, 384, b * 256 + tid);
    else if (b < 80)  swz_body(Wn2, Bsw2, 256, (b - 48) * 256 + tid);
    else if (b < 84)  swz_split_body(Wu0, Wu0h, Wu0l, 64, 128, (b - 80) * 256 + tid);
    else if (b < 88)  swz_split_body(Wu1, Wu1h, Wu1l, 64, 128, (b - 84) * 256 + tid);
    else if (b < 92)  swz_split_body(Wuh, Wuhh, Wuhl, 64, 128, (b - 88) * 256 + tid);
    else if (b < 100) swz_split_body(Wd, Wdh, Wdl, 256, 64, (b - 92) * 256 + tid);
    else {
        for (int i = (b - 100) * 256 + tid; i < N + 1; i += 25 * 256)
            counts[i] = 0;
    }
}

// ---------------------------------------------------------------------------
// Stage A: _x = x @ W_down + b_down via hi/lo split bf16 MFMA (proven R8)
// ---------------------------------------------------------------------------
__global__ __launch_bounds__(256, 4) void k_down(
    const float* __restrict__ x, const unsigned short* __restrict__ Wdh,
    const unsigned short* __restrict__ Wdl, const float* __restrict__ bd,
    float* __restrict__ xp, int N)
{
    __shared__ __align__(16) unsigned short Ahi[32 * 264];
    __shared__ __align__(16) unsigned short Alo[32 * 264];

    int n0 = blockIdx.x * 32;
    int tid = threadIdx.x;
    int lane = tid & 63;
    int w = tid >> 6;
    int rt = w & 1;
    int cg = w >> 1;
    int lcol = lane & 15;
    int quad = lane >> 4;
    int kq = quad * 8;

    for (int t = tid; t < 32 * 64; t += 256) {
        int r = t >> 6, c4 = t & 63;
        int n = n0 + r;
        float4 v = {0.f, 0.f, 0.f, 0.f};
        if (n < N) v = *(const float4*)&x[(size_t)n * 256 + c4 * 4];
        unsigned short hx = f2bf(v.x), hy = f2bf(v.y);
        unsigned short hz = f2bf(v.z), hw = f2bf(v.w);
        uint2 oh, ol;
        oh.x = (unsigned)hx | ((unsigned)hy << 16);
        oh.y = (unsigned)hz | ((unsigned)hw << 16);
        ol.x = (unsigned)f2bf(v.x - ubf(hx)) | ((unsigned)f2bf(v.y - ubf(hy)) << 16);
        ol.y = (unsigned)f2bf(v.z - ubf(hz)) | ((unsigned)f2bf(v.w - ubf(hw)) << 16);
        *(uint2*)&Ahi[r * 264 + c4 * 4] = oh;
        *(uint2*)&Alo[r * 264 + c4 * 4] = ol;
    }
    __syncthreads();

    int arow = rt * 16 + lcol;
    f32x4 acc[2];
    acc[0] = (f32x4){0.f, 0.f, 0.f, 0.f};
    acc[1] = (f32x4){0.f, 0.f, 0.f, 0.f};
#pragma unroll
    for (int ks = 0; ks < 8; ks++) {
        bf16x8 ah = *(const bf16x8*)&Ahi[arow * 264 + ks * 32 + kq];
        bf16x8 al = *(const bf16x8*)&Alo[arow * 264 + ks * 32 + kq];
#pragma unroll
        for (int t = 0; t < 2; t++) {
            int ct = cg * 2 + t;
            size_t bi = ((size_t)((ks * 4 + ct) * 64 + lane)) * 8;
            bf16x8 bh = *(const bf16x8*)&Wdh[bi];
            bf16x8 bl = *(const bf16x8*)&Wdl[bi];
            acc[t] = __builtin_amdgcn_mfma_f32_16x16x32_bf16(ah, bh, acc[t], 0, 0, 0);
            acc[t] = __builtin_amdgcn_mfma_f32_16x16x32_bf16(ah, bl, acc[t], 0, 0, 0);
            acc[t] = __builtin_amdgcn_mfma_f32_16x16x32_bf16(al, bh, acc[t], 0, 0, 0);
        }
    }
#pragma unroll
    for (int t = 0; t < 2; t++) {
        int col = cg * 32 + t * 16 + lcol;
        float bb = bd[col];
#pragma unroll
        for (int q = 0; q < 4; q++) {
            int row = rt * 16 + quad * 4 + q;
            int n = n0 + row;
            if (n < N) xp[(size_t)n * 64 + col] = acc[t][q] + bb;
        }
    }
}

// ---------------------------------------------------------------------------
// Stage B: CSR build; scatter packs per-edge record into CSR order:
// 12 floats/edge {e, j, factor, s1x, s1y, s1z, h0..h4, pad}.
// ---------------------------------------------------------------------------
__global__ __launch_bounds__(256) void k_hist(
    const int* __restrict__ iidx, int* __restrict__ counts, int E)
{
    int e = blockIdx.x * 256 + threadIdx.x;
    if (e < E) atomicAdd(&counts[iidx[e]], 1);
}

__global__ __launch_bounds__(1024) void k_scan(
    const int* __restrict__ counts, int* __restrict__ rowptr,
    int* __restrict__ cursor, int N)
{
    __shared__ int part[1024];
    int t = threadIdx.x;
    int chunk = (N + 1023) / 1024;
    int beg = t * chunk;
    int end = min(beg + chunk, N);
    int s = 0;
    for (int i = beg; i < end; i++) s += counts[i];
    part[t] = s;
    __syncthreads();
    for (int off = 1; off < 1024; off <<= 1) {
        int v = (t >= off) ? part[t - off] : 0;
        __syncthreads();
        part[t] += v;
        __syncthreads();
    }
    int run = (t == 0) ? 0 : part[t - 1];
    for (int i = beg; i < end; i++) {
        rowptr[i] = run;
        cursor[i] = run;
        run += counts[i];
    }
    if (t == 1023) rowptr[N] = part[1023];
}

__global__ __launch_bounds__(256) void k_scatter_pack(
    const int* __restrict__ iidx, const int* __restrict__ jidx,
    const float* __restrict__ factor, const float* __restrict__ sph0,
    const float* __restrict__ sph1, int* __restrict__ cursor,
    float* __restrict__ packed, int E)
{
    int e = blockIdx.x * 256 + threadIdx.x;
    if (e >= E) return;
    int pos = atomicAdd(&cursor[iidx[e]], 1);
    float4 w0, w1, w2;
    w0.x = __int_as_float(e);
    w0.y = __int_as_float(jidx[e]);
    w0.z = factor[e];
    w0.w = sph1[e * 3 + 0];
    w1.x = sph1[e * 3 + 1];
    w1.y = sph1[e * 3 + 2];
    w1.z = sph0[e * 5 + 0];
    w1.w = sph0[e * 5 + 1];
    w2.x = sph0[e * 5 + 2];
    w2.y = sph0[e * 5 + 3];
    w2.z = sph0[e * 5 + 4];
    w2.w = 0.f;
    float4* q = (float4*)&packed[(size_t)pos * 12];
    q[0] = w0; q[1] = w1; q[2] = w2;
}

// ---------------------------------------------------------------------------
// k_gather: one wave per node; coalesced packed-record staging + readlane
// broadcast (proven R7).
// ---------------------------------------------------------------------------
__global__ __launch_bounds__(256) void k_gather(
    const float* __restrict__ xp, const float* __restrict__ rbf,
    const float* __restrict__ packed, const int* __restrict__ rowptr,
    float* __restrict__ agg0, float* __restrict__ agg1,
    float* __restrict__ aggh, int N)
{
    int n = blockIdx.x * 4 + (threadIdx.x >> 6);
    if (n >= N) return;
    int p = threadIdx.x & 63;
    int beg = rowptr[n], end = rowptr[n + 1];

    float a0 = 0.f;
    float a1x = 0.f, a1y = 0.f, a1z = 0.f;
    float h0 = 0.f, h1 = 0.f, h2 = 0.f, h3 = 0.f, h4 = 0.f;

    for (int base = beg; base < end; base += 64) {
        int m = end - base;
        if (m > 64) m = 64;
        float4 w0 = {0.f, 0.f, 0.f, 0.f};
        float4 w1 = {0.f, 0.f, 0.f, 0.f};
        float4 w2 = {0.f, 0.f, 0.f, 0.f};
        if (base + p < end) {
            const float4* q = (const float4*)&packed[(size_t)(base + p) * 12];
            w0 = q[0]; w1 = q[1]; w2 = q[2];
        }
        int k = 0;
        for (; k + 3 < m; k += 4) {
            int e0 = RLi(w0.x, k),     e1 = RLi(w0.x, k + 1);
            int e2 = RLi(w0.x, k + 2), e3 = RLi(w0.x, k + 3);
            int j0 = RLi(w0.y, k),     j1 = RLi(w0.y, k + 1);
            int j2 = RLi(w0.y, k + 2), j3 = RLi(w0.y, k + 3);
            float x0 = xp[(size_t)j0 * 64 + p], r0 = rbf[(size_t)e0 * 64 + p];
            float x1 = xp[(size_t)j1 * 64 + p], r1 = rbf[(size_t)e1 * 64 + p];
            float x2 = xp[(size_t)j2 * 64 + p], r2 = rbf[(size_t)e2 * 64 + p];
            float x3 = xp[(size_t)j3 * 64 + p], r3 = rbf[(size_t)e3 * 64 + p];
            float f0 = RLf(w0.z, k),     f1 = RLf(w0.z, k + 1);
            float f2 = RLf(w0.z, k + 2), f3 = RLf(w0.z, k + 3);
            float v0 = x0 * r0 * f0, v1 = x1 * r1 * f1;
            float v2 = x2 * r2 * f2, v3 = x3 * r3 * f3;
            a0 += (v0 + v1) + (v2 + v3);
            a1x += v0 * RLf(w0.w, k)     + v1 * RLf(w0.w, k + 1)
                 + v2 * RLf(w0.w, k + 2) + v3 * RLf(w0.w, k + 3);
            a1y += v0 * RLf(w1.x, k)     + v1 * RLf(w1.x, k + 1)
                 + v2 * RLf(w1.x, k + 2) + v3 * RLf(w1.x, k + 3);
            a1z += v0 * RLf(w1.y, k)     + v1 * RLf(w1.y, k + 1)
                 + v2 * RLf(w1.y, k + 2) + v3 * RLf(w1.y, k + 3);
            h0  += v0 * RLf(w1.z, k)     + v1 * RLf(w1.z, k + 1)
                 + v2 * RLf(w1.z, k + 2) + v3 * RLf(w1.z, k + 3);
            h1  += v0 * RLf(w1.w, k)     + v1 * RLf(w1.w, k + 1)
                 + v2 * RLf(w1.w, k + 2) + v3 * RLf(w1.w, k + 3);
            h2  += v0 * RLf(w2.x, k)     + v1 * RLf(w2.x, k + 1)
                 + v2 * RLf(w2.x, k + 2) + v3 * RLf(w2.x, k + 3);
            h3  += v0 * RLf(w2.y, k)     + v1 * RLf(w2.y, k + 1)
                 + v2 * RLf(w2.y, k + 2) + v3 * RLf(w2.y, k + 3);
            h4  += v0 * RLf(w2.z, k)     + v1 * RLf(w2.z, k + 1)
                 + v2 * RLf(w2.z, k + 2) + v3 * RLf(w2.z, k + 3);
        }
        for (; k < m; k++) {
            int e0 = RLi(w0.x, k);
            int j0 = RLi(w0.y, k);
            float f0 = RLf(w0.z, k);
            float v0 = xp[(size_t)j0 * 64 + p] * rbf[(size_t)e0 * 64 + p] * f0;
            a0 += v0;
            a1x += v0 * RLf(w0.w, k);
            a1y += v0 * RLf(w1.x, k);
            a1z += v0 * RLf(w1.y, k);
            h0  += v0 * RLf(w1.z, k);
            h1  += v0 * RLf(w1.w, k);
            h2  += v0 * RLf(w2.x, k);
            h3  += v0 * RLf(w2.y, k);
            h4  += v0 * RLf(w2.z, k);
        }
    }

    agg0[(size_t)n * 64 + p] = a0;
    agg1[((size_t)n * 3 + 0) * 64 + p] = a1x;
    agg1[((size_t)n * 3 + 1) * 64 + p] = a1y;
    agg1[((size_t)n * 3 + 2) * 64 + p] = a1z;
    aggh[((size_t)n * 5 + 0) * 64 + p] = h0;
    aggh[((size_t)n * 5 + 1) * 64 + p] = h1;
    aggh[((size_t)n * 5 + 2) * 64 + p] = h2;
    aggh[((size_t)n * 5 + 3) * 64 + p] = h3;
    aggh[((size_t)n * 5 + 4) * 64 + p] = h4;
}

// ---------------------------------------------------------------------------
// Stage C1: node features via MFMA with hi/lo bf16 split (proven R6)
// ---------------------------------------------------------------------------
__global__ __launch_bounds__(256, 3) void k_node(
    const float* __restrict__ xp, const float* __restrict__ agg0,
    const float* __restrict__ agg1, const float* __restrict__ aggh,
    const unsigned short* __restrict__ Wu0h, const unsigned short* __restrict__ Wu0l,
    const unsigned short* __restrict__ Wu1h, const unsigned short* __restrict__ Wu1l,
    const unsigned short* __restrict__ Wuhh, const unsigned short* __restrict__ Wuhl,
    const float* __restrict__ bu0, float* __restrict__ node, int N)
{
    __shared__ float xs[16 * 64];
    __shared__ __align__(16) unsigned short Ahi[9 * 16 * 72];
    __shared__ __align__(16) unsigned short Alo[9 * 16 * 72];

    int n0 = blockIdx.x * 16;
    int tid = threadIdx.x;
    int lane = tid & 63;
    int w = tid >> 6;          // wave -> col group
    int lcol = lane & 15;
    int quad = lane >> 4;
    int kq = quad * 8;

    // stage xp tile
    for (int t = tid; t < 16 * 64; t += 256) {
        int n = n0 + (t >> 6);
        xs[t] = (n < N) ? xp[(size_t)n * 64 + (t & 63)] : 0.f;
    }
    __syncthreads();

    // build 9 hi/lo A-tiles: m=0: xs*agg0; m=1..3: xs*agg1[c]; m=4..8: xs*aggh[c]
    for (int t = tid; t < 9 * 1024; t += 256) {
        int m = t >> 10;
        int rem = t & 1023;
        int r = rem >> 6, c = rem & 63;
        int n = n0 + r;
        float v = 0.f;
        if (n < N) {
            float xv = xs[rem];
            if (m == 0)      v = xv * agg0[(size_t)n * 64 + c];
            else if (m < 4)  v = xv * agg1[((size_t)n * 3 + (m - 1)) * 64 + c];
            else             v = xv * aggh[((size_t)n * 5 + (m - 4)) * 64 + c];
        }
        unsigned short h = f2bf(v);
        float fh = __uint_as_float((unsigned)h << 16);
        Ahi[(m * 16 + r) * 72 + c] = h;
        Alo[(m * 16 + r) * 72 + c] = f2bf(v - fh);
    }
    __syncthreads();

    // ---- G0: l0 = a0 @ Wu0 + bu0 ----
    {
        bf16x8 bh[2][2], bl[2][2];
#pragma unroll
        for (int ks = 0; ks < 2; ks++)
#pragma unroll
            for (int t = 0; t < 2; t++) {
                size_t bi = ((size_t)((ks * 8 + w * 2 + t) * 64 + lane)) * 8;
                bh[ks][t] = *(const bf16x8*)&Wu0h[bi];
                bl[ks][t] = *(const bf16x8*)&Wu0l[bi];
            }
        f32x4 acc[2];
        acc[0] = (f32x4){0.f, 0.f, 0.f, 0.f};
        acc[1] = (f32x4){0.f, 0.f, 0.f, 0.f};
#pragma unroll
        for (int ks = 0; ks < 2; ks++) {
            bf16x8 ah = *(const bf16x8*)&Ahi[lcol * 72 + ks * 32 + kq];
            bf16x8 al = *(const bf16x8*)&Alo[lcol * 72 + ks * 32 + kq];
#pragma unroll
            for (int t = 0; t < 2; t++) {
                acc[t] = __builtin_amdgcn_mfma_f32_16x16x32_bf16(ah, bh[ks][t], acc[t], 0, 0, 0);
                acc[t] = __builtin_amdgcn_mfma_f32_16x16x32_bf16(ah, bl[ks][t], acc[t], 0, 0, 0);
                acc[t] = __builtin_amdgcn_mfma_f32_16x16x32_bf16(al, bh[ks][t], acc[t], 0, 0, 0);
            }
        }
#pragma unroll
        for (int t = 0; t < 2; t++) {
            int col = w * 32 + t * 16 + lcol;
            float bb = bu0[col];
#pragma unroll
            for (int q = 0; q < 4; q++) {
                int n = n0 + quad * 4 + q;
                if (n < N) node[(size_t)n * 384 + col] = acc[t][q] + bb;
            }
        }
    }

    // ---- G1: l1 = sum_c ((a1_c @ Wu1))^2 ----
    {
        bf16x8 bh[2][2], bl[2][2];
#pragma unroll
        for (int ks = 0; ks < 2; ks++)
#pragma unroll
            for (int t = 0; t < 2; t++) {
                size_t bi = ((size_t)((ks * 8 + w * 2 + t) * 64 + lane)) * 8;
                bh[ks][t] = *(const bf16x8*)&Wu1h[bi];
                bl[ks][t] = *(const bf16x8*)&Wu1l[bi];
            }
        f32x4 S[2];
        S[0] = (f32x4){0.f, 0.f, 0.f, 0.f};
        S[1] = (f32x4){0.f, 0.f, 0.f, 0.f};
#pragma unroll
        for (int c = 0; c < 3; c++) {
            f32x4 d[2];
            d[0] = (f32x4){0.f, 0.f, 0.f, 0.f};
            d[1] = (f32x4){0.f, 0.f, 0.f, 0.f};
            int abase = (1 + c) * (16 * 72);
#pragma unroll
            for (int ks = 0; ks < 2; ks++) {
                bf16x8 ah = *(const bf16x8*)&Ahi[abase + lcol * 72 + ks * 32 + kq];
                bf16x8 al = *(const bf16x8*)&Alo[abase + lcol * 72 + ks * 32 + kq];
#pragma unroll
                for (int t = 0; t < 2; t++) {
                    d[t] = __builtin_amdgcn_mfma_f32_16x16x32_bf16(ah, bh[ks][t], d[t], 0, 0, 0);
                    d[t] = __builtin_amdgcn_mfma_f32_16x16x32_bf16(ah, bl[ks][t], d[t], 0, 0, 0);
                    d[t] = __builtin_amdgcn_mfma_f32_16x16x32_bf16(al, bh[ks][t], d[t], 0, 0, 0);
                }
            }
            S[0] += d[0] * d[0];
            S[1] += d[1] * d[1];
        }
#pragma unroll
        for (int t = 0; t < 2; t++) {
            int col = w * 32 + t * 16 + lcol;
#pragma unroll
            for (int q = 0; q < 4; q++) {
                int n = n0 + quad * 4 + q;
                if (n < N) node[(size_t)n * 384 + 128 + col] = S[t][q];
            }
        }
    }

    // ---- G2: lh = sum_c ((ah_c @ Wuh))^2 ----
    {
        bf16x8 bh[2][2], bl[2][2];
#pragma unroll
        for (int ks = 0; ks < 2; ks++)
#pragma unroll
            for (int t = 0; t < 2; t++) {
                size_t bi = ((size_t)((ks * 8 + w * 2 + t) * 64 + lane)) * 8;
                bh[ks][t] = *(const bf16x8*)&Wuhh[bi];
                bl[ks][t] = *(const bf16x8*)&Wuhl[bi];
            }
        f32x4 S[2];
        S[0] = (f32x4){0.f, 0.f, 0.f, 0.f};
        S[1] = (f32x4){0.f, 0.f, 0.f, 0.f};
#pragma unroll
        for (int c = 0; c < 5; c++) {
            f32x4 d[2];
            d[0] = (f32x4){0.f, 0.f, 0.f, 0.f};
            d[1] = (f32x4){0.f, 0.f, 0.f, 0.f};
            int abase = (4 + c) * (16 * 72);
#pragma unroll
            for (int ks = 0; ks < 2; ks++) {
                bf16x8 ah = *(const bf16x8*)&Ahi[abase + lcol * 72 + ks * 32 + kq];
                bf16x8 al = *(const bf16x8*)&Alo[abase + lcol * 72 + ks * 32 + kq];
#pragma unroll
                for (int t = 0; t < 2; t++) {
                    d[t] = __builtin_amdgcn_mfma_f32_16x16x32_bf16(ah, bh[ks][t], d[t], 0, 0, 0);
                    d[t] = __builtin_amdgcn_mfma_f32_16x16x32_bf16(ah, bl[ks][t], d[t], 0, 0, 0);
                    d[t] = __builtin_amdgcn_mfma_f32_16x16x32_bf16(al, bh[ks][t], d[t], 0, 0, 0);
                }
            }
            S[0] += d[0] * d[0];
            S[1] += d[1] * d[1];
        }
#pragma unroll
        for (int t = 0; t < 2; t++) {
            int col = w * 32 + t * 16 + lcol;
#pragma unroll
            for (int q = 0; q < 4; q++) {
                int n = n0 + quad * 4 + q;
                if (n < N) node[(size_t)n * 384 + 256 + col] = S[t][q];
            }
        }
    }
}

// ---------------------------------------------------------------------------
// Stage C2: bf16 MFMA fused GEMM1+LN+SiLU+GEMM2 (unchanged, proven)
// ---------------------------------------------------------------------------
__global__ __launch_bounds__(256, 4) void k_final(
    const float* __restrict__ node, const unsigned short* __restrict__ Bsw1,
    const float* __restrict__ bn1, const float* __restrict__ lng,
    const float* __restrict__ lnb, const unsigned short* __restrict__ Bsw2,
    const float* __restrict__ bn2, const float* __restrict__ x,
    float* __restrict__ out, int N)
{
    __shared__ unsigned short Abf[32 * 392];   // GEMM1 A [32][384+8]; reused as GEMM2 A [32][256+8]
    __shared__ float red[32][33];
    __shared__ float red2[32][33];
    __shared__ float mstat[32][2];

    int n0 = blockIdx.x * 32;
    int tid = threadIdx.x;
    int lane = tid & 63;
    int w = tid >> 6;
    int rt = w & 1;
    int cg = w >> 1;
    int lcol = lane & 15;
    int quad = lane >> 4;
    int arow = rt * 16 + lcol;       // A-frag row this lane reads
    int kq = quad * 8;               // A/B-frag k sub-offset

    // ---- stage node tile as bf16 -> Abf[32][392] ----
    for (int i = tid; i < 32 * 192; i += 256) {
        int r = i / 192, c2 = i - r * 192;
        int n = n0 + r;
        float2 v;
        if (n < N) v = *(const float2*)&node[(size_t)n * 384 + 2 * c2];
        else { v.x = 0.f; v.y = 0.f; }
        *(unsigned*)&Abf[r * 392 + 2 * c2] = pack2(v.x, v.y);
    }
    __syncthreads();

    // ---- GEMM1: T = node @ Wn1 ----
    f32x4 acc[8];
#pragma unroll
    for (int t = 0; t < 8; t++) acc[t] = (f32x4){0.f, 0.f, 0.f, 0.f};
    for (int ks = 0; ks < 12; ks++) {
        bf16x8 a = *(const bf16x8*)&Abf[arow * 392 + ks * 32 + kq];
        const bf16x8* bp =
            (const bf16x8*)&Bsw1[(size_t)(((ks * 16 + cg * 8) * 64) + lane) * 8];
#pragma unroll
        for (int t = 0; t < 8; t++)
            acc[t] = __builtin_amdgcn_mfma_f32_16x16x32_bf16(a, bp[t * 64], acc[t], 0, 0, 0);
    }

    // ---- per-row LN stats from accumulators ----
    float bias[8];
#pragma unroll
    for (int t = 0; t < 8; t++) bias[t] = bn1[cg * 128 + t * 16 + lcol];
#pragma unroll
    for (int q = 0; q < 4; q++) {
        float s = 0.f, s2 = 0.f;
#pragma unroll
        for (int t = 0; t < 8; t++) {
            float v = acc[t][q] + bias[t];
            s += v; s2 += v * v;
        }
        int row = rt * 16 + quad * 4 + q;
        red[row][cg * 16 + lcol] = s;
        red2[row][cg * 16 + lcol] = s2;
    }
    __syncthreads();
    if (tid < 32) {
        float s = 0.f, s2 = 0.f;
#pragma unroll
        for (int u = 0; u < 32; u++) { s += red[tid][u]; s2 += red2[tid][u]; }
        float m = s * (1.f / 256.f);
        float var = s2 * (1.f / 256.f) - m * m;
        mstat[tid][0] = m;
        mstat[tid][1] = rsqrtf(var + 1e-5f);
    }
    __syncthreads();

    // ---- LN + SiLU, write h as bf16 GEMM2 A-tile [32][264] ----
#pragma unroll
    for (int t = 0; t < 8; t++) {
        int col = cg * 128 + t * 16 + lcol;
        float gg = lng[col], bb = lnb[col];
#pragma unroll
        for (int q = 0; q < 4; q++) {
            int row = rt * 16 + quad * 4 + q;
            float z = (acc[t][q] + bias[t] - mstat[row][0]) * mstat[row][1] * gg + bb;
            float h = z / (1.f + __expf(-z));
            Abf[row * 264 + col] = f2bf(h);
        }
    }
    __syncthreads();

    // ---- GEMM2: out = h @ Wn2 + bn2 + x ----
    f32x4 o[8];
#pragma unroll
    for (int t = 0; t < 8; t++) o[t] = (f32x4){0.f, 0.f, 0.f, 0.f};
    for (int ks = 0; ks < 8; ks++) {
        bf16x8 a = *(const bf16x8*)&Abf[arow * 264 + ks * 32 + kq];
        const bf16x8* bp =
            (const bf16x8*)&Bsw2[(size_t)(((ks * 16 + cg * 8) * 64) + lane) * 8];
#pragma unroll
        for (int t = 0; t < 8; t++)
            o[t] = __builtin_amdgcn_mfma_f32_16x16x32_bf16(a, bp[t * 64], o[t], 0, 0, 0);
    }
#pragma unroll
    for (int t = 0; t < 8; t++) {
        int col = cg * 128 + t * 16 + lcol;
        float ob = bn2[col];
#pragma unroll
        for (int q = 0; q < 4; q++) {
            int row = rt * 16 + quad * 4 + q;
            int n = n0 + row;
            if (n < N)
                out[(size_t)n * 256 + col] = o[t][q] + ob + x[(size_t)n * 256 + col];
        }
    }
}

// ---------------------------------------------------------------------------
extern "C" void kernel_launch(void* const* d_in, const int* in_sizes, int n_in,
                              void* d_out, int out_size, void* d_ws, size_t ws_size,
                              hipStream_t stream)
{
    const float* x      = (const float*)d_in[0];
    const float* rbf    = (const float*)d_in[1];
    const float* factor = (const float*)d_in[2];
    const float* sph0   = (const float*)d_in[3];
    const float* sph1   = (const float*)d_in[4];
    const float* Wd     = (const float*)d_in[5];
    const float* bd     = (const float*)d_in[6];
    const float* Wu0    = (const float*)d_in[7];
    const float* bu0    = (const float*)d_in[8];
    const float* Wu1    = (const float*)d_in[9];
    const float* Wuh    = (const float*)d_in[10];
    const float* Wn1    = (const float*)d_in[11];
    const float* bn1    = (const float*)d_in[12];
    const float* lng    = (const float*)d_in[13];
    const float* lnb    = (const float*)d_in[14];
    const float* Wn2    = (const float*)d_in[15];
    const float* bn2    = (const float*)d_in[16];
    const int*   jidx   = (const int*)d_in[17];
    const int*   iidx   = (const int*)d_in[18];
    float* out = (float*)d_out;

    int N = in_sizes[0] / 256;
    int E = in_sizes[17];

    float* ws   = (float*)d_ws;
    float* xp   = ws;                        // [N,64]
    float* agg0 = xp   + (size_t)N * 64;     // [N,64]
    float* agg1 = agg0 + (size_t)N * 64;     // [N,3,64]
    float* aggh = agg1 + (size_t)N * 192;    // [N,5,64]
    float* node = aggh + (size_t)N * 320;    // [N,384]
    // swizzled bf16 weights after node (one-time conversion per launch)
    unsigned short* Bsw1 = (unsigned short*)(node + (size_t)N * 384); // 12*16*64*8
    unsigned short* Bsw2 = Bsw1 + 12 * 16 * 64 * 8;                    // 8*16*64*8
    unsigned short* Wu0h_s = Bsw2 + 8 * 16 * 64 * 8;
    unsigned short* Wu0l_s = Wu0h_s + 64 * 128;
    unsigned short* Wu1h_s = Wu0l_s + 64 * 128;
    unsigned short* Wu1l_s = Wu1h_s + 64 * 128;
    unsigned short* Wuhh_s = Wu1l_s + 64 * 128;
    unsigned short* Wuhl_s = Wuhh_s + 64 * 128;
    unsigned short* Wdh_s  = Wuhl_s + 64 * 128;
    unsigned short* Wdl_s  = Wdh_s + 256 * 64;

    // CSR scratch + packed edge records aliased onto the node buffer (dead
    // before k_node writes it; k_gather fully consumes packed before k_node).
    int* counts  = (int*)node;               // [N+1]
    int* rowptr  = counts + (N + 1);         // [N+1]
    int* cursor  = rowptr + (N + 1);         // [N]
    float* packed = node + 131072;           // [E,12] CSR-ordered edge records

    k_prep<<<dim3(125), dim3(256), 0, stream>>>(
        Wn1, Bsw1, Wn2, Bsw2, Wu0, Wu0h_s, Wu0l_s, Wu1, Wu1h_s, Wu1l_s,
        Wuh, Wuhh_s, Wuhl_s, Wd, Wdh_s, Wdl_s, counts, N);
    k_down<<<dim3((N + 31) / 32), dim3(256), 0, stream>>>(
        x, Wdh_s, Wdl_s, bd, xp, N);
    k_hist<<<dim3((E + 255) / 256), dim3(256), 0, stream>>>(iidx, counts, E);
    k_scan<<<dim3(1), dim3(1024), 0, stream>>>(counts, rowptr, cursor, N);
    k_scatter_pack<<<dim3((E + 255) / 256), dim3(256), 0, stream>>>(
        iidx, jidx, factor, sph0, sph1, cursor, packed, E);
    k_gather<<<dim3((N + 3) / 4), dim3(256), 0, stream>>>(
        xp, rbf, packed, rowptr, agg0, agg1, aggh, N);
    k_node<<<dim3((N + 15) / 16), dim3(256), 0, stream>>>(
        xp, agg0, agg1, aggh, Wu0h_s, Wu0l_s, Wu1h_s, Wu1l_s, Wuhh_s, Wuhl_s,
        bu0, node, N);
    k_final<<<dim3((N + 31) / 32), dim3(256), 0, stream>>>(
        node, Bsw1, bn1, lng, lnb, Bsw2, bn2, x, out, N);
}

// Round 6
// 478.454 us; speedup vs baseline: 1.6664x; 1.0370x over previous
//
#include <hip/hip_runtime.h>
#include <hip/hip_bf16.h>

typedef __attribute__((ext_vector_type(8))) short bf16x8;
typedef __attribute__((ext_vector_type(4))) float f32x4;

__device__ __forceinline__ unsigned short f2bf(float f) {
    unsigned u = __float_as_uint(f);
    return (unsigned short)((u + 0x7FFF + ((u >> 16) & 1)) >> 16);  // RNE
}
__device__ __forceinline__ unsigned pack2(float a, float b) {
    return (unsigned)f2bf(a) | ((unsigned)f2bf(b) << 16);
}
__device__ __forceinline__ float ubf(unsigned short h) {
    return __uint_as_float((unsigned)h << 16);
}
// register broadcast: lane k (uniform) -> all lanes, result in SGPR
__device__ __forceinline__ int RLi(float v, int k) {
    return __builtin_amdgcn_readlane(__float_as_int(v), k);
}
__device__ __forceinline__ float RLf(float v, int k) {
    return __uint_as_float((unsigned)__builtin_amdgcn_readlane(__float_as_int(v), k));
}

// ---------------------------------------------------------------------------
// k_prep: all one-time weight swizzles + counts zeroing in ONE launch.
// blocks 0-47: Wn1 swz; 48-79: Wn2 swz; 80-83: Wu0 split; 84-87: Wu1 split;
// 88-91: Wuh split; 92-99: Wd split; 100-124: zero counts. (Proven R10.)
// ---------------------------------------------------------------------------
__device__ void swz_body(const float* __restrict__ W,
                         unsigned short* __restrict__ Bsw, int K, int idx)
{
    int total = (K >> 5) * 1024;            // (K/32) * 16 ct * 64 lanes
    if (idx >= total) return;
    int lane = idx & 63;
    int ct = (idx >> 6) & 15;
    int ks = idx >> 10;
    int col = ct * 16 + (lane & 15);
    int kbase = (ks << 5) + ((lane >> 4) << 3);
    const float* p = &W[(size_t)kbase * 256 + col];
    uint4 o;
    o.x = pack2(p[0 * 256], p[1 * 256]);
    o.y = pack2(p[2 * 256], p[3 * 256]);
    o.z = pack2(p[4 * 256], p[5 * 256]);
    o.w = pack2(p[6 * 256], p[7 * 256]);
    *(uint4*)&Bsw[(size_t)idx * 8] = o;
}

__device__ void swz_split_body(const float* __restrict__ W,
                               unsigned short* __restrict__ Bh,
                               unsigned short* __restrict__ Bl,
                               int K, int C, int idx)
{
    int ct_n = C >> 4;
    int total = (K >> 5) * ct_n * 64;
    if (idx >= total) return;
    int per_ks = ct_n * 64;
    int ks = idx / per_ks;
    int rem = idx - ks * per_ks;
    int ct = rem >> 6;
    int lane = rem & 63;
    int col = ct * 16 + (lane & 15);
    int kbase = (ks << 5) + ((lane >> 4) << 3);
    const float* p = &W[(size_t)kbase * C + col];
    unsigned short hs[8], ls[8];
#pragma unroll
    for (int j = 0; j < 8; j++) {
        float wv = p[(size_t)j * C];
        unsigned short h = f2bf(wv);
        hs[j] = h;
        ls[j] = f2bf(wv - ubf(h));
    }
    uint4 oh, ol;
    oh.x = (unsigned)hs[0] | ((unsigned)hs[1] << 16);
    oh.y = (unsigned)hs[2] | ((unsigned)hs[3] << 16);
    oh.z = (unsigned)hs[4] | ((unsigned)hs[5] << 16);
    oh.w = (unsigned)hs[6] | ((unsigned)hs[7] << 16);
    ol.x = (unsigned)ls[0] | ((unsigned)ls[1] << 16);
    ol.y = (unsigned)ls[2] | ((unsigned)ls[3] << 16);
    ol.z = (unsigned)ls[4] | ((unsigned)ls[5] << 16);
    ol.w = (unsigned)ls[6] | ((unsigned)ls[7] << 16);
    *(uint4*)&Bh[(size_t)idx * 8] = oh;
    *(uint4*)&Bl[(size_t)idx * 8] = ol;
}

__global__ __launch_bounds__(256) void k_prep(
    const float* __restrict__ Wn1, unsigned short* __restrict__ Bsw1,
    const float* __restrict__ Wn2, unsigned short* __restrict__ Bsw2,
    const float* __restrict__ Wu0, unsigned short* __restrict__ Wu0h, unsigned short* __restrict__ Wu0l,
    const float* __restrict__ Wu1, unsigned short* __restrict__ Wu1h, unsigned short* __restrict__ Wu1l,
    const float* __restrict__ Wuh, unsigned short* __restrict__ Wuhh, unsigned short* __restrict__ Wuhl,
    const float* __restrict__ Wd, unsigned short* __restrict__ Wdh, unsigned short* __restrict__ Wdl,
    int* __restrict__ counts, int N)
{
    int b = blockIdx.x;
    int tid = threadIdx.x;
    if (b < 48)       swz_body(Wn1, Bsw1, 384, b * 256 + tid);
    else if (b < 80)  swz_body(Wn2, Bsw2, 256, (b - 48) * 256 + tid);
    else if (b < 84)  swz_split_body(Wu0, Wu0h, Wu0l, 64, 128, (b - 80) * 256 + tid);
    else if (b < 88)  swz_split_body(Wu1, Wu1h, Wu1l, 64, 128, (b - 84) * 256 + tid);
    else if (b < 92)  swz_split_body(Wuh, Wuhh, Wuhl, 64, 128, (b - 88) * 256 + tid);
    else if (b < 100) swz_split_body(Wd, Wdh, Wdl, 256, 64, (b - 92) * 256 + tid);
    else {
        for (int i = (b - 100) * 256 + tid; i < N + 1; i += 25 * 256)
            counts[i] = 0;
    }
}

// ---------------------------------------------------------------------------
// R11: k_down + k_hist fused (independent work, block-partitioned).
// blocks [0, nDown): hi/lo split MFMA down-projection (proven R8 body).
// blocks [nDown, nDown+nHist): edge histogram (proven body).
// ---------------------------------------------------------------------------
__global__ __launch_bounds__(256, 4) void k_down_hist(
    const float* __restrict__ x, const unsigned short* __restrict__ Wdh,
    const unsigned short* __restrict__ Wdl, const float* __restrict__ bd,
    float* __restrict__ xp, const int* __restrict__ iidx,
    int* __restrict__ counts, int N, int E, int nDown)
{
    __shared__ __align__(16) unsigned short Ahi[32 * 264];
    __shared__ __align__(16) unsigned short Alo[32 * 264];

    if ((int)blockIdx.x >= nDown) {
        int e = ((int)blockIdx.x - nDown) * 256 + threadIdx.x;
        if (e < E) atomicAdd(&counts[iidx[e]], 1);
        return;
    }

    int n0 = blockIdx.x * 32;
    int tid = threadIdx.x;
    int lane = tid & 63;
    int w = tid >> 6;
    int rt = w & 1;
    int cg = w >> 1;
    int lcol = lane & 15;
    int quad = lane >> 4;
    int kq = quad * 8;

    for (int t = tid; t < 32 * 64; t += 256) {
        int r = t >> 6, c4 = t & 63;
        int n = n0 + r;
        float4 v = {0.f, 0.f, 0.f, 0.f};
        if (n < N) v = *(const float4*)&x[(size_t)n * 256 + c4 * 4];
        unsigned short hx = f2bf(v.x), hy = f2bf(v.y);
        unsigned short hz = f2bf(v.z), hw = f2bf(v.w);
        uint2 oh, ol;
        oh.x = (unsigned)hx | ((unsigned)hy << 16);
        oh.y = (unsigned)hz | ((unsigned)hw << 16);
        ol.x = (unsigned)f2bf(v.x - ubf(hx)) | ((unsigned)f2bf(v.y - ubf(hy)) << 16);
        ol.y = (unsigned)f2bf(v.z - ubf(hz)) | ((unsigned)f2bf(v.w - ubf(hw)) << 16);
        *(uint2*)&Ahi[r * 264 + c4 * 4] = oh;
        *(uint2*)&Alo[r * 264 + c4 * 4] = ol;
    }
    __syncthreads();

    int arow = rt * 16 + lcol;
    f32x4 acc[2];
    acc[0] = (f32x4){0.f, 0.f, 0.f, 0.f};
    acc[1] = (f32x4){0.f, 0.f, 0.f, 0.f};
#pragma unroll
    for (int ks = 0; ks < 8; ks++) {
        bf16x8 ah = *(const bf16x8*)&Ahi[arow * 264 + ks * 32 + kq];
        bf16x8 al = *(const bf16x8*)&Alo[arow * 264 + ks * 32 + kq];
#pragma unroll
        for (int t = 0; t < 2; t++) {
            int ct = cg * 2 + t;
            size_t bi = ((size_t)((ks * 4 + ct) * 64 + lane)) * 8;
            bf16x8 bh = *(const bf16x8*)&Wdh[bi];
            bf16x8 bl = *(const bf16x8*)&Wdl[bi];
            acc[t] = __builtin_amdgcn_mfma_f32_16x16x32_bf16(ah, bh, acc[t], 0, 0, 0);
            acc[t] = __builtin_amdgcn_mfma_f32_16x16x32_bf16(ah, bl, acc[t], 0, 0, 0);
            acc[t] = __builtin_amdgcn_mfma_f32_16x16x32_bf16(al, bh, acc[t], 0, 0, 0);
        }
    }
#pragma unroll
    for (int t = 0; t < 2; t++) {
        int col = cg * 32 + t * 16 + lcol;
        float bb = bd[col];
#pragma unroll
        for (int q = 0; q < 4; q++) {
            int row = rt * 16 + quad * 4 + q;
            int n = n0 + row;
            if (n < N) xp[(size_t)n * 64 + col] = acc[t][q] + bb;
        }
    }
}

// ---------------------------------------------------------------------------
// Stage B: CSR scan + pack-scatter (proven).
// ---------------------------------------------------------------------------
__global__ __launch_bounds__(1024) void k_scan(
    const int* __restrict__ counts, int* __restrict__ rowptr,
    int* __restrict__ cursor, int N)
{
    __shared__ int part[1024];
    int t = threadIdx.x;
    int chunk = (N + 1023) / 1024;
    int beg = t * chunk;
    int end = min(beg + chunk, N);
    int s = 0;
    for (int i = beg; i < end; i++) s += counts[i];
    part[t] = s;
    __syncthreads();
    for (int off = 1; off < 1024; off <<= 1) {
        int v = (t >= off) ? part[t - off] : 0;
        __syncthreads();
        part[t] += v;
        __syncthreads();
    }
    int run = (t == 0) ? 0 : part[t - 1];
    for (int i = beg; i < end; i++) {
        rowptr[i] = run;
        cursor[i] = run;
        run += counts[i];
    }
    if (t == 1023) rowptr[N] = part[1023];
}

__global__ __launch_bounds__(256) void k_scatter_pack(
    const int* __restrict__ iidx, const int* __restrict__ jidx,
    const float* __restrict__ factor, const float* __restrict__ sph0,
    const float* __restrict__ sph1, int* __restrict__ cursor,
    float* __restrict__ packed, int E)
{
    int e = blockIdx.x * 256 + threadIdx.x;
    if (e >= E) return;
    int pos = atomicAdd(&cursor[iidx[e]], 1);
    float4 w0, w1, w2;
    w0.x = __int_as_float(e);
    w0.y = __int_as_float(jidx[e]);
    w0.z = factor[e];
    w0.w = sph1[e * 3 + 0];
    w1.x = sph1[e * 3 + 1];
    w1.y = sph1[e * 3 + 2];
    w1.z = sph0[e * 5 + 0];
    w1.w = sph0[e * 5 + 1];
    w2.x = sph0[e * 5 + 2];
    w2.y = sph0[e * 5 + 3];
    w2.z = sph0[e * 5 + 4];
    w2.w = 0.f;
    float4* q = (float4*)&packed[(size_t)pos * 12];
    q[0] = w0; q[1] = w1; q[2] = w2;
}

// ---------------------------------------------------------------------------
// k_gather: one wave per node; coalesced packed-record staging + readlane
// broadcast (proven R7).
// ---------------------------------------------------------------------------
__global__ __launch_bounds__(256) void k_gather(
    const float* __restrict__ xp, const float* __restrict__ rbf,
    const float* __restrict__ packed, const int* __restrict__ rowptr,
    float* __restrict__ agg0, float* __restrict__ agg1,
    float* __restrict__ aggh, int N)
{
    int n = blockIdx.x * 4 + (threadIdx.x >> 6);
    if (n >= N) return;
    int p = threadIdx.x & 63;
    int beg = rowptr[n], end = rowptr[n + 1];

    float a0 = 0.f;
    float a1x = 0.f, a1y = 0.f, a1z = 0.f;
    float h0 = 0.f, h1 = 0.f, h2 = 0.f, h3 = 0.f, h4 = 0.f;

    for (int base = beg; base < end; base += 64) {
        int m = end - base;
        if (m > 64) m = 64;
        float4 w0 = {0.f, 0.f, 0.f, 0.f};
        float4 w1 = {0.f, 0.f, 0.f, 0.f};
        float4 w2 = {0.f, 0.f, 0.f, 0.f};
        if (base + p < end) {
            const float4* q = (const float4*)&packed[(size_t)(base + p) * 12];
            w0 = q[0]; w1 = q[1]; w2 = q[2];
        }
        int k = 0;
        for (; k + 3 < m; k += 4) {
            int e0 = RLi(w0.x, k),     e1 = RLi(w0.x, k + 1);
            int e2 = RLi(w0.x, k + 2), e3 = RLi(w0.x, k + 3);
            int j0 = RLi(w0.y, k),     j1 = RLi(w0.y, k + 1);
            int j2 = RLi(w0.y, k + 2), j3 = RLi(w0.y, k + 3);
            float x0 = xp[(size_t)j0 * 64 + p], r0 = rbf[(size_t)e0 * 64 + p];
            float x1 = xp[(size_t)j1 * 64 + p], r1 = rbf[(size_t)e1 * 64 + p];
            float x2 = xp[(size_t)j2 * 64 + p], r2 = rbf[(size_t)e2 * 64 + p];
            float x3 = xp[(size_t)j3 * 64 + p], r3 = rbf[(size_t)e3 * 64 + p];
            float f0 = RLf(w0.z, k),     f1 = RLf(w0.z, k + 1);
            float f2 = RLf(w0.z, k + 2), f3 = RLf(w0.z, k + 3);
            float v0 = x0 * r0 * f0, v1 = x1 * r1 * f1;
            float v2 = x2 * r2 * f2, v3 = x3 * r3 * f3;
            a0 += (v0 + v1) + (v2 + v3);
            a1x += v0 * RLf(w0.w, k)     + v1 * RLf(w0.w, k + 1)
                 + v2 * RLf(w0.w, k + 2) + v3 * RLf(w0.w, k + 3);
            a1y += v0 * RLf(w1.x, k)     + v1 * RLf(w1.x, k + 1)
                 + v2 * RLf(w1.x, k + 2) + v3 * RLf(w1.x, k + 3);
            a1z += v0 * RLf(w1.y, k)     + v1 * RLf(w1.y, k + 1)
                 + v2 * RLf(w1.y, k + 2) + v3 * RLf(w1.y, k + 3);
            h0  += v0 * RLf(w1.z, k)     + v1 * RLf(w1.z, k + 1)
                 + v2 * RLf(w1.z, k + 2) + v3 * RLf(w1.z, k + 3);
            h1  += v0 * RLf(w1.w, k)     + v1 * RLf(w1.w, k + 1)
                 + v2 * RLf(w1.w, k + 2) + v3 * RLf(w1.w, k + 3);
            h2  += v0 * RLf(w2.x, k)     + v1 * RLf(w2.x, k + 1)
                 + v2 * RLf(w2.x, k + 2) + v3 * RLf(w2.x, k + 3);
            h3  += v0 * RLf(w2.y, k)     + v1 * RLf(w2.y, k + 1)
                 + v2 * RLf(w2.y, k + 2) + v3 * RLf(w2.y, k + 3);
            h4  += v0 * RLf(w2.z, k)     + v1 * RLf(w2.z, k + 1)
                 + v2 * RLf(w2.z, k + 2) + v3 * RLf(w2.z, k + 3);
        }
        for (; k < m; k++) {
            int e0 = RLi(w0.x, k);
            int j0 = RLi(w0.y, k);
            float f0 = RLf(w0.z, k);
            float v0 = xp[(size_t)j0 * 64 + p] * rbf[(size_t)e0 * 64 + p] * f0;
            a0 += v0;
            a1x += v0 * RLf(w0.w, k);
            a1y += v0 * RLf(w1.x, k);
            a1z += v0 * RLf(w1.y, k);
            h0  += v0 * RLf(w1.z, k);
            h1  += v0 * RLf(w1.w, k);
            h2  += v0 * RLf(w2.x, k);
            h3  += v0 * RLf(w2.y, k);
            h4  += v0 * RLf(w2.z, k);
        }
    }

    agg0[(size_t)n * 64 + p] = a0;
    agg1[((size_t)n * 3 + 0) * 64 + p] = a1x;
    agg1[((size_t)n * 3 + 1) * 64 + p] = a1y;
    agg1[((size_t)n * 3 + 2) * 64 + p] = a1z;
    aggh[((size_t)n * 5 + 0) * 64 + p] = h0;
    aggh[((size_t)n * 5 + 1) * 64 + p] = h1;
    aggh[((size_t)n * 5 + 2) * 64 + p] = h2;
    aggh[((size_t)n * 5 + 3) * 64 + p] = h3;
    aggh[((size_t)n * 5 + 4) * 64 + p] = h4;
}

// ---------------------------------------------------------------------------
// Stage C1: node features via MFMA, hi/lo bf16 split (proven R6).
// R11: node output stored as bf16 — same f2bf rounding k_final applied during
// staging, so bit-identical downstream; halves node write traffic.
// ---------------------------------------------------------------------------
__global__ __launch_bounds__(256, 3) void k_node(
    const float* __restrict__ xp, const float* __restrict__ agg0,
    const float* __restrict__ agg1, const float* __restrict__ aggh,
    const unsigned short* __restrict__ Wu0h, const unsigned short* __restrict__ Wu0l,
    const unsigned short* __restrict__ Wu1h, const unsigned short* __restrict__ Wu1l,
    const unsigned short* __restrict__ Wuhh, const unsigned short* __restrict__ Wuhl,
    const float* __restrict__ bu0, unsigned short* __restrict__ node, int N)
{
    __shared__ float xs[16 * 64];
    __shared__ __align__(16) unsigned short Ahi[9 * 16 * 72];
    __shared__ __align__(16) unsigned short Alo[9 * 16 * 72];

    int n0 = blockIdx.x * 16;
    int tid = threadIdx.x;
    int lane = tid & 63;
    int w = tid >> 6;          // wave -> col group
    int lcol = lane & 15;
    int quad = lane >> 4;
    int kq = quad * 8;

    // stage xp tile
    for (int t = tid; t < 16 * 64; t += 256) {
        int n = n0 + (t >> 6);
        xs[t] = (n < N) ? xp[(size_t)n * 64 + (t & 63)] : 0.f;
    }
    __syncthreads();

    // build 9 hi/lo A-tiles: m=0: xs*agg0; m=1..3: xs*agg1[c]; m=4..8: xs*aggh[c]
    for (int t = tid; t < 9 * 1024; t += 256) {
        int m = t >> 10;
        int rem = t & 1023;
        int r = rem >> 6, c = rem & 63;
        int n = n0 + r;
        float v = 0.f;
        if (n < N) {
            float xv = xs[rem];
            if (m == 0)      v = xv * agg0[(size_t)n * 64 + c];
            else if (m < 4)  v = xv * agg1[((size_t)n * 3 + (m - 1)) * 64 + c];
            else             v = xv * aggh[((size_t)n * 5 + (m - 4)) * 64 + c];
        }
        unsigned short h = f2bf(v);
        float fh = __uint_as_float((unsigned)h << 16);
        Ahi[(m * 16 + r) * 72 + c] = h;
        Alo[(m * 16 + r) * 72 + c] = f2bf(v - fh);
    }
    __syncthreads();

    // ---- G0: l0 = a0 @ Wu0 + bu0 ----
    {
        bf16x8 bh[2][2], bl[2][2];
#pragma unroll
        for (int ks = 0; ks < 2; ks++)
#pragma unroll
            for (int t = 0; t < 2; t++) {
                size_t bi = ((size_t)((ks * 8 + w * 2 + t) * 64 + lane)) * 8;
                bh[ks][t] = *(const bf16x8*)&Wu0h[bi];
                bl[ks][t] = *(const bf16x8*)&Wu0l[bi];
            }
        f32x4 acc[2];
        acc[0] = (f32x4){0.f, 0.f, 0.f, 0.f};
        acc[1] = (f32x4){0.f, 0.f, 0.f, 0.f};
#pragma unroll
        for (int ks = 0; ks < 2; ks++) {
            bf16x8 ah = *(const bf16x8*)&Ahi[lcol * 72 + ks * 32 + kq];
            bf16x8 al = *(const bf16x8*)&Alo[lcol * 72 + ks * 32 + kq];
#pragma unroll
            for (int t = 0; t < 2; t++) {
                acc[t] = __builtin_amdgcn_mfma_f32_16x16x32_bf16(ah, bh[ks][t], acc[t], 0, 0, 0);
                acc[t] = __builtin_amdgcn_mfma_f32_16x16x32_bf16(ah, bl[ks][t], acc[t], 0, 0, 0);
                acc[t] = __builtin_amdgcn_mfma_f32_16x16x32_bf16(al, bh[ks][t], acc[t], 0, 0, 0);
            }
        }
#pragma unroll
        for (int t = 0; t < 2; t++) {
            int col = w * 32 + t * 16 + lcol;
            float bb = bu0[col];
#pragma unroll
            for (int q = 0; q < 4; q++) {
                int n = n0 + quad * 4 + q;
                if (n < N) node[(size_t)n * 384 + col] = f2bf(acc[t][q] + bb);
            }
        }
    }

    // ---- G1: l1 = sum_c ((a1_c @ Wu1))^2 ----
    {
        bf16x8 bh[2][2], bl[2][2];
#pragma unroll
        for (int ks = 0; ks < 2; ks++)
#pragma unroll
            for (int t = 0; t < 2; t++) {
                size_t bi = ((size_t)((ks * 8 + w * 2 + t) * 64 + lane)) * 8;
                bh[ks][t] = *(const bf16x8*)&Wu1h[bi];
                bl[ks][t] = *(const bf16x8*)&Wu1l[bi];
            }
        f32x4 S[2];
        S[0] = (f32x4){0.f, 0.f, 0.f, 0.f};
        S[1] = (f32x4){0.f, 0.f, 0.f, 0.f};
#pragma unroll
        for (int c = 0; c < 3; c++) {
            f32x4 d[2];
            d[0] = (f32x4){0.f, 0.f, 0.f, 0.f};
            d[1] = (f32x4){0.f, 0.f, 0.f, 0.f};
            int abase = (1 + c) * (16 * 72);
#pragma unroll
            for (int ks = 0; ks < 2; ks++) {
                bf16x8 ah = *(const bf16x8*)&Ahi[abase + lcol * 72 + ks * 32 + kq];
                bf16x8 al = *(const bf16x8*)&Alo[abase + lcol * 72 + ks * 32 + kq];
#pragma unroll
                for (int t = 0; t < 2; t++) {
                    d[t] = __builtin_amdgcn_mfma_f32_16x16x32_bf16(ah, bh[ks][t], d[t], 0, 0, 0);
                    d[t] = __builtin_amdgcn_mfma_f32_16x16x32_bf16(ah, bl[ks][t], d[t], 0, 0, 0);
                    d[t] = __builtin_amdgcn_mfma_f32_16x16x32_bf16(al, bh[ks][t], d[t], 0, 0, 0);
                }
            }
            S[0] += d[0] * d[0];
            S[1] += d[1] * d[1];
        }
#pragma unroll
        for (int t = 0; t < 2; t++) {
            int col = w * 32 + t * 16 + lcol;
#pragma unroll
            for (int q = 0; q < 4; q++) {
                int n = n0 + quad * 4 + q;
                if (n < N) node[(size_t)n * 384 + 128 + col] = f2bf(S[t][q]);
            }
        }
    }

    // ---- G2: lh = sum_c ((ah_c @ Wuh))^2 ----
    {
        bf16x8 bh[2][2], bl[2][2];
#pragma unroll
        for (int ks = 0; ks < 2; ks++)
#pragma unroll
            for (int t = 0; t < 2; t++) {
                size_t bi = ((size_t)((ks * 8 + w * 2 + t) * 64 + lane)) * 8;
                bh[ks][t] = *(const bf16x8*)&Wuhh[bi];
                bl[ks][t] = *(const bf16x8*)&Wuhl[bi];
            }
        f32x4 S[2];
        S[0] = (f32x4){0.f, 0.f, 0.f, 0.f};
        S[1] = (f32x4){0.f, 0.f, 0.f, 0.f};
#pragma unroll
        for (int c = 0; c < 5; c++) {
            f32x4 d[2];
            d[0] = (f32x4){0.f, 0.f, 0.f, 0.f};
            d[1] = (f32x4){0.f, 0.f, 0.f, 0.f};
            int abase = (4 + c) * (16 * 72);
#pragma unroll
            for (int ks = 0; ks < 2; ks++) {
                bf16x8 ah = *(const bf16x8*)&Ahi[abase + lcol * 72 + ks * 32 + kq];
                bf16x8 al = *(const bf16x8*)&Alo[abase + lcol * 72 + ks * 32 + kq];
#pragma unroll
                for (int t = 0; t < 2; t++) {
                    d[t] = __builtin_amdgcn_mfma_f32_16x16x32_bf16(ah, bh[ks][t], d[t], 0, 0, 0);
                    d[t] = __builtin_amdgcn_mfma_f32_16x16x32_bf16(ah, bl[ks][t], d[t], 0, 0, 0);
                    d[t] = __builtin_amdgcn_mfma_f32_16x16x32_bf16(al, bh[ks][t], d[t], 0, 0, 0);
                }
            }
            S[0] += d[0] * d[0];
            S[1] += d[1] * d[1];
        }
#pragma unroll
        for (int t = 0; t < 2; t++) {
            int col = w * 32 + t * 16 + lcol;
#pragma unroll
            for (int q = 0; q < 4; q++) {
                int n = n0 + quad * 4 + q;
                if (n < N) node[(size_t)n * 384 + 256 + col] = f2bf(S[t][q]);
            }
        }
    }
}

// ---------------------------------------------------------------------------
// Stage C2: bf16 MFMA fused GEMM1+LN+SiLU+GEMM2 (proven).
// R11: node input is already bf16 -> staging is a straight uint4 copy.
// ---------------------------------------------------------------------------
__global__ __launch_bounds__(256, 4) void k_final(
    const unsigned short* __restrict__ node, const unsigned short* __restrict__ Bsw1,
    const float* __restrict__ bn1, const float* __restrict__ lng,
    const float* __restrict__ lnb, const unsigned short* __restrict__ Bsw2,
    const float* __restrict__ bn2, const float* __restrict__ x,
    float* __restrict__ out, int N)
{
    __shared__ __align__(16) unsigned short Abf[32 * 392];   // GEMM1 A [32][384+8]; reused as GEMM2 A [32][256+8]
    __shared__ float red[32][33];
    __shared__ float red2[32][33];
    __shared__ float mstat[32][2];

    int n0 = blockIdx.x * 32;
    int tid = threadIdx.x;
    int lane = tid & 63;
    int w = tid >> 6;
    int rt = w & 1;
    int cg = w >> 1;
    int lcol = lane & 15;
    int quad = lane >> 4;
    int arow = rt * 16 + lcol;       // A-frag row this lane reads
    int kq = quad * 8;               // A/B-frag k sub-offset

    // ---- stage bf16 node tile -> Abf[32][392] (48 uint4 per row) ----
    for (int i = tid; i < 32 * 48; i += 256) {
        int r = i / 48, c8 = i - r * 48;
        int n = n0 + r;
        uint4 v = {0u, 0u, 0u, 0u};
        if (n < N) v = *(const uint4*)&node[(size_t)n * 384 + c8 * 8];
        *(uint4*)&Abf[r * 392 + c8 * 8] = v;
    }
    __syncthreads();

    // ---- GEMM1: T = node @ Wn1 ----
    f32x4 acc[8];
#pragma unroll
    for (int t = 0; t < 8; t++) acc[t] = (f32x4){0.f, 0.f, 0.f, 0.f};
    for (int ks = 0; ks < 12; ks++) {
        bf16x8 a = *(const bf16x8*)&Abf[arow * 392 + ks * 32 + kq];
        const bf16x8* bp =
            (const bf16x8*)&Bsw1[(size_t)(((ks * 16 + cg * 8) * 64) + lane) * 8];
#pragma unroll
        for (int t = 0; t < 8; t++)
            acc[t] = __builtin_amdgcn_mfma_f32_16x16x32_bf16(a, bp[t * 64], acc[t], 0, 0, 0);
    }

    // ---- per-row LN stats from accumulators ----
    float bias[8];
#pragma unroll
    for (int t = 0; t < 8; t++) bias[t] = bn1[cg * 128 + t * 16 + lcol];
#pragma unroll
    for (int q = 0; q < 4; q++) {
        float s = 0.f, s2 = 0.f;
#pragma unroll
        for (int t = 0; t < 8; t++) {
            float v = acc[t][q] + bias[t];
            s += v; s2 += v * v;
        }
        int row = rt * 16 + quad * 4 + q;
        red[row][cg * 16 + lcol] = s;
        red2[row][cg * 16 + lcol] = s2;
    }
    __syncthreads();
    if (tid < 32) {
        float s = 0.f, s2 = 0.f;
#pragma unroll
        for (int u = 0; u < 32; u++) { s += red[tid][u]; s2 += red2[tid][u]; }
        float m = s * (1.f / 256.f);
        float var = s2 * (1.f / 256.f) - m * m;
        mstat[tid][0] = m;
        mstat[tid][1] = rsqrtf(var + 1e-5f);
    }
    __syncthreads();

    // ---- LN + SiLU, write h as bf16 GEMM2 A-tile [32][264] ----
#pragma unroll
    for (int t = 0; t < 8; t++) {
        int col = cg * 128 + t * 16 + lcol;
        float gg = lng[col], bb = lnb[col];
#pragma unroll
        for (int q = 0; q < 4; q++) {
            int row = rt * 16 + quad * 4 + q;
            float z = (acc[t][q] + bias[t] - mstat[row][0]) * mstat[row][1] * gg + bb;
            float h = z / (1.f + __expf(-z));
            Abf[row * 264 + col] = f2bf(h);
        }
    }
    __syncthreads();

    // ---- GEMM2: out = h @ Wn2 + bn2 + x ----
    f32x4 o[8];
#pragma unroll
    for (int t = 0; t < 8; t++) o[t] = (f32x4){0.f, 0.f, 0.f, 0.f};
    for (int ks = 0; ks < 8; ks++) {
        bf16x8 a = *(const bf16x8*)&Abf[arow * 264 + ks * 32 + kq];
        const bf16x8* bp =
            (const bf16x8*)&Bsw2[(size_t)(((ks * 16 + cg * 8) * 64) + lane) * 8];
#pragma unroll
        for (int t = 0; t < 8; t++)
            o[t] = __builtin_amdgcn_mfma_f32_16x16x32_bf16(a, bp[t * 64], o[t], 0, 0, 0);
    }
#pragma unroll
    for (int t = 0; t < 8; t++) {
        int col = cg * 128 + t * 16 + lcol;
        float ob = bn2[col];
#pragma unroll
        for (int q = 0; q < 4; q++) {
            int row = rt * 16 + quad * 4 + q;
            int n = n0 + row;
            if (n < N)
                out[(size_t)n * 256 + col] = o[t][q] + ob + x[(size_t)n * 256 + col];
        }
    }
}

// ---------------------------------------------------------------------------
extern "C" void kernel_launch(void* const* d_in, const int* in_sizes, int n_in,
                              void* d_out, int out_size, void* d_ws, size_t ws_size,
                              hipStream_t stream)
{
    const float* x      = (const float*)d_in[0];
    const float* rbf    = (const float*)d_in[1];
    const float* factor = (const float*)d_in[2];
    const float* sph0   = (const float*)d_in[3];
    const float* sph1   = (const float*)d_in[4];
    const float* Wd     = (const float*)d_in[5];
    const float* bd     = (const float*)d_in[6];
    const float* Wu0    = (const float*)d_in[7];
    const float* bu0    = (const float*)d_in[8];
    const float* Wu1    = (const float*)d_in[9];
    const float* Wuh    = (const float*)d_in[10];
    const float* Wn1    = (const float*)d_in[11];
    const float* bn1    = (const float*)d_in[12];
    const float* lng    = (const float*)d_in[13];
    const float* lnb    = (const float*)d_in[14];
    const float* Wn2    = (const float*)d_in[15];
    const float* bn2    = (const float*)d_in[16];
    const int*   jidx   = (const int*)d_in[17];
    const int*   iidx   = (const int*)d_in[18];
    float* out = (float*)d_out;

    int N = in_sizes[0] / 256;
    int E = in_sizes[17];

    float* ws   = (float*)d_ws;
    float* xp   = ws;                        // [N,64]
    float* agg0 = xp   + (size_t)N * 64;     // [N,64]
    float* agg1 = agg0 + (size_t)N * 64;     // [N,3,64]
    float* aggh = agg1 + (size_t)N * 192;    // [N,5,64]
    float* nodeF = aggh + (size_t)N * 320;   // node region (sized as N*384 f32)
    unsigned short* nodeB = (unsigned short*)nodeF;  // bf16 node [N,384]
    // swizzled bf16 weights after the node region (offsets unchanged vs R10)
    unsigned short* Bsw1 = (unsigned short*)(nodeF + (size_t)N * 384); // 12*16*64*8
    unsigned short* Bsw2 = Bsw1 + 12 * 16 * 64 * 8;                    // 8*16*64*8
    unsigned short* Wu0h_s = Bsw2 + 8 * 16 * 64 * 8;
    unsigned short* Wu0l_s = Wu0h_s + 64 * 128;
    unsigned short* Wu1h_s = Wu0l_s + 64 * 128;
    unsigned short* Wu1l_s = Wu1h_s + 64 * 128;
    unsigned short* Wuhh_s = Wu1l_s + 64 * 128;
    unsigned short* Wuhl_s = Wuhh_s + 64 * 128;
    unsigned short* Wdh_s  = Wuhl_s + 64 * 128;
    unsigned short* Wdl_s  = Wdh_s + 256 * 64;

    // CSR scratch + packed edge records aliased onto the node region (dead
    // before k_node writes it; k_gather fully consumes packed before k_node).
    int* counts  = (int*)nodeF;              // [N+1]
    int* rowptr  = counts + (N + 1);         // [N+1]
    int* cursor  = rowptr + (N + 1);         // [N]
    float* packed = nodeF + 131072;          // [E,12] CSR-ordered edge records

    int nDown = (N + 31) / 32;
    int nHist = (E + 255) / 256;

    k_prep<<<dim3(125), dim3(256), 0, stream>>>(
        Wn1, Bsw1, Wn2, Bsw2, Wu0, Wu0h_s, Wu0l_s, Wu1, Wu1h_s, Wu1l_s,
        Wuh, Wuhh_s, Wuhl_s, Wd, Wdh_s, Wdl_s, counts, N);
    k_down_hist<<<dim3(nDown + nHist), dim3(256), 0, stream>>>(
        x, Wdh_s, Wdl_s, bd, xp, iidx, counts, N, E, nDown);
    k_scan<<<dim3(1), dim3(1024), 0, stream>>>(counts, rowptr, cursor, N);
    k_scatter_pack<<<dim3(nHist), dim3(256), 0, stream>>>(
        iidx, jidx, factor, sph0, sph1, cursor, packed, E);
    k_gather<<<dim3((N + 3) / 4), dim3(256), 0, stream>>>(
        xp, rbf, packed, rowptr, agg0, agg1, aggh, N);
    k_node<<<dim3((N + 15) / 16), dim3(256), 0, stream>>>(
        xp, agg0, agg1, aggh, Wu0h_s, Wu0l_s, Wu1h_s, Wu1l_s, Wuhh_s, Wuhl_s,
        bu0, nodeB, N);
    k_final<<<dim3((N + 31) / 32), dim3(256), 0, stream>>>(
        nodeB, Bsw1, bn1, lng, lnb, Bsw2, bn2, x, out, N);
}

// Round 7
// 449.864 us; speedup vs baseline: 1.7723x; 1.0636x over previous
//
#include <hip/hip_runtime.h>
#include <hip/hip_bf16.h>

typedef __attribute__((ext_vector_type(8))) short bf16x8;
typedef __attribute__((ext_vector_type(4))) float f32x4;

__device__ __forceinline__ unsigned short f2bf(float f) {
    unsigned u = __float_as_uint(f);
    return (unsigned short)((u + 0x7FFF + ((u >> 16) & 1)) >> 16);  // RNE
}
__device__ __forceinline__ unsigned pack2(float a, float b) {
    return (unsigned)f2bf(a) | ((unsigned)f2bf(b) << 16);
}
__device__ __forceinline__ float ubf(unsigned short h) {
    return __uint_as_float((unsigned)h << 16);
}
// register broadcast: lane k (uniform) -> all lanes, result in SGPR
__device__ __forceinline__ int RLi(float v, int k) {
    return __builtin_amdgcn_readlane(__float_as_int(v), k);
}
__device__ __forceinline__ float RLf(float v, int k) {
    return __uint_as_float((unsigned)__builtin_amdgcn_readlane(__float_as_int(v), k));
}

// ---------------------------------------------------------------------------
// k_prep: all one-time weight swizzles + counts zeroing in ONE launch.
// (Proven R10.)
// ---------------------------------------------------------------------------
__device__ void swz_body(const float* __restrict__ W,
                         unsigned short* __restrict__ Bsw, int K, int idx)
{
    int total = (K >> 5) * 1024;            // (K/32) * 16 ct * 64 lanes
    if (idx >= total) return;
    int lane = idx & 63;
    int ct = (idx >> 6) & 15;
    int ks = idx >> 10;
    int col = ct * 16 + (lane & 15);
    int kbase = (ks << 5) + ((lane >> 4) << 3);
    const float* p = &W[(size_t)kbase * 256 + col];
    uint4 o;
    o.x = pack2(p[0 * 256], p[1 * 256]);
    o.y = pack2(p[2 * 256], p[3 * 256]);
    o.z = pack2(p[4 * 256], p[5 * 256]);
    o.w = pack2(p[6 * 256], p[7 * 256]);
    *(uint4*)&Bsw[(size_t)idx * 8] = o;
}

__device__ void swz_split_body(const float* __restrict__ W,
                               unsigned short* __restrict__ Bh,
                               unsigned short* __restrict__ Bl,
                               int K, int C, int idx)
{
    int ct_n = C >> 4;
    int total = (K >> 5) * ct_n * 64;
    if (idx >= total) return;
    int per_ks = ct_n * 64;
    int ks = idx / per_ks;
    int rem = idx - ks * per_ks;
    int ct = rem >> 6;
    int lane = rem & 63;
    int col = ct * 16 + (lane & 15);
    int kbase = (ks << 5) + ((lane >> 4) << 3);
    const float* p = &W[(size_t)kbase * C + col];
    unsigned short hs[8], ls[8];
#pragma unroll
    for (int j = 0; j < 8; j++) {
        float wv = p[(size_t)j * C];
        unsigned short h = f2bf(wv);
        hs[j] = h;
        ls[j] = f2bf(wv - ubf(h));
    }
    uint4 oh, ol;
    oh.x = (unsigned)hs[0] | ((unsigned)hs[1] << 16);
    oh.y = (unsigned)hs[2] | ((unsigned)hs[3] << 16);
    oh.z = (unsigned)hs[4] | ((unsigned)hs[5] << 16);
    oh.w = (unsigned)hs[6] | ((unsigned)hs[7] << 16);
    ol.x = (unsigned)ls[0] | ((unsigned)ls[1] << 16);
    ol.y = (unsigned)ls[2] | ((unsigned)ls[3] << 16);
    ol.z = (unsigned)ls[4] | ((unsigned)ls[5] << 16);
    ol.w = (unsigned)ls[6] | ((unsigned)ls[7] << 16);
    *(uint4*)&Bh[(size_t)idx * 8] = oh;
    *(uint4*)&Bl[(size_t)idx * 8] = ol;
}

__global__ __launch_bounds__(256) void k_prep(
    const float* __restrict__ Wn1, unsigned short* __restrict__ Bsw1,
    const float* __restrict__ Wn2, unsigned short* __restrict__ Bsw2,
    const float* __restrict__ Wu0, unsigned short* __restrict__ Wu0h, unsigned short* __restrict__ Wu0l,
    const float* __restrict__ Wu1, unsigned short* __restrict__ Wu1h, unsigned short* __restrict__ Wu1l,
    const float* __restrict__ Wuh, unsigned short* __restrict__ Wuhh, unsigned short* __restrict__ Wuhl,
    const float* __restrict__ Wd, unsigned short* __restrict__ Wdh, unsigned short* __restrict__ Wdl,
    int* __restrict__ counts, int N)
{
    int b = blockIdx.x;
    int tid = threadIdx.x;
    if (b < 48)       swz_body(Wn1, Bsw1, 384, b * 256 + tid);
    else if (b < 80)  swz_body(Wn2, Bsw2, 256, (b - 48) * 256 + tid);
    else if (b < 84)  swz_split_body(Wu0, Wu0h, Wu0l, 64, 128, (b - 80) * 256 + tid);
    else if (b < 88)  swz_split_body(Wu1, Wu1h, Wu1l, 64, 128, (b - 84) * 256 + tid);
    else if (b < 92)  swz_split_body(Wuh, Wuhh, Wuhl, 64, 128, (b - 88) * 256 + tid);
    else if (b < 100) swz_split_body(Wd, Wdh, Wdl, 256, 64, (b - 92) * 256 + tid);
    else {
        for (int i = (b - 100) * 256 + tid; i < N + 1; i += 25 * 256)
            counts[i] = 0;
    }
}

// ---------------------------------------------------------------------------
// k_down + k_hist fused (proven R11).
// ---------------------------------------------------------------------------
__global__ __launch_bounds__(256, 4) void k_down_hist(
    const float* __restrict__ x, const unsigned short* __restrict__ Wdh,
    const unsigned short* __restrict__ Wdl, const float* __restrict__ bd,
    float* __restrict__ xp, const int* __restrict__ iidx,
    int* __restrict__ counts, int N, int E, int nDown)
{
    __shared__ __align__(16) unsigned short Ahi[32 * 264];
    __shared__ __align__(16) unsigned short Alo[32 * 264];

    if ((int)blockIdx.x >= nDown) {
        int e = ((int)blockIdx.x - nDown) * 256 + threadIdx.x;
        if (e < E) atomicAdd(&counts[iidx[e]], 1);
        return;
    }

    int n0 = blockIdx.x * 32;
    int tid = threadIdx.x;
    int lane = tid & 63;
    int w = tid >> 6;
    int rt = w & 1;
    int cg = w >> 1;
    int lcol = lane & 15;
    int quad = lane >> 4;
    int kq = quad * 8;

    for (int t = tid; t < 32 * 64; t += 256) {
        int r = t >> 6, c4 = t & 63;
        int n = n0 + r;
        float4 v = {0.f, 0.f, 0.f, 0.f};
        if (n < N) v = *(const float4*)&x[(size_t)n * 256 + c4 * 4];
        unsigned short hx = f2bf(v.x), hy = f2bf(v.y);
        unsigned short hz = f2bf(v.z), hw = f2bf(v.w);
        uint2 oh, ol;
        oh.x = (unsigned)hx | ((unsigned)hy << 16);
        oh.y = (unsigned)hz | ((unsigned)hw << 16);
        ol.x = (unsigned)f2bf(v.x - ubf(hx)) | ((unsigned)f2bf(v.y - ubf(hy)) << 16);
        ol.y = (unsigned)f2bf(v.z - ubf(hz)) | ((unsigned)f2bf(v.w - ubf(hw)) << 16);
        *(uint2*)&Ahi[r * 264 + c4 * 4] = oh;
        *(uint2*)&Alo[r * 264 + c4 * 4] = ol;
    }
    __syncthreads();

    int arow = rt * 16 + lcol;
    f32x4 acc[2];
    acc[0] = (f32x4){0.f, 0.f, 0.f, 0.f};
    acc[1] = (f32x4){0.f, 0.f, 0.f, 0.f};
#pragma unroll
    for (int ks = 0; ks < 8; ks++) {
        bf16x8 ah = *(const bf16x8*)&Ahi[arow * 264 + ks * 32 + kq];
        bf16x8 al = *(const bf16x8*)&Alo[arow * 264 + ks * 32 + kq];
#pragma unroll
        for (int t = 0; t < 2; t++) {
            int ct = cg * 2 + t;
            size_t bi = ((size_t)((ks * 4 + ct) * 64 + lane)) * 8;
            bf16x8 bh = *(const bf16x8*)&Wdh[bi];
            bf16x8 bl = *(const bf16x8*)&Wdl[bi];
            acc[t] = __builtin_amdgcn_mfma_f32_16x16x32_bf16(ah, bh, acc[t], 0, 0, 0);
            acc[t] = __builtin_amdgcn_mfma_f32_16x16x32_bf16(ah, bl, acc[t], 0, 0, 0);
            acc[t] = __builtin_amdgcn_mfma_f32_16x16x32_bf16(al, bh, acc[t], 0, 0, 0);
        }
    }
#pragma unroll
    for (int t = 0; t < 2; t++) {
        int col = cg * 32 + t * 16 + lcol;
        float bb = bd[col];
#pragma unroll
        for (int q = 0; q < 4; q++) {
            int row = rt * 16 + quad * 4 + q;
            int n = n0 + row;
            if (n < N) xp[(size_t)n * 64 + col] = acc[t][q] + bb;
        }
    }
}

// ---------------------------------------------------------------------------
// Stage B: CSR scan + pack-scatter (proven).
// ---------------------------------------------------------------------------
__global__ __launch_bounds__(1024) void k_scan(
    const int* __restrict__ counts, int* __restrict__ rowptr,
    int* __restrict__ cursor, int N)
{
    __shared__ int part[1024];
    int t = threadIdx.x;
    int chunk = (N + 1023) / 1024;
    int beg = t * chunk;
    int end = min(beg + chunk, N);
    int s = 0;
    for (int i = beg; i < end; i++) s += counts[i];
    part[t] = s;
    __syncthreads();
    for (int off = 1; off < 1024; off <<= 1) {
        int v = (t >= off) ? part[t - off] : 0;
        __syncthreads();
        part[t] += v;
        __syncthreads();
    }
    int run = (t == 0) ? 0 : part[t - 1];
    for (int i = beg; i < end; i++) {
        rowptr[i] = run;
        cursor[i] = run;
        run += counts[i];
    }
    if (t == 1023) rowptr[N] = part[1023];
}

__global__ __launch_bounds__(256) void k_scatter_pack(
    const int* __restrict__ iidx, const int* __restrict__ jidx,
    const float* __restrict__ factor, const float* __restrict__ sph0,
    const float* __restrict__ sph1, int* __restrict__ cursor,
    float* __restrict__ packed, int E)
{
    int e = blockIdx.x * 256 + threadIdx.x;
    if (e >= E) return;
    int pos = atomicAdd(&cursor[iidx[e]], 1);
    float4 w0, w1, w2;
    w0.x = __int_as_float(e);
    w0.y = __int_as_float(jidx[e]);
    w0.z = factor[e];
    w0.w = sph1[e * 3 + 0];
    w1.x = sph1[e * 3 + 1];
    w1.y = sph1[e * 3 + 2];
    w1.z = sph0[e * 5 + 0];
    w1.w = sph0[e * 5 + 1];
    w2.x = sph0[e * 5 + 2];
    w2.y = sph0[e * 5 + 3];
    w2.z = sph0[e * 5 + 4];
    w2.w = 0.f;
    float4* q = (float4*)&packed[(size_t)pos * 12];
    q[0] = w0; q[1] = w1; q[2] = w2;
}

// ---------------------------------------------------------------------------
// k_gather (R12): proven R7 gather; epilogue now multiplies by xp[n] and
// stores the 9 aggregates directly as hi/lo bf16 A-tiles in k_node's layout
// aggHi/aggLo[((n>>4)*9 + m)*1024 + (n&15)*64 + p]. Bit-identical values to
// the old k_node build (same f2bf of same fp32 products).
// ---------------------------------------------------------------------------
__global__ __launch_bounds__(256) void k_gather(
    const float* __restrict__ xp, const float* __restrict__ rbf,
    const float* __restrict__ packed, const int* __restrict__ rowptr,
    unsigned short* __restrict__ aggHi, unsigned short* __restrict__ aggLo,
    int N)
{
    int n = blockIdx.x * 4 + (threadIdx.x >> 6);
    if (n >= N) return;
    int p = threadIdx.x & 63;
    int beg = rowptr[n], end = rowptr[n + 1];

    float a0 = 0.f;
    float a1x = 0.f, a1y = 0.f, a1z = 0.f;
    float h0 = 0.f, h1 = 0.f, h2 = 0.f, h3 = 0.f, h4 = 0.f;

    for (int base = beg; base < end; base += 64) {
        int m = end - base;
        if (m > 64) m = 64;
        float4 w0 = {0.f, 0.f, 0.f, 0.f};
        float4 w1 = {0.f, 0.f, 0.f, 0.f};
        float4 w2 = {0.f, 0.f, 0.f, 0.f};
        if (base + p < end) {
            const float4* q = (const float4*)&packed[(size_t)(base + p) * 12];
            w0 = q[0]; w1 = q[1]; w2 = q[2];
        }
        int k = 0;
        for (; k + 3 < m; k += 4) {
            int e0 = RLi(w0.x, k),     e1 = RLi(w0.x, k + 1);
            int e2 = RLi(w0.x, k + 2), e3 = RLi(w0.x, k + 3);
            int j0 = RLi(w0.y, k),     j1 = RLi(w0.y, k + 1);
            int j2 = RLi(w0.y, k + 2), j3 = RLi(w0.y, k + 3);
            float x0 = xp[(size_t)j0 * 64 + p], r0 = rbf[(size_t)e0 * 64 + p];
            float x1 = xp[(size_t)j1 * 64 + p], r1 = rbf[(size_t)e1 * 64 + p];
            float x2 = xp[(size_t)j2 * 64 + p], r2 = rbf[(size_t)e2 * 64 + p];
            float x3 = xp[(size_t)j3 * 64 + p], r3 = rbf[(size_t)e3 * 64 + p];
            float f0 = RLf(w0.z, k),     f1 = RLf(w0.z, k + 1);
            float f2 = RLf(w0.z, k + 2), f3 = RLf(w0.z, k + 3);
            float v0 = x0 * r0 * f0, v1 = x1 * r1 * f1;
            float v2 = x2 * r2 * f2, v3 = x3 * r3 * f3;
            a0 += (v0 + v1) + (v2 + v3);
            a1x += v0 * RLf(w0.w, k)     + v1 * RLf(w0.w, k + 1)
                 + v2 * RLf(w0.w, k + 2) + v3 * RLf(w0.w, k + 3);
            a1y += v0 * RLf(w1.x, k)     + v1 * RLf(w1.x, k + 1)
                 + v2 * RLf(w1.x, k + 2) + v3 * RLf(w1.x, k + 3);
            a1z += v0 * RLf(w1.y, k)     + v1 * RLf(w1.y, k + 1)
                 + v2 * RLf(w1.y, k + 2) + v3 * RLf(w1.y, k + 3);
            h0  += v0 * RLf(w1.z, k)     + v1 * RLf(w1.z, k + 1)
                 + v2 * RLf(w1.z, k + 2) + v3 * RLf(w1.z, k + 3);
            h1  += v0 * RLf(w1.w, k)     + v1 * RLf(w1.w, k + 1)
                 + v2 * RLf(w1.w, k + 2) + v3 * RLf(w1.w, k + 3);
            h2  += v0 * RLf(w2.x, k)     + v1 * RLf(w2.x, k + 1)
                 + v2 * RLf(w2.x, k + 2) + v3 * RLf(w2.x, k + 3);
            h3  += v0 * RLf(w2.y, k)     + v1 * RLf(w2.y, k + 1)
                 + v2 * RLf(w2.y, k + 2) + v3 * RLf(w2.y, k + 3);
            h4  += v0 * RLf(w2.z, k)     + v1 * RLf(w2.z, k + 1)
                 + v2 * RLf(w2.z, k + 2) + v3 * RLf(w2.z, k + 3);
        }
        for (; k < m; k++) {
            int e0 = RLi(w0.x, k);
            int j0 = RLi(w0.y, k);
            float f0 = RLf(w0.z, k);
            float v0 = xp[(size_t)j0 * 64 + p] * rbf[(size_t)e0 * 64 + p] * f0;
            a0 += v0;
            a1x += v0 * RLf(w0.w, k);
            a1y += v0 * RLf(w1.x, k);
            a1z += v0 * RLf(w1.y, k);
            h0  += v0 * RLf(w1.z, k);
            h1  += v0 * RLf(w1.w, k);
            h2  += v0 * RLf(w2.x, k);
            h3  += v0 * RLf(w2.y, k);
            h4  += v0 * RLf(w2.z, k);
        }
    }

    // epilogue: A-tile values (x-multiplied), hi/lo bf16, in k_node layout
    float xv = xp[(size_t)n * 64 + p];
    float vals[9] = {xv * a0, xv * a1x, xv * a1y, xv * a1z,
                     xv * h0, xv * h1, xv * h2, xv * h3, xv * h4};
    size_t b9 = (size_t)(n >> 4) * 9216 + (size_t)(n & 15) * 64 + p;
#pragma unroll
    for (int m = 0; m < 9; m++) {
        unsigned short hh = f2bf(vals[m]);
        aggHi[b9 + m * 1024] = hh;
        aggLo[b9 + m * 1024] = f2bf(vals[m] - ubf(hh));
    }
}

// ---------------------------------------------------------------------------
// Stage C1 (R12): A-tiles arrive pre-built in global (hi/lo bf16) — staging
// is a pure uint4 copy (zero for pad rows). MFMA phases unchanged (proven R6).
// ---------------------------------------------------------------------------
__global__ __launch_bounds__(256, 3) void k_node(
    const unsigned short* __restrict__ aggHi, const unsigned short* __restrict__ aggLo,
    const unsigned short* __restrict__ Wu0h, const unsigned short* __restrict__ Wu0l,
    const unsigned short* __restrict__ Wu1h, const unsigned short* __restrict__ Wu1l,
    const unsigned short* __restrict__ Wuhh, const unsigned short* __restrict__ Wuhl,
    const float* __restrict__ bu0, unsigned short* __restrict__ node, int N)
{
    __shared__ __align__(16) unsigned short Ahi[9 * 16 * 72];
    __shared__ __align__(16) unsigned short Alo[9 * 16 * 72];

    int n0 = blockIdx.x * 16;
    int tid = threadIdx.x;
    int lane = tid & 63;
    int w = tid >> 6;          // wave -> col group
    int lcol = lane & 15;
    int quad = lane >> 4;
    int kq = quad * 8;

    // copy pre-built tiles: 144 rows x 64 shorts (=8 uint4) each, per array
    size_t gbase = (size_t)blockIdx.x * 9216;
    for (int t = tid; t < 1152; t += 256) {
        int row = t >> 3, c8 = t & 7;
        int n = n0 + (row & 15);
        uint4 v = {0u, 0u, 0u, 0u};
        if (n < N) v = *(const uint4*)&aggHi[gbase + (size_t)row * 64 + c8 * 8];
        *(uint4*)&Ahi[row * 72 + c8 * 8] = v;
    }
    for (int t = tid; t < 1152; t += 256) {
        int row = t >> 3, c8 = t & 7;
        int n = n0 + (row & 15);
        uint4 v = {0u, 0u, 0u, 0u};
        if (n < N) v = *(const uint4*)&aggLo[gbase + (size_t)row * 64 + c8 * 8];
        *(uint4*)&Alo[row * 72 + c8 * 8] = v;
    }
    __syncthreads();

    // ---- G0: l0 = a0 @ Wu0 + bu0 ----
    {
        bf16x8 bh[2][2], bl[2][2];
#pragma unroll
        for (int ks = 0; ks < 2; ks++)
#pragma unroll
            for (int t = 0; t < 2; t++) {
                size_t bi = ((size_t)((ks * 8 + w * 2 + t) * 64 + lane)) * 8;
                bh[ks][t] = *(const bf16x8*)&Wu0h[bi];
                bl[ks][t] = *(const bf16x8*)&Wu0l[bi];
            }
        f32x4 acc[2];
        acc[0] = (f32x4){0.f, 0.f, 0.f, 0.f};
        acc[1] = (f32x4){0.f, 0.f, 0.f, 0.f};
#pragma unroll
        for (int ks = 0; ks < 2; ks++) {
            bf16x8 ah = *(const bf16x8*)&Ahi[lcol * 72 + ks * 32 + kq];
            bf16x8 al = *(const bf16x8*)&Alo[lcol * 72 + ks * 32 + kq];
#pragma unroll
            for (int t = 0; t < 2; t++) {
                acc[t] = __builtin_amdgcn_mfma_f32_16x16x32_bf16(ah, bh[ks][t], acc[t], 0, 0, 0);
                acc[t] = __builtin_amdgcn_mfma_f32_16x16x32_bf16(ah, bl[ks][t], acc[t], 0, 0, 0);
                acc[t] = __builtin_amdgcn_mfma_f32_16x16x32_bf16(al, bh[ks][t], acc[t], 0, 0, 0);
            }
        }
#pragma unroll
        for (int t = 0; t < 2; t++) {
            int col = w * 32 + t * 16 + lcol;
            float bb = bu0[col];
#pragma unroll
            for (int q = 0; q < 4; q++) {
                int n = n0 + quad * 4 + q;
                if (n < N) node[(size_t)n * 384 + col] = f2bf(acc[t][q] + bb);
            }
        }
    }

    // ---- G1: l1 = sum_c ((a1_c @ Wu1))^2 ----
    {
        bf16x8 bh[2][2], bl[2][2];
#pragma unroll
        for (int ks = 0; ks < 2; ks++)
#pragma unroll
            for (int t = 0; t < 2; t++) {
                size_t bi = ((size_t)((ks * 8 + w * 2 + t) * 64 + lane)) * 8;
                bh[ks][t] = *(const bf16x8*)&Wu1h[bi];
                bl[ks][t] = *(const bf16x8*)&Wu1l[bi];
            }
        f32x4 S[2];
        S[0] = (f32x4){0.f, 0.f, 0.f, 0.f};
        S[1] = (f32x4){0.f, 0.f, 0.f, 0.f};
#pragma unroll
        for (int c = 0; c < 3; c++) {
            f32x4 d[2];
            d[0] = (f32x4){0.f, 0.f, 0.f, 0.f};
            d[1] = (f32x4){0.f, 0.f, 0.f, 0.f};
            int abase = (1 + c) * (16 * 72);
#pragma unroll
            for (int ks = 0; ks < 2; ks++) {
                bf16x8 ah = *(const bf16x8*)&Ahi[abase + lcol * 72 + ks * 32 + kq];
                bf16x8 al = *(const bf16x8*)&Alo[abase + lcol * 72 + ks * 32 + kq];
#pragma unroll
                for (int t = 0; t < 2; t++) {
                    d[t] = __builtin_amdgcn_mfma_f32_16x16x32_bf16(ah, bh[ks][t], d[t], 0, 0, 0);
                    d[t] = __builtin_amdgcn_mfma_f32_16x16x32_bf16(ah, bl[ks][t], d[t], 0, 0, 0);
                    d[t] = __builtin_amdgcn_mfma_f32_16x16x32_bf16(al, bh[ks][t], d[t], 0, 0, 0);
                }
            }
            S[0] += d[0] * d[0];
            S[1] += d[1] * d[1];
        }
#pragma unroll
        for (int t = 0; t < 2; t++) {
            int col = w * 32 + t * 16 + lcol;
#pragma unroll
            for (int q = 0; q < 4; q++) {
                int n = n0 + quad * 4 + q;
                if (n < N) node[(size_t)n * 384 + 128 + col] = f2bf(S[t][q]);
            }
        }
    }

    // ---- G2: lh = sum_c ((ah_c @ Wuh))^2 ----
    {
        bf16x8 bh[2][2], bl[2][2];
#pragma unroll
        for (int ks = 0; ks < 2; ks++)
#pragma unroll
            for (int t = 0; t < 2; t++) {
                size_t bi = ((size_t)((ks * 8 + w * 2 + t) * 64 + lane)) * 8;
                bh[ks][t] = *(const bf16x8*)&Wuhh[bi];
                bl[ks][t] = *(const bf16x8*)&Wuhl[bi];
            }
        f32x4 S[2];
        S[0] = (f32x4){0.f, 0.f, 0.f, 0.f};
        S[1] = (f32x4){0.f, 0.f, 0.f, 0.f};
#pragma unroll
        for (int c = 0; c < 5; c++) {
            f32x4 d[2];
            d[0] = (f32x4){0.f, 0.f, 0.f, 0.f};
            d[1] = (f32x4){0.f, 0.f, 0.f, 0.f};
            int abase = (4 + c) * (16 * 72);
#pragma unroll
            for (int ks = 0; ks < 2; ks++) {
                bf16x8 ah = *(const bf16x8*)&Ahi[abase + lcol * 72 + ks * 32 + kq];
                bf16x8 al = *(const bf16x8*)&Alo[abase + lcol * 72 + ks * 32 + kq];
#pragma unroll
                for (int t = 0; t < 2; t++) {
                    d[t] = __builtin_amdgcn_mfma_f32_16x16x32_bf16(ah, bh[ks][t], d[t], 0, 0, 0);
                    d[t] = __builtin_amdgcn_mfma_f32_16x16x32_bf16(ah, bl[ks][t], d[t], 0, 0, 0);
                    d[t] = __builtin_amdgcn_mfma_f32_16x16x32_bf16(al, bh[ks][t], d[t], 0, 0, 0);
                }
            }
            S[0] += d[0] * d[0];
            S[1] += d[1] * d[1];
        }
#pragma unroll
        for (int t = 0; t < 2; t++) {
            int col = w * 32 + t * 16 + lcol;
#pragma unroll
            for (int q = 0; q < 4; q++) {
                int n = n0 + quad * 4 + q;
                if (n < N) node[(size_t)n * 384 + 256 + col] = f2bf(S[t][q]);
            }
        }
    }
}

// ---------------------------------------------------------------------------
// Stage C2: bf16 MFMA fused GEMM1+LN+SiLU+GEMM2 (proven R11).
// ---------------------------------------------------------------------------
__global__ __launch_bounds__(256, 4) void k_final(
    const unsigned short* __restrict__ node, const unsigned short* __restrict__ Bsw1,
    const float* __restrict__ bn1, const float* __restrict__ lng,
    const float* __restrict__ lnb, const unsigned short* __restrict__ Bsw2,
    const float* __restrict__ bn2, const float* __restrict__ x,
    float* __restrict__ out, int N)
{
    __shared__ __align__(16) unsigned short Abf[32 * 392];   // GEMM1 A [32][384+8]; reused as GEMM2 A [32][256+8]
    __shared__ float red[32][33];
    __shared__ float red2[32][33];
    __shared__ float mstat[32][2];

    int n0 = blockIdx.x * 32;
    int tid = threadIdx.x;
    int lane = tid & 63;
    int w = tid >> 6;
    int rt = w & 1;
    int cg = w >> 1;
    int lcol = lane & 15;
    int quad = lane >> 4;
    int arow = rt * 16 + lcol;       // A-frag row this lane reads
    int kq = quad * 8;               // A/B-frag k sub-offset

    // ---- stage bf16 node tile -> Abf[32][392] (48 uint4 per row) ----
    for (int i = tid; i < 32 * 48; i += 256) {
        int r = i / 48, c8 = i - r * 48;
        int n = n0 + r;
        uint4 v = {0u, 0u, 0u, 0u};
        if (n < N) v = *(const uint4*)&node[(size_t)n * 384 + c8 * 8];
        *(uint4*)&Abf[r * 392 + c8 * 8] = v;
    }
    __syncthreads();

    // ---- GEMM1: T = node @ Wn1 ----
    f32x4 acc[8];
#pragma unroll
    for (int t = 0; t < 8; t++) acc[t] = (f32x4){0.f, 0.f, 0.f, 0.f};
    for (int ks = 0; ks < 12; ks++) {
        bf16x8 a = *(const bf16x8*)&Abf[arow * 392 + ks * 32 + kq];
        const bf16x8* bp =
            (const bf16x8*)&Bsw1[(size_t)(((ks * 16 + cg * 8) * 64) + lane) * 8];
#pragma unroll
        for (int t = 0; t < 8; t++)
            acc[t] = __builtin_amdgcn_mfma_f32_16x16x32_bf16(a, bp[t * 64], acc[t], 0, 0, 0);
    }

    // ---- per-row LN stats from accumulators ----
    float bias[8];
#pragma unroll
    for (int t = 0; t < 8; t++) bias[t] = bn1[cg * 128 + t * 16 + lcol];
#pragma unroll
    for (int q = 0; q < 4; q++) {
        float s = 0.f, s2 = 0.f;
#pragma unroll
        for (int t = 0; t < 8; t++) {
            float v = acc[t][q] + bias[t];
            s += v; s2 += v * v;
        }
        int row = rt * 16 + quad * 4 + q;
        red[row][cg * 16 + lcol] = s;
        red2[row][cg * 16 + lcol] = s2;
    }
    __syncthreads();
    if (tid < 32) {
        float s = 0.f, s2 = 0.f;
#pragma unroll
        for (int u = 0; u < 32; u++) { s += red[tid][u]; s2 += red2[tid][u]; }
        float m = s * (1.f / 256.f);
        float var = s2 * (1.f / 256.f) - m * m;
        mstat[tid][0] = m;
        mstat[tid][1] = rsqrtf(var + 1e-5f);
    }
    __syncthreads();

    // ---- LN + SiLU, write h as bf16 GEMM2 A-tile [32][264] ----
#pragma unroll
    for (int t = 0; t < 8; t++) {
        int col = cg * 128 + t * 16 + lcol;
        float gg = lng[col], bb = lnb[col];
#pragma unroll
        for (int q = 0; q < 4; q++) {
            int row = rt * 16 + quad * 4 + q;
            float z = (acc[t][q] + bias[t] - mstat[row][0]) * mstat[row][1] * gg + bb;
            float h = z / (1.f + __expf(-z));
            Abf[row * 264 + col] = f2bf(h);
        }
    }
    __syncthreads();

    // ---- GEMM2: out = h @ Wn2 + bn2 + x ----
    f32x4 o[8];
#pragma unroll
    for (int t = 0; t < 8; t++) o[t] = (f32x4){0.f, 0.f, 0.f, 0.f};
    for (int ks = 0; ks < 8; ks++) {
        bf16x8 a = *(const bf16x8*)&Abf[arow * 264 + ks * 32 + kq];
        const bf16x8* bp =
            (const bf16x8*)&Bsw2[(size_t)(((ks * 16 + cg * 8) * 64) + lane) * 8];
#pragma unroll
        for (int t = 0; t < 8; t++)
            o[t] = __builtin_amdgcn_mfma_f32_16x16x32_bf16(a, bp[t * 64], o[t], 0, 0, 0);
    }
#pragma unroll
    for (int t = 0; t < 8; t++) {
        int col = cg * 128 + t * 16 + lcol;
        float ob = bn2[col];
#pragma unroll
        for (int q = 0; q < 4; q++) {
            int row = rt * 16 + quad * 4 + q;
            int n = n0 + row;
            if (n < N)
                out[(size_t)n * 256 + col] = o[t][q] + ob + x[(size_t)n * 256 + col];
        }
    }
}

// ---------------------------------------------------------------------------
extern "C" void kernel_launch(void* const* d_in, const int* in_sizes, int n_in,
                              void* d_out, int out_size, void* d_ws, size_t ws_size,
                              hipStream_t stream)
{
    const float* x      = (const float*)d_in[0];
    const float* rbf    = (const float*)d_in[1];
    const float* factor = (const float*)d_in[2];
    const float* sph0   = (const float*)d_in[3];
    const float* sph1   = (const float*)d_in[4];
    const float* Wd     = (const float*)d_in[5];
    const float* bd     = (const float*)d_in[6];
    const float* Wu0    = (const float*)d_in[7];
    const float* bu0    = (const float*)d_in[8];
    const float* Wu1    = (const float*)d_in[9];
    const float* Wuh    = (const float*)d_in[10];
    const float* Wn1    = (const float*)d_in[11];
    const float* bn1    = (const float*)d_in[12];
    const float* lng    = (const float*)d_in[13];
    const float* lnb    = (const float*)d_in[14];
    const float* Wn2    = (const float*)d_in[15];
    const float* bn2    = (const float*)d_in[16];
    const int*   jidx   = (const int*)d_in[17];
    const int*   iidx   = (const int*)d_in[18];
    float* out = (float*)d_out;

    int N = in_sizes[0] / 256;
    int E = in_sizes[17];
    int nblk = (N + 15) / 16;

    float* ws   = (float*)d_ws;
    float* xp   = ws;                                  // [N,64] f32
    float* aggF = xp + (size_t)N * 64;                 // A-tile region: nblk*9216 floats
    unsigned short* aggHi = (unsigned short*)aggF;     // [nblk*9216] bf16
    unsigned short* aggLo = aggHi + (size_t)nblk * 9216;
    float* nodeF = aggF + (size_t)nblk * 9216;         // node region (N*384 f32 worth)
    unsigned short* nodeB = (unsigned short*)nodeF;    // bf16 node [N,384]
    // swizzled bf16 weights after the node region
    unsigned short* Bsw1 = (unsigned short*)(nodeF + (size_t)N * 384); // 12*16*64*8
    unsigned short* Bsw2 = Bsw1 + 12 * 16 * 64 * 8;                    // 8*16*64*8
    unsigned short* Wu0h_s = Bsw2 + 8 * 16 * 64 * 8;
    unsigned short* Wu0l_s = Wu0h_s + 64 * 128;
    unsigned short* Wu1h_s = Wu0l_s + 64 * 128;
    unsigned short* Wu1l_s = Wu1h_s + 64 * 128;
    unsigned short* Wuhh_s = Wu1l_s + 64 * 128;
    unsigned short* Wuhl_s = Wuhh_s + 64 * 128;
    unsigned short* Wdh_s  = Wuhl_s + 64 * 128;
    unsigned short* Wdl_s  = Wdh_s + 256 * 64;

    // CSR scratch + packed edge records aliased onto the node region (dead
    // before k_node writes node; k_gather fully consumes packed first).
    int* counts  = (int*)nodeF;              // [N+1]
    int* rowptr  = counts + (N + 1);         // [N+1]
    int* cursor  = rowptr + (N + 1);         // [N]
    float* packed = nodeF + 131072;          // [E,12] CSR-ordered edge records

    int nDown = (N + 31) / 32;
    int nHist = (E + 255) / 256;

    k_prep<<<dim3(125), dim3(256), 0, stream>>>(
        Wn1, Bsw1, Wn2, Bsw2, Wu0, Wu0h_s, Wu0l_s, Wu1, Wu1h_s, Wu1l_s,
        Wuh, Wuhh_s, Wuhl_s, Wd, Wdh_s, Wdl_s, counts, N);
    k_down_hist<<<dim3(nDown + nHist), dim3(256), 0, stream>>>(
        x, Wdh_s, Wdl_s, bd, xp, iidx, counts, N, E, nDown);
    k_scan<<<dim3(1), dim3(1024), 0, stream>>>(counts, rowptr, cursor, N);
    k_scatter_pack<<<dim3(nHist), dim3(256), 0, stream>>>(
        iidx, jidx, factor, sph0, sph1, cursor, packed, E);
    k_gather<<<dim3((N + 3) / 4), dim3(256), 0, stream>>>(
        xp, rbf, packed, rowptr, aggHi, aggLo, N);
    k_node<<<dim3(nblk), dim3(256), 0, stream>>>(
        aggHi, aggLo, Wu0h_s, Wu0l_s, Wu1h_s, Wu1l_s, Wuhh_s, Wuhl_s,
        bu0, nodeB, N);
    k_final<<<dim3((N + 31) / 32), dim3(256), 0, stream>>>(
        nodeB, Bsw1, bn1, lng, lnb, Bsw2, bn2, x, out, N);
}

// Round 8
// 448.123 us; speedup vs baseline: 1.7792x; 1.0039x over previous
//
#include <hip/hip_runtime.h>
#include <hip/hip_bf16.h>

typedef __attribute__((ext_vector_type(8))) short bf16x8;
typedef __attribute__((ext_vector_type(4))) float f32x4;

__device__ __forceinline__ unsigned short f2bf(float f) {
    unsigned u = __float_as_uint(f);
    return (unsigned short)((u + 0x7FFF + ((u >> 16) & 1)) >> 16);  // RNE
}
__device__ __forceinline__ unsigned pack2(float a, float b) {
    return (unsigned)f2bf(a) | ((unsigned)f2bf(b) << 16);
}
__device__ __forceinline__ float ubf(unsigned short h) {
    return __uint_as_float((unsigned)h << 16);
}
// register broadcast: lane k (uniform) -> all lanes, result in SGPR
__device__ __forceinline__ int RLi(float v, int k) {
    return __builtin_amdgcn_readlane(__float_as_int(v), k);
}
__device__ __forceinline__ float RLf(float v, int k) {
    return __uint_as_float((unsigned)__builtin_amdgcn_readlane(__float_as_int(v), k));
}

// ---------------------------------------------------------------------------
// k_prep: all one-time weight swizzles + counts zeroing in ONE launch.
// (Proven R10.)
// ---------------------------------------------------------------------------
__device__ void swz_body(const float* __restrict__ W,
                         unsigned short* __restrict__ Bsw, int K, int idx)
{
    int total = (K >> 5) * 1024;            // (K/32) * 16 ct * 64 lanes
    if (idx >= total) return;
    int lane = idx & 63;
    int ct = (idx >> 6) & 15;
    int ks = idx >> 10;
    int col = ct * 16 + (lane & 15);
    int kbase = (ks << 5) + ((lane >> 4) << 3);
    const float* p = &W[(size_t)kbase * 256 + col];
    uint4 o;
    o.x = pack2(p[0 * 256], p[1 * 256]);
    o.y = pack2(p[2 * 256], p[3 * 256]);
    o.z = pack2(p[4 * 256], p[5 * 256]);
    o.w = pack2(p[6 * 256], p[7 * 256]);
    *(uint4*)&Bsw[(size_t)idx * 8] = o;
}

__device__ void swz_split_body(const float* __restrict__ W,
                               unsigned short* __restrict__ Bh,
                               unsigned short* __restrict__ Bl,
                               int K, int C, int idx)
{
    int ct_n = C >> 4;
    int total = (K >> 5) * ct_n * 64;
    if (idx >= total) return;
    int per_ks = ct_n * 64;
    int ks = idx / per_ks;
    int rem = idx - ks * per_ks;
    int ct = rem >> 6;
    int lane = rem & 63;
    int col = ct * 16 + (lane & 15);
    int kbase = (ks << 5) + ((lane >> 4) << 3);
    const float* p = &W[(size_t)kbase * C + col];
    unsigned short hs[8], ls[8];
#pragma unroll
    for (int j = 0; j < 8; j++) {
        float wv = p[(size_t)j * C];
        unsigned short h = f2bf(wv);
        hs[j] = h;
        ls[j] = f2bf(wv - ubf(h));
    }
    uint4 oh, ol;
    oh.x = (unsigned)hs[0] | ((unsigned)hs[1] << 16);
    oh.y = (unsigned)hs[2] | ((unsigned)hs[3] << 16);
    oh.z = (unsigned)hs[4] | ((unsigned)hs[5] << 16);
    oh.w = (unsigned)hs[6] | ((unsigned)hs[7] << 16);
    ol.x = (unsigned)ls[0] | ((unsigned)ls[1] << 16);
    ol.y = (unsigned)ls[2] | ((unsigned)ls[3] << 16);
    ol.z = (unsigned)ls[4] | ((unsigned)ls[5] << 16);
    ol.w = (unsigned)ls[6] | ((unsigned)ls[7] << 16);
    *(uint4*)&Bh[(size_t)idx * 8] = oh;
    *(uint4*)&Bl[(size_t)idx * 8] = ol;
}

__global__ __launch_bounds__(256) void k_prep(
    const float* __restrict__ Wn1, unsigned short* __restrict__ Bsw1,
    const float* __restrict__ Wn2, unsigned short* __restrict__ Bsw2,
    const float* __restrict__ Wu0, unsigned short* __restrict__ Wu0h, unsigned short* __restrict__ Wu0l,
    const float* __restrict__ Wu1, unsigned short* __restrict__ Wu1h, unsigned short* __restrict__ Wu1l,
    const float* __restrict__ Wuh, unsigned short* __restrict__ Wuhh, unsigned short* __restrict__ Wuhl,
    const float* __restrict__ Wd, unsigned short* __restrict__ Wdh, unsigned short* __restrict__ Wdl,
    int* __restrict__ counts, int N)
{
    int b = blockIdx.x;
    int tid = threadIdx.x;
    if (b < 48)       swz_body(Wn1, Bsw1, 384, b * 256 + tid);
    else if (b < 80)  swz_body(Wn2, Bsw2, 256, (b - 48) * 256 + tid);
    else if (b < 84)  swz_split_body(Wu0, Wu0h, Wu0l, 64, 128, (b - 80) * 256 + tid);
    else if (b < 88)  swz_split_body(Wu1, Wu1h, Wu1l, 64, 128, (b - 84) * 256 + tid);
    else if (b < 92)  swz_split_body(Wuh, Wuhh, Wuhl, 64, 128, (b - 88) * 256 + tid);
    else if (b < 100) swz_split_body(Wd, Wdh, Wdl, 256, 64, (b - 92) * 256 + tid);
    else {
        for (int i = (b - 100) * 256 + tid; i < N + 1; i += 25 * 256)
            counts[i] = 0;
    }
}

// ---------------------------------------------------------------------------
// k_down + k_hist fused (proven R11).
// ---------------------------------------------------------------------------
__global__ __launch_bounds__(256, 4) void k_down_hist(
    const float* __restrict__ x, const unsigned short* __restrict__ Wdh,
    const unsigned short* __restrict__ Wdl, const float* __restrict__ bd,
    float* __restrict__ xp, const int* __restrict__ iidx,
    int* __restrict__ counts, int N, int E, int nDown)
{
    __shared__ __align__(16) unsigned short Ahi[32 * 264];
    __shared__ __align__(16) unsigned short Alo[32 * 264];

    if ((int)blockIdx.x >= nDown) {
        int e = ((int)blockIdx.x - nDown) * 256 + threadIdx.x;
        if (e < E) atomicAdd(&counts[iidx[e]], 1);
        return;
    }

    int n0 = blockIdx.x * 32;
    int tid = threadIdx.x;
    int lane = tid & 63;
    int w = tid >> 6;
    int rt = w & 1;
    int cg = w >> 1;
    int lcol = lane & 15;
    int quad = lane >> 4;
    int kq = quad * 8;

    for (int t = tid; t < 32 * 64; t += 256) {
        int r = t >> 6, c4 = t & 63;
        int n = n0 + r;
        float4 v = {0.f, 0.f, 0.f, 0.f};
        if (n < N) v = *(const float4*)&x[(size_t)n * 256 + c4 * 4];
        unsigned short hx = f2bf(v.x), hy = f2bf(v.y);
        unsigned short hz = f2bf(v.z), hw = f2bf(v.w);
        uint2 oh, ol;
        oh.x = (unsigned)hx | ((unsigned)hy << 16);
        oh.y = (unsigned)hz | ((unsigned)hw << 16);
        ol.x = (unsigned)f2bf(v.x - ubf(hx)) | ((unsigned)f2bf(v.y - ubf(hy)) << 16);
        ol.y = (unsigned)f2bf(v.z - ubf(hz)) | ((unsigned)f2bf(v.w - ubf(hw)) << 16);
        *(uint2*)&Ahi[r * 264 + c4 * 4] = oh;
        *(uint2*)&Alo[r * 264 + c4 * 4] = ol;
    }
    __syncthreads();

    int arow = rt * 16 + lcol;
    f32x4 acc[2];
    acc[0] = (f32x4){0.f, 0.f, 0.f, 0.f};
    acc[1] = (f32x4){0.f, 0.f, 0.f, 0.f};
#pragma unroll
    for (int ks = 0; ks < 8; ks++) {
        bf16x8 ah = *(const bf16x8*)&Ahi[arow * 264 + ks * 32 + kq];
        bf16x8 al = *(const bf16x8*)&Alo[arow * 264 + ks * 32 + kq];
#pragma unroll
        for (int t = 0; t < 2; t++) {
            int ct = cg * 2 + t;
            size_t bi = ((size_t)((ks * 4 + ct) * 64 + lane)) * 8;
            bf16x8 bh = *(const bf16x8*)&Wdh[bi];
            bf16x8 bl = *(const bf16x8*)&Wdl[bi];
            acc[t] = __builtin_amdgcn_mfma_f32_16x16x32_bf16(ah, bh, acc[t], 0, 0, 0);
            acc[t] = __builtin_amdgcn_mfma_f32_16x16x32_bf16(ah, bl, acc[t], 0, 0, 0);
            acc[t] = __builtin_amdgcn_mfma_f32_16x16x32_bf16(al, bh, acc[t], 0, 0, 0);
        }
    }
#pragma unroll
    for (int t = 0; t < 2; t++) {
        int col = cg * 32 + t * 16 + lcol;
        float bb = bd[col];
#pragma unroll
        for (int q = 0; q < 4; q++) {
            int row = rt * 16 + quad * 4 + q;
            int n = n0 + row;
            if (n < N) xp[(size_t)n * 64 + col] = acc[t][q] + bb;
        }
    }
}

// ---------------------------------------------------------------------------
// Stage B: CSR scan + pack-scatter (proven).
// ---------------------------------------------------------------------------
__global__ __launch_bounds__(1024) void k_scan(
    const int* __restrict__ counts, int* __restrict__ rowptr,
    int* __restrict__ cursor, int N)
{
    __shared__ int part[1024];
    int t = threadIdx.x;
    int chunk = (N + 1023) / 1024;
    int beg = t * chunk;
    int end = min(beg + chunk, N);
    int s = 0;
    for (int i = beg; i < end; i++) s += counts[i];
    part[t] = s;
    __syncthreads();
    for (int off = 1; off < 1024; off <<= 1) {
        int v = (t >= off) ? part[t - off] : 0;
        __syncthreads();
        part[t] += v;
        __syncthreads();
    }
    int run = (t == 0) ? 0 : part[t - 1];
    for (int i = beg; i < end; i++) {
        rowptr[i] = run;
        cursor[i] = run;
        run += counts[i];
    }
    if (t == 1023) rowptr[N] = part[1023];
}

__global__ __launch_bounds__(256) void k_scatter_pack(
    const int* __restrict__ iidx, const int* __restrict__ jidx,
    const float* __restrict__ factor, const float* __restrict__ sph0,
    const float* __restrict__ sph1, int* __restrict__ cursor,
    float* __restrict__ packed, int E)
{
    int e = blockIdx.x * 256 + threadIdx.x;
    if (e >= E) return;
    int pos = atomicAdd(&cursor[iidx[e]], 1);
    float4 w0, w1, w2;
    w0.x = __int_as_float(e);
    w0.y = __int_as_float(jidx[e]);
    w0.z = factor[e];
    w0.w = sph1[e * 3 + 0];
    w1.x = sph1[e * 3 + 1];
    w1.y = sph1[e * 3 + 2];
    w1.z = sph0[e * 5 + 0];
    w1.w = sph0[e * 5 + 1];
    w2.x = sph0[e * 5 + 2];
    w2.y = sph0[e * 5 + 3];
    w2.z = sph0[e * 5 + 4];
    w2.w = 0.f;
    float4* q = (float4*)&packed[(size_t)pos * 12];
    q[0] = w0; q[1] = w1; q[2] = w2;
}

// ---------------------------------------------------------------------------
// k_gather (R13): R12 gather with 8-wide main unroll (16 row-loads in
// flight — latency-bound loop, doubles MLP). Epilogue stores hi/lo bf16
// A-tiles in k_node layout (proven R12).
// ---------------------------------------------------------------------------
__global__ __launch_bounds__(256) void k_gather(
    const float* __restrict__ xp, const float* __restrict__ rbf,
    const float* __restrict__ packed, const int* __restrict__ rowptr,
    unsigned short* __restrict__ aggHi, unsigned short* __restrict__ aggLo,
    int N)
{
    int n = blockIdx.x * 4 + (threadIdx.x >> 6);
    if (n >= N) return;
    int p = threadIdx.x & 63;
    int beg = rowptr[n], end = rowptr[n + 1];

    float a0 = 0.f;
    float a1x = 0.f, a1y = 0.f, a1z = 0.f;
    float h0 = 0.f, h1 = 0.f, h2 = 0.f, h3 = 0.f, h4 = 0.f;

    for (int base = beg; base < end; base += 64) {
        int m = end - base;
        if (m > 64) m = 64;
        float4 w0 = {0.f, 0.f, 0.f, 0.f};
        float4 w1 = {0.f, 0.f, 0.f, 0.f};
        float4 w2 = {0.f, 0.f, 0.f, 0.f};
        if (base + p < end) {
            const float4* q = (const float4*)&packed[(size_t)(base + p) * 12];
            w0 = q[0]; w1 = q[1]; w2 = q[2];
        }
        int k = 0;
        for (; k + 7 < m; k += 8) {
            int e0 = RLi(w0.x, k),     e1 = RLi(w0.x, k + 1);
            int e2 = RLi(w0.x, k + 2), e3 = RLi(w0.x, k + 3);
            int e4 = RLi(w0.x, k + 4), e5 = RLi(w0.x, k + 5);
            int e6 = RLi(w0.x, k + 6), e7 = RLi(w0.x, k + 7);
            int j0 = RLi(w0.y, k),     j1 = RLi(w0.y, k + 1);
            int j2 = RLi(w0.y, k + 2), j3 = RLi(w0.y, k + 3);
            int j4 = RLi(w0.y, k + 4), j5 = RLi(w0.y, k + 5);
            int j6 = RLi(w0.y, k + 6), j7 = RLi(w0.y, k + 7);
            float x0 = xp[(size_t)j0 * 64 + p], r0 = rbf[(size_t)e0 * 64 + p];
            float x1 = xp[(size_t)j1 * 64 + p], r1 = rbf[(size_t)e1 * 64 + p];
            float x2 = xp[(size_t)j2 * 64 + p], r2 = rbf[(size_t)e2 * 64 + p];
            float x3 = xp[(size_t)j3 * 64 + p], r3 = rbf[(size_t)e3 * 64 + p];
            float x4 = xp[(size_t)j4 * 64 + p], r4 = rbf[(size_t)e4 * 64 + p];
            float x5 = xp[(size_t)j5 * 64 + p], r5 = rbf[(size_t)e5 * 64 + p];
            float x6 = xp[(size_t)j6 * 64 + p], r6 = rbf[(size_t)e6 * 64 + p];
            float x7 = xp[(size_t)j7 * 64 + p], r7 = rbf[(size_t)e7 * 64 + p];
            float f0 = RLf(w0.z, k),     f1 = RLf(w0.z, k + 1);
            float f2 = RLf(w0.z, k + 2), f3 = RLf(w0.z, k + 3);
            float f4 = RLf(w0.z, k + 4), f5 = RLf(w0.z, k + 5);
            float f6 = RLf(w0.z, k + 6), f7 = RLf(w0.z, k + 7);
            float v0 = x0 * r0 * f0, v1 = x1 * r1 * f1;
            float v2 = x2 * r2 * f2, v3 = x3 * r3 * f3;
            float v4 = x4 * r4 * f4, v5 = x5 * r5 * f5;
            float v6 = x6 * r6 * f6, v7 = x7 * r7 * f7;
            a0 += ((v0 + v1) + (v2 + v3)) + ((v4 + v5) + (v6 + v7));
            a1x += ((v0 * RLf(w0.w, k)     + v1 * RLf(w0.w, k + 1))
                  + (v2 * RLf(w0.w, k + 2) + v3 * RLf(w0.w, k + 3)))
                 + ((v4 * RLf(w0.w, k + 4) + v5 * RLf(w0.w, k + 5))
                  + (v6 * RLf(w0.w, k + 6) + v7 * RLf(w0.w, k + 7)));
            a1y += ((v0 * RLf(w1.x, k)     + v1 * RLf(w1.x, k + 1))
                  + (v2 * RLf(w1.x, k + 2) + v3 * RLf(w1.x, k + 3)))
                 + ((v4 * RLf(w1.x, k + 4) + v5 * RLf(w1.x, k + 5))
                  + (v6 * RLf(w1.x, k + 6) + v7 * RLf(w1.x, k + 7)));
            a1z += ((v0 * RLf(w1.y, k)     + v1 * RLf(w1.y, k + 1))
                  + (v2 * RLf(w1.y, k + 2) + v3 * RLf(w1.y, k + 3)))
                 + ((v4 * RLf(w1.y, k + 4) + v5 * RLf(w1.y, k + 5))
                  + (v6 * RLf(w1.y, k + 6) + v7 * RLf(w1.y, k + 7)));
            h0  += ((v0 * RLf(w1.z, k)     + v1 * RLf(w1.z, k + 1))
                  + (v2 * RLf(w1.z, k + 2) + v3 * RLf(w1.z, k + 3)))
                 + ((v4 * RLf(w1.z, k + 4) + v5 * RLf(w1.z, k + 5))
                  + (v6 * RLf(w1.z, k + 6) + v7 * RLf(w1.z, k + 7)));
            h1  += ((v0 * RLf(w1.w, k)     + v1 * RLf(w1.w, k + 1))
                  + (v2 * RLf(w1.w, k + 2) + v3 * RLf(w1.w, k + 3)))
                 + ((v4 * RLf(w1.w, k + 4) + v5 * RLf(w1.w, k + 5))
                  + (v6 * RLf(w1.w, k + 6) + v7 * RLf(w1.w, k + 7)));
            h2  += ((v0 * RLf(w2.x, k)     + v1 * RLf(w2.x, k + 1))
                  + (v2 * RLf(w2.x, k + 2) + v3 * RLf(w2.x, k + 3)))
                 + ((v4 * RLf(w2.x, k + 4) + v5 * RLf(w2.x, k + 5))
                  + (v6 * RLf(w2.x, k + 6) + v7 * RLf(w2.x, k + 7)));
            h3  += ((v0 * RLf(w2.y, k)     + v1 * RLf(w2.y, k + 1))
                  + (v2 * RLf(w2.y, k + 2) + v3 * RLf(w2.y, k + 3)))
                 + ((v4 * RLf(w2.y, k + 4) + v5 * RLf(w2.y, k + 5))
                  + (v6 * RLf(w2.y, k + 6) + v7 * RLf(w2.y, k + 7)));
            h4  += ((v0 * RLf(w2.z, k)     + v1 * RLf(w2.z, k + 1))
                  + (v2 * RLf(w2.z, k + 2) + v3 * RLf(w2.z, k + 3)))
                 + ((v4 * RLf(w2.z, k + 4) + v5 * RLf(w2.z, k + 5))
                  + (v6 * RLf(w2.z, k + 6) + v7 * RLf(w2.z, k + 7)));
        }
        for (; k + 3 < m; k += 4) {
            int e0 = RLi(w0.x, k),     e1 = RLi(w0.x, k + 1);
            int e2 = RLi(w0.x, k + 2), e3 = RLi(w0.x, k + 3);
            int j0 = RLi(w0.y, k),     j1 = RLi(w0.y, k + 1);
            int j2 = RLi(w0.y, k + 2), j3 = RLi(w0.y, k + 3);
            float x0 = xp[(size_t)j0 * 64 + p], r0 = rbf[(size_t)e0 * 64 + p];
            float x1 = xp[(size_t)j1 * 64 + p], r1 = rbf[(size_t)e1 * 64 + p];
            float x2 = xp[(size_t)j2 * 64 + p], r2 = rbf[(size_t)e2 * 64 + p];
            float x3 = xp[(size_t)j3 * 64 + p], r3 = rbf[(size_t)e3 * 64 + p];
            float f0 = RLf(w0.z, k),     f1 = RLf(w0.z, k + 1);
            float f2 = RLf(w0.z, k + 2), f3 = RLf(w0.z, k + 3);
            float v0 = x0 * r0 * f0, v1 = x1 * r1 * f1;
            float v2 = x2 * r2 * f2, v3 = x3 * r3 * f3;
            a0 += (v0 + v1) + (v2 + v3);
            a1x += v0 * RLf(w0.w, k)     + v1 * RLf(w0.w, k + 1)
                 + v2 * RLf(w0.w, k + 2) + v3 * RLf(w0.w, k + 3);
            a1y += v0 * RLf(w1.x, k)     + v1 * RLf(w1.x, k + 1)
                 + v2 * RLf(w1.x, k + 2) + v3 * RLf(w1.x, k + 3);
            a1z += v0 * RLf(w1.y, k)     + v1 * RLf(w1.y, k + 1)
                 + v2 * RLf(w1.y, k + 2) + v3 * RLf(w1.y, k + 3);
            h0  += v0 * RLf(w1.z, k)     + v1 * RLf(w1.z, k + 1)
                 + v2 * RLf(w1.z, k + 2) + v3 * RLf(w1.z, k + 3);
            h1  += v0 * RLf(w1.w, k)     + v1 * RLf(w1.w, k + 1)
                 + v2 * RLf(w1.w, k + 2) + v3 * RLf(w1.w, k + 3);
            h2  += v0 * RLf(w2.x, k)     + v1 * RLf(w2.x, k + 1)
                 + v2 * RLf(w2.x, k + 2) + v3 * RLf(w2.x, k + 3);
            h3  += v0 * RLf(w2.y, k)     + v1 * RLf(w2.y, k + 1)
                 + v2 * RLf(w2.y, k + 2) + v3 * RLf(w2.y, k + 3);
            h4  += v0 * RLf(w2.z, k)     + v1 * RLf(w2.z, k + 1)
                 + v2 * RLf(w2.z, k + 2) + v3 * RLf(w2.z, k + 3);
        }
        for (; k < m; k++) {
            int e0 = RLi(w0.x, k);
            int j0 = RLi(w0.y, k);
            float f0 = RLf(w0.z, k);
            float v0 = xp[(size_t)j0 * 64 + p] * rbf[(size_t)e0 * 64 + p] * f0;
            a0 += v0;
            a1x += v0 * RLf(w0.w, k);
            a1y += v0 * RLf(w1.x, k);
            a1z += v0 * RLf(w1.y, k);
            h0  += v0 * RLf(w1.z, k);
            h1  += v0 * RLf(w1.w, k);
            h2  += v0 * RLf(w2.x, k);
            h3  += v0 * RLf(w2.y, k);
            h4  += v0 * RLf(w2.z, k);
        }
    }

    // epilogue: A-tile values (x-multiplied), hi/lo bf16, in k_node layout
    float xv = xp[(size_t)n * 64 + p];
    float vals[9] = {xv * a0, xv * a1x, xv * a1y, xv * a1z,
                     xv * h0, xv * h1, xv * h2, xv * h3, xv * h4};
    size_t b9 = (size_t)(n >> 4) * 9216 + (size_t)(n & 15) * 64 + p;
#pragma unroll
    for (int m = 0; m < 9; m++) {
        unsigned short hh = f2bf(vals[m]);
        aggHi[b9 + m * 1024] = hh;
        aggLo[b9 + m * 1024] = f2bf(vals[m] - ubf(hh));
    }
}

// ---------------------------------------------------------------------------
// Stage C1 (proven R12): A-tiles pre-built in global; staging is uint4 copy.
// ---------------------------------------------------------------------------
__global__ __launch_bounds__(256, 3) void k_node(
    const unsigned short* __restrict__ aggHi, const unsigned short* __restrict__ aggLo,
    const unsigned short* __restrict__ Wu0h, const unsigned short* __restrict__ Wu0l,
    const unsigned short* __restrict__ Wu1h, const unsigned short* __restrict__ Wu1l,
    const unsigned short* __restrict__ Wuhh, const unsigned short* __restrict__ Wuhl,
    const float* __restrict__ bu0, unsigned short* __restrict__ node, int N)
{
    __shared__ __align__(16) unsigned short Ahi[9 * 16 * 72];
    __shared__ __align__(16) unsigned short Alo[9 * 16 * 72];

    int n0 = blockIdx.x * 16;
    int tid = threadIdx.x;
    int lane = tid & 63;
    int w = tid >> 6;          // wave -> col group
    int lcol = lane & 15;
    int quad = lane >> 4;
    int kq = quad * 8;

    // copy pre-built tiles: 144 rows x 64 shorts (=8 uint4) each, per array
    size_t gbase = (size_t)blockIdx.x * 9216;
    for (int t = tid; t < 1152; t += 256) {
        int row = t >> 3, c8 = t & 7;
        int n = n0 + (row & 15);
        uint4 v = {0u, 0u, 0u, 0u};
        if (n < N) v = *(const uint4*)&aggHi[gbase + (size_t)row * 64 + c8 * 8];
        *(uint4*)&Ahi[row * 72 + c8 * 8] = v;
    }
    for (int t = tid; t < 1152; t += 256) {
        int row = t >> 3, c8 = t & 7;
        int n = n0 + (row & 15);
        uint4 v = {0u, 0u, 0u, 0u};
        if (n < N) v = *(const uint4*)&aggLo[gbase + (size_t)row * 64 + c8 * 8];
        *(uint4*)&Alo[row * 72 + c8 * 8] = v;
    }
    __syncthreads();

    // ---- G0: l0 = a0 @ Wu0 + bu0 ----
    {
        bf16x8 bh[2][2], bl[2][2];
#pragma unroll
        for (int ks = 0; ks < 2; ks++)
#pragma unroll
            for (int t = 0; t < 2; t++) {
                size_t bi = ((size_t)((ks * 8 + w * 2 + t) * 64 + lane)) * 8;
                bh[ks][t] = *(const bf16x8*)&Wu0h[bi];
                bl[ks][t] = *(const bf16x8*)&Wu0l[bi];
            }
        f32x4 acc[2];
        acc[0] = (f32x4){0.f, 0.f, 0.f, 0.f};
        acc[1] = (f32x4){0.f, 0.f, 0.f, 0.f};
#pragma unroll
        for (int ks = 0; ks < 2; ks++) {
            bf16x8 ah = *(const bf16x8*)&Ahi[lcol * 72 + ks * 32 + kq];
            bf16x8 al = *(const bf16x8*)&Alo[lcol * 72 + ks * 32 + kq];
#pragma unroll
            for (int t = 0; t < 2; t++) {
                acc[t] = __builtin_amdgcn_mfma_f32_16x16x32_bf16(ah, bh[ks][t], acc[t], 0, 0, 0);
                acc[t] = __builtin_amdgcn_mfma_f32_16x16x32_bf16(ah, bl[ks][t], acc[t], 0, 0, 0);
                acc[t] = __builtin_amdgcn_mfma_f32_16x16x32_bf16(al, bh[ks][t], acc[t], 0, 0, 0);
            }
        }
#pragma unroll
        for (int t = 0; t < 2; t++) {
            int col = w * 32 + t * 16 + lcol;
            float bb = bu0[col];
#pragma unroll
            for (int q = 0; q < 4; q++) {
                int n = n0 + quad * 4 + q;
                if (n < N) node[(size_t)n * 384 + col] = f2bf(acc[t][q] + bb);
            }
        }
    }

    // ---- G1: l1 = sum_c ((a1_c @ Wu1))^2 ----
    {
        bf16x8 bh[2][2], bl[2][2];
#pragma unroll
        for (int ks = 0; ks < 2; ks++)
#pragma unroll
            for (int t = 0; t < 2; t++) {
                size_t bi = ((size_t)((ks * 8 + w * 2 + t) * 64 + lane)) * 8;
                bh[ks][t] = *(const bf16x8*)&Wu1h[bi];
                bl[ks][t] = *(const bf16x8*)&Wu1l[bi];
            }
        f32x4 S[2];
        S[0] = (f32x4){0.f, 0.f, 0.f, 0.f};
        S[1] = (f32x4){0.f, 0.f, 0.f, 0.f};
#pragma unroll
        for (int c = 0; c < 3; c++) {
            f32x4 d[2];
            d[0] = (f32x4){0.f, 0.f, 0.f, 0.f};
            d[1] = (f32x4){0.f, 0.f, 0.f, 0.f};
            int abase = (1 + c) * (16 * 72);
#pragma unroll
            for (int ks = 0; ks < 2; ks++) {
                bf16x8 ah = *(const bf16x8*)&Ahi[abase + lcol * 72 + ks * 32 + kq];
                bf16x8 al = *(const bf16x8*)&Alo[abase + lcol * 72 + ks * 32 + kq];
#pragma unroll
                for (int t = 0; t < 2; t++) {
                    d[t] = __builtin_amdgcn_mfma_f32_16x16x32_bf16(ah, bh[ks][t], d[t], 0, 0, 0);
                    d[t] = __builtin_amdgcn_mfma_f32_16x16x32_bf16(ah, bl[ks][t], d[t], 0, 0, 0);
                    d[t] = __builtin_amdgcn_mfma_f32_16x16x32_bf16(al, bh[ks][t], d[t], 0, 0, 0);
                }
            }
            S[0] += d[0] * d[0];
            S[1] += d[1] * d[1];
        }
#pragma unroll
        for (int t = 0; t < 2; t++) {
            int col = w * 32 + t * 16 + lcol;
#pragma unroll
            for (int q = 0; q < 4; q++) {
                int n = n0 + quad * 4 + q;
                if (n < N) node[(size_t)n * 384 + 128 + col] = f2bf(S[t][q]);
            }
        }
    }

    // ---- G2: lh = sum_c ((ah_c @ Wuh))^2 ----
    {
        bf16x8 bh[2][2], bl[2][2];
#pragma unroll
        for (int ks = 0; ks < 2; ks++)
#pragma unroll
            for (int t = 0; t < 2; t++) {
                size_t bi = ((size_t)((ks * 8 + w * 2 + t) * 64 + lane)) * 8;
                bh[ks][t] = *(const bf16x8*)&Wuhh[bi];
                bl[ks][t] = *(const bf16x8*)&Wuhl[bi];
            }
        f32x4 S[2];
        S[0] = (f32x4){0.f, 0.f, 0.f, 0.f};
        S[1] = (f32x4){0.f, 0.f, 0.f, 0.f};
#pragma unroll
        for (int c = 0; c < 5; c++) {
            f32x4 d[2];
            d[0] = (f32x4){0.f, 0.f, 0.f, 0.f};
            d[1] = (f32x4){0.f, 0.f, 0.f, 0.f};
            int abase = (4 + c) * (16 * 72);
#pragma unroll
            for (int ks = 0; ks < 2; ks++) {
                bf16x8 ah = *(const bf16x8*)&Ahi[abase + lcol * 72 + ks * 32 + kq];
                bf16x8 al = *(const bf16x8*)&Alo[abase + lcol * 72 + ks * 32 + kq];
#pragma unroll
                for (int t = 0; t < 2; t++) {
                    d[t] = __builtin_amdgcn_mfma_f32_16x16x32_bf16(ah, bh[ks][t], d[t], 0, 0, 0);
                    d[t] = __builtin_amdgcn_mfma_f32_16x16x32_bf16(ah, bl[ks][t], d[t], 0, 0, 0);
                    d[t] = __builtin_amdgcn_mfma_f32_16x16x32_bf16(al, bh[ks][t], d[t], 0, 0, 0);
                }
            }
            S[0] += d[0] * d[0];
            S[1] += d[1] * d[1];
        }
#pragma unroll
        for (int t = 0; t < 2; t++) {
            int col = w * 32 + t * 16 + lcol;
#pragma unroll
            for (int q = 0; q < 4; q++) {
                int n = n0 + quad * 4 + q;
                if (n < N) node[(size_t)n * 384 + 256 + col] = f2bf(S[t][q]);
            }
        }
    }
}

// ---------------------------------------------------------------------------
// Stage C2: bf16 MFMA fused GEMM1+LN+SiLU+GEMM2 (proven R11).
// R13: LN stats via all-thread parallel reduction (8 thr/row + shfl tree)
// instead of 32-thread serial loop.
// ---------------------------------------------------------------------------
__global__ __launch_bounds__(256, 4) void k_final(
    const unsigned short* __restrict__ node, const unsigned short* __restrict__ Bsw1,
    const float* __restrict__ bn1, const float* __restrict__ lng,
    const float* __restrict__ lnb, const unsigned short* __restrict__ Bsw2,
    const float* __restrict__ bn2, const float* __restrict__ x,
    float* __restrict__ out, int N)
{
    __shared__ __align__(16) unsigned short Abf[32 * 392];   // GEMM1 A [32][384+8]; reused as GEMM2 A [32][256+8]
    __shared__ float red[32][33];
    __shared__ float red2[32][33];
    __shared__ float mstat[32][2];

    int n0 = blockIdx.x * 32;
    int tid = threadIdx.x;
    int lane = tid & 63;
    int w = tid >> 6;
    int rt = w & 1;
    int cg = w >> 1;
    int lcol = lane & 15;
    int quad = lane >> 4;
    int arow = rt * 16 + lcol;       // A-frag row this lane reads
    int kq = quad * 8;               // A/B-frag k sub-offset

    // ---- stage bf16 node tile -> Abf[32][392] (48 uint4 per row) ----
    for (int i = tid; i < 32 * 48; i += 256) {
        int r = i / 48, c8 = i - r * 48;
        int n = n0 + r;
        uint4 v = {0u, 0u, 0u, 0u};
        if (n < N) v = *(const uint4*)&node[(size_t)n * 384 + c8 * 8];
        *(uint4*)&Abf[r * 392 + c8 * 8] = v;
    }
    __syncthreads();

    // ---- GEMM1: T = node @ Wn1 ----
    f32x4 acc[8];
#pragma unroll
    for (int t = 0; t < 8; t++) acc[t] = (f32x4){0.f, 0.f, 0.f, 0.f};
    for (int ks = 0; ks < 12; ks++) {
        bf16x8 a = *(const bf16x8*)&Abf[arow * 392 + ks * 32 + kq];
        const bf16x8* bp =
            (const bf16x8*)&Bsw1[(size_t)(((ks * 16 + cg * 8) * 64) + lane) * 8];
#pragma unroll
        for (int t = 0; t < 8; t++)
            acc[t] = __builtin_amdgcn_mfma_f32_16x16x32_bf16(a, bp[t * 64], acc[t], 0, 0, 0);
    }

    // ---- per-row LN partials from accumulators ----
    float bias[8];
#pragma unroll
    for (int t = 0; t < 8; t++) bias[t] = bn1[cg * 128 + t * 16 + lcol];
#pragma unroll
    for (int q = 0; q < 4; q++) {
        float s = 0.f, s2 = 0.f;
#pragma unroll
        for (int t = 0; t < 8; t++) {
            float v = acc[t][q] + bias[t];
            s += v; s2 += v * v;
        }
        int row = rt * 16 + quad * 4 + q;
        red[row][cg * 16 + lcol] = s;
        red2[row][cg * 16 + lcol] = s2;
    }
    __syncthreads();
    {
        // parallel stats: 8 threads/row, 4 partials each, shfl tree
        int row = tid >> 3, g = tid & 7;
        float s = 0.f, s2 = 0.f;
#pragma unroll
        for (int u = 0; u < 4; u++) {
            s  += red[row][g * 4 + u];
            s2 += red2[row][g * 4 + u];
        }
        s  += __shfl_down(s, 4);  s2 += __shfl_down(s2, 4);
        s  += __shfl_down(s, 2);  s2 += __shfl_down(s2, 2);
        s  += __shfl_down(s, 1);  s2 += __shfl_down(s2, 1);
        if (g == 0) {
            float mn = s * (1.f / 256.f);
            float var = s2 * (1.f / 256.f) - mn * mn;
            mstat[row][0] = mn;
            mstat[row][1] = rsqrtf(var + 1e-5f);
        }
    }
    __syncthreads();

    // ---- LN + SiLU, write h as bf16 GEMM2 A-tile [32][264] ----
#pragma unroll
    for (int t = 0; t < 8; t++) {
        int col = cg * 128 + t * 16 + lcol;
        float gg = lng[col], bb = lnb[col];
#pragma unroll
        for (int q = 0; q < 4; q++) {
            int row = rt * 16 + quad * 4 + q;
            float z = (acc[t][q] + bias[t] - mstat[row][0]) * mstat[row][1] * gg + bb;
            float h = z / (1.f + __expf(-z));
            Abf[row * 264 + col] = f2bf(h);
        }
    }
    __syncthreads();

    // ---- GEMM2: out = h @ Wn2 + bn2 + x ----
    f32x4 o[8];
#pragma unroll
    for (int t = 0; t < 8; t++) o[t] = (f32x4){0.f, 0.f, 0.f, 0.f};
    for (int ks = 0; ks < 8; ks++) {
        bf16x8 a = *(const bf16x8*)&Abf[arow * 264 + ks * 32 + kq];
        const bf16x8* bp =
            (const bf16x8*)&Bsw2[(size_t)(((ks * 16 + cg * 8) * 64) + lane) * 8];
#pragma unroll
        for (int t = 0; t < 8; t++)
            o[t] = __builtin_amdgcn_mfma_f32_16x16x32_bf16(a, bp[t * 64], o[t], 0, 0, 0);
    }
#pragma unroll
    for (int t = 0; t < 8; t++) {
        int col = cg * 128 + t * 16 + lcol;
        float ob = bn2[col];
#pragma unroll
        for (int q = 0; q < 4; q++) {
            int row = rt * 16 + quad * 4 + q;
            int n = n0 + row;
            if (n < N)
                out[(size_t)n * 256 + col] = o[t][q] + ob + x[(size_t)n * 256 + col];
        }
    }
}

// ---------------------------------------------------------------------------
extern "C" void kernel_launch(void* const* d_in, const int* in_sizes, int n_in,
                              void* d_out, int out_size, void* d_ws, size_t ws_size,
                              hipStream_t stream)
{
    const float* x      = (const float*)d_in[0];
    const float* rbf    = (const float*)d_in[1];
    const float* factor = (const float*)d_in[2];
    const float* sph0   = (const float*)d_in[3];
    const float* sph1   = (const float*)d_in[4];
    const float* Wd     = (const float*)d_in[5];
    const float* bd     = (const float*)d_in[6];
    const float* Wu0    = (const float*)d_in[7];
    const float* bu0    = (const float*)d_in[8];
    const float* Wu1    = (const float*)d_in[9];
    const float* Wuh    = (const float*)d_in[10];
    const float* Wn1    = (const float*)d_in[11];
    const float* bn1    = (const float*)d_in[12];
    const float* lng    = (const float*)d_in[13];
    const float* lnb    = (const float*)d_in[14];
    const float* Wn2    = (const float*)d_in[15];
    const float* bn2    = (const float*)d_in[16];
    const int*   jidx   = (const int*)d_in[17];
    const int*   iidx   = (const int*)d_in[18];
    float* out = (float*)d_out;

    int N = in_sizes[0] / 256;
    int E = in_sizes[17];
    int nblk = (N + 15) / 16;

    float* ws   = (float*)d_ws;
    float* xp   = ws;                                  // [N,64] f32
    float* aggF = xp + (size_t)N * 64;                 // A-tile region: nblk*9216 floats
    unsigned short* aggHi = (unsigned short*)aggF;     // [nblk*9216] bf16
    unsigned short* aggLo = aggHi + (size_t)nblk * 9216;
    float* nodeF = aggF + (size_t)nblk * 9216;         // node region (N*384 f32 worth)
    unsigned short* nodeB = (unsigned short*)nodeF;    // bf16 node [N,384]
    // swizzled bf16 weights after the node region
    unsigned short* Bsw1 = (unsigned short*)(nodeF + (size_t)N * 384); // 12*16*64*8
    unsigned short* Bsw2 = Bsw1 + 12 * 16 * 64 * 8;                    // 8*16*64*8
    unsigned short* Wu0h_s = Bsw2 + 8 * 16 * 64 * 8;
    unsigned short* Wu0l_s = Wu0h_s + 64 * 128;
    unsigned short* Wu1h_s = Wu0l_s + 64 * 128;
    unsigned short* Wu1l_s = Wu1h_s + 64 * 128;
    unsigned short* Wuhh_s = Wu1l_s + 64 * 128;
    unsigned short* Wuhl_s = Wuhh_s + 64 * 128;
    unsigned short* Wdh_s  = Wuhl_s + 64 * 128;
    unsigned short* Wdl_s  = Wdh_s + 256 * 64;

    // CSR scratch + packed edge records aliased onto the node region (dead
    // before k_node writes node; k_gather fully consumes packed first).
    int* counts  = (int*)nodeF;              // [N+1]
    int* rowptr  = counts + (N + 1);         // [N+1]
    int* cursor  = rowptr + (N + 1);         // [N]
    float* packed = nodeF + 131072;          // [E,12] CSR-ordered edge records

    int nDown = (N + 31) / 32;
    int nHist = (E + 255) / 256;

    k_prep<<<dim3(125), dim3(256), 0, stream>>>(
        Wn1, Bsw1, Wn2, Bsw2, Wu0, Wu0h_s, Wu0l_s, Wu1, Wu1h_s, Wu1l_s,
        Wuh, Wuhh_s, Wuhl_s, Wd, Wdh_s, Wdl_s, counts, N);
    k_down_hist<<<dim3(nDown + nHist), dim3(256), 0, stream>>>(
        x, Wdh_s, Wdl_s, bd, xp, iidx, counts, N, E, nDown);
    k_scan<<<dim3(1), dim3(1024), 0, stream>>>(counts, rowptr, cursor, N);
    k_scatter_pack<<<dim3(nHist), dim3(256), 0, stream>>>(
        iidx, jidx, factor, sph0, sph1, cursor, packed, E);
    k_gather<<<dim3((N + 3) / 4), dim3(256), 0, stream>>>(
        xp, rbf, packed, rowptr, aggHi, aggLo, N);
    k_node<<<dim3(nblk), dim3(256), 0, stream>>>(
        aggHi, aggLo, Wu0h_s, Wu0l_s, Wu1h_s, Wu1l_s, Wuhh_s, Wuhl_s,
        bu0, nodeB, N);
    k_final<<<dim3((N + 31) / 32), dim3(256), 0, stream>>>(
        nodeB, Bsw1, bn1, lng, lnb, Bsw2, bn2, x, out, N);
}

// Round 10
// 445.832 us; speedup vs baseline: 1.7883x; 1.0051x over previous
//
#include <hip/hip_runtime.h>
#include <hip/hip_bf16.h>

typedef __attribute__((ext_vector_type(8))) short bf16x8;
typedef __attribute__((ext_vector_type(4))) float f32x4;

__device__ __forceinline__ unsigned short f2bf(float f) {
    unsigned u = __float_as_uint(f);
    return (unsigned short)((u + 0x7FFF + ((u >> 16) & 1)) >> 16);  // RNE
}
__device__ __forceinline__ unsigned pack2(float a, float b) {
    return (unsigned)f2bf(a) | ((unsigned)f2bf(b) << 16);
}
__device__ __forceinline__ float ubf(unsigned short h) {
    return __uint_as_float((unsigned)h << 16);
}
// register broadcast: lane k (uniform) -> all lanes, result in SGPR
__device__ __forceinline__ int RLi(float v, int k) {
    return __builtin_amdgcn_readlane(__float_as_int(v), k);
}
__device__ __forceinline__ float RLf(float v, int k) {
    return __uint_as_float((unsigned)__builtin_amdgcn_readlane(__float_as_int(v), k));
}

// ---------------------------------------------------------------------------
// k_prep: all one-time weight swizzles + counts zeroing in ONE launch.
// (Proven R10.)
// ---------------------------------------------------------------------------
__device__ void swz_body(const float* __restrict__ W,
                         unsigned short* __restrict__ Bsw, int K, int idx)
{
    int total = (K >> 5) * 1024;            // (K/32) * 16 ct * 64 lanes
    if (idx >= total) return;
    int lane = idx & 63;
    int ct = (idx >> 6) & 15;
    int ks = idx >> 10;
    int col = ct * 16 + (lane & 15);
    int kbase = (ks << 5) + ((lane >> 4) << 3);
    const float* p = &W[(size_t)kbase * 256 + col];
    uint4 o;
    o.x = pack2(p[0 * 256], p[1 * 256]);
    o.y = pack2(p[2 * 256], p[3 * 256]);
    o.z = pack2(p[4 * 256], p[5 * 256]);
    o.w = pack2(p[6 * 256], p[7 * 256]);
    *(uint4*)&Bsw[(size_t)idx * 8] = o;
}

__device__ void swz_split_body(const float* __restrict__ W,
                               unsigned short* __restrict__ Bh,
                               unsigned short* __restrict__ Bl,
                               int K, int C, int idx)
{
    int ct_n = C >> 4;
    int total = (K >> 5) * ct_n * 64;
    if (idx >= total) return;
    int per_ks = ct_n * 64;
    int ks = idx / per_ks;
    int rem = idx - ks * per_ks;
    int ct = rem >> 6;
    int lane = rem & 63;
    int col = ct * 16 + (lane & 15);
    int kbase = (ks << 5) + ((lane >> 4) << 3);
    const float* p = &W[(size_t)kbase * C + col];
    unsigned short hs[8], ls[8];
#pragma unroll
    for (int j = 0; j < 8; j++) {
        float wv = p[(size_t)j * C];
        unsigned short h = f2bf(wv);
        hs[j] = h;
        ls[j] = f2bf(wv - ubf(h));
    }
    uint4 oh, ol;
    oh.x = (unsigned)hs[0] | ((unsigned)hs[1] << 16);
    oh.y = (unsigned)hs[2] | ((unsigned)hs[3] << 16);
    oh.z = (unsigned)hs[4] | ((unsigned)hs[5] << 16);
    oh.w = (unsigned)hs[6] | ((unsigned)hs[7] << 16);
    ol.x = (unsigned)ls[0] | ((unsigned)ls[1] << 16);
    ol.y = (unsigned)ls[2] | ((unsigned)ls[3] << 16);
    ol.z = (unsigned)ls[4] | ((unsigned)ls[5] << 16);
    ol.w = (unsigned)ls[6] | ((unsigned)ls[7] << 16);
    *(uint4*)&Bh[(size_t)idx * 8] = oh;
    *(uint4*)&Bl[(size_t)idx * 8] = ol;
}

__global__ __launch_bounds__(256) void k_prep(
    const float* __restrict__ Wn1, unsigned short* __restrict__ Bsw1,
    const float* __restrict__ Wn2, unsigned short* __restrict__ Bsw2,
    const float* __restrict__ Wu0, unsigned short* __restrict__ Wu0h, unsigned short* __restrict__ Wu0l,
    const float* __restrict__ Wu1, unsigned short* __restrict__ Wu1h, unsigned short* __restrict__ Wu1l,
    const float* __restrict__ Wuh, unsigned short* __restrict__ Wuhh, unsigned short* __restrict__ Wuhl,
    const float* __restrict__ Wd, unsigned short* __restrict__ Wdh, unsigned short* __restrict__ Wdl,
    int* __restrict__ counts, int N)
{
    int b = blockIdx.x;
    int tid = threadIdx.x;
    if (b < 48)       swz_body(Wn1, Bsw1, 384, b * 256 + tid);
    else if (b < 80)  swz_body(Wn2, Bsw2, 256, (b - 48) * 256 + tid);
    else if (b < 84)  swz_split_body(Wu0, Wu0h, Wu0l, 64, 128, (b - 80) * 256 + tid);
    else if (b < 88)  swz_split_body(Wu1, Wu1h, Wu1l, 64, 128, (b - 84) * 256 + tid);
    else if (b < 92)  swz_split_body(Wuh, Wuhh, Wuhl, 64, 128, (b - 88) * 256 + tid);
    else if (b < 100) swz_split_body(Wd, Wdh, Wdl, 256, 64, (b - 92) * 256 + tid);
    else {
        for (int i = (b - 100) * 256 + tid; i < N + 1; i += 25 * 256)
            counts[i] = 0;
    }
}

// ---------------------------------------------------------------------------
// k_hist: standalone edge histogram (R14: unfused so scan isn't blocked by
// the long down-projection; also no dead LDS reservation -> full occupancy).
// ---------------------------------------------------------------------------
__global__ __launch_bounds__(256) void k_hist(
    const int* __restrict__ iidx, int* __restrict__ counts, int E)
{
    int e = blockIdx.x * 256 + threadIdx.x;
    if (e < E) atomicAdd(&counts[iidx[e]], 1);
}

// ---------------------------------------------------------------------------
// k_scan: CSR prefix (proven).
// ---------------------------------------------------------------------------
__global__ __launch_bounds__(1024) void k_scan(
    const int* __restrict__ counts, int* __restrict__ rowptr,
    int* __restrict__ cursor, int N)
{
    __shared__ int part[1024];
    int t = threadIdx.x;
    int chunk = (N + 1023) / 1024;
    int beg = t * chunk;
    int end = min(beg + chunk, N);
    int s = 0;
    for (int i = beg; i < end; i++) s += counts[i];
    part[t] = s;
    __syncthreads();
    for (int off = 1; off < 1024; off <<= 1) {
        int v = (t >= off) ? part[t - off] : 0;
        __syncthreads();
        part[t] += v;
        __syncthreads();
    }
    int run = (t == 0) ? 0 : part[t - 1];
    for (int i = beg; i < end; i++) {
        rowptr[i] = run;
        cursor[i] = run;
        run += counts[i];
    }
    if (t == 1023) rowptr[N] = part[1023];
}

// ---------------------------------------------------------------------------
// R14: k_down + k_scatter_pack fused (independent: down needs only prep's
// Wd frags, scatter needs only scan's cursor; both ready at launch; outputs
// disjoint xpB vs packed). down now overlaps scatter instead of blocking scan.
// R14: xp output stored as bf16 (xpB) -> 3.2 MB, fits per-XCD L2 for the
// gather's random row reads.
// ---------------------------------------------------------------------------
__global__ __launch_bounds__(256, 4) void k_down_scatter(
    const float* __restrict__ x, const unsigned short* __restrict__ Wdh,
    const unsigned short* __restrict__ Wdl, const float* __restrict__ bd,
    unsigned short* __restrict__ xpB,
    const int* __restrict__ iidx, const int* __restrict__ jidx,
    const float* __restrict__ factor, const float* __restrict__ sph0,
    const float* __restrict__ sph1, int* __restrict__ cursor,
    float* __restrict__ packed, int N, int E, int nDown)
{
    __shared__ __align__(16) unsigned short Ahi[32 * 264];
    __shared__ __align__(16) unsigned short Alo[32 * 264];

    if ((int)blockIdx.x >= nDown) {
        int e = ((int)blockIdx.x - nDown) * 256 + threadIdx.x;
        if (e < E) {
            int pos = atomicAdd(&cursor[iidx[e]], 1);
            float4 w0, w1, w2;
            w0.x = __int_as_float(e);
            w0.y = __int_as_float(jidx[e]);
            w0.z = factor[e];
            w0.w = sph1[e * 3 + 0];
            w1.x = sph1[e * 3 + 1];
            w1.y = sph1[e * 3 + 2];
            w1.z = sph0[e * 5 + 0];
            w1.w = sph0[e * 5 + 1];
            w2.x = sph0[e * 5 + 2];
            w2.y = sph0[e * 5 + 3];
            w2.z = sph0[e * 5 + 4];
            w2.w = 0.f;
            float4* q = (float4*)&packed[(size_t)pos * 12];
            q[0] = w0; q[1] = w1; q[2] = w2;
        }
        return;
    }

    int n0 = blockIdx.x * 32;
    int tid = threadIdx.x;
    int lane = tid & 63;
    int w = tid >> 6;
    int rt = w & 1;
    int cg = w >> 1;
    int lcol = lane & 15;
    int quad = lane >> 4;
    int kq = quad * 8;

    for (int t = tid; t < 32 * 64; t += 256) {
        int r = t >> 6, c4 = t & 63;
        int n = n0 + r;
        float4 v = {0.f, 0.f, 0.f, 0.f};
        if (n < N) v = *(const float4*)&x[(size_t)n * 256 + c4 * 4];
        unsigned short hx = f2bf(v.x), hy = f2bf(v.y);
        unsigned short hz = f2bf(v.z), hw = f2bf(v.w);
        uint2 oh, ol;
        oh.x = (unsigned)hx | ((unsigned)hy << 16);
        oh.y = (unsigned)hz | ((unsigned)hw << 16);
        ol.x = (unsigned)f2bf(v.x - ubf(hx)) | ((unsigned)f2bf(v.y - ubf(hy)) << 16);
        ol.y = (unsigned)f2bf(v.z - ubf(hz)) | ((unsigned)f2bf(v.w - ubf(hw)) << 16);
        *(uint2*)&Ahi[r * 264 + c4 * 4] = oh;
        *(uint2*)&Alo[r * 264 + c4 * 4] = ol;
    }
    __syncthreads();

    int arow = rt * 16 + lcol;
    f32x4 acc[2];
    acc[0] = (f32x4){0.f, 0.f, 0.f, 0.f};
    acc[1] = (f32x4){0.f, 0.f, 0.f, 0.f};
#pragma unroll
    for (int ks = 0; ks < 8; ks++) {
        bf16x8 ah = *(const bf16x8*)&Ahi[arow * 264 + ks * 32 + kq];
        bf16x8 al = *(const bf16x8*)&Alo[arow * 264 + ks * 32 + kq];
#pragma unroll
        for (int t = 0; t < 2; t++) {
            int ct = cg * 2 + t;
            size_t bi = ((size_t)((ks * 4 + ct) * 64 + lane)) * 8;
            bf16x8 bh = *(const bf16x8*)&Wdh[bi];
            bf16x8 bl = *(const bf16x8*)&Wdl[bi];
            acc[t] = __builtin_amdgcn_mfma_f32_16x16x32_bf16(ah, bh, acc[t], 0, 0, 0);
            acc[t] = __builtin_amdgcn_mfma_f32_16x16x32_bf16(ah, bl, acc[t], 0, 0, 0);
            acc[t] = __builtin_amdgcn_mfma_f32_16x16x32_bf16(al, bh, acc[t], 0, 0, 0);
        }
    }
#pragma unroll
    for (int t = 0; t < 2; t++) {
        int col = cg * 32 + t * 16 + lcol;
        float bb = bd[col];
#pragma unroll
        for (int q = 0; q < 4; q++) {
            int row = rt * 16 + quad * 4 + q;
            int n = n0 + row;
            if (n < N) xpB[(size_t)n * 64 + col] = f2bf(acc[t][q] + bb);
        }
    }
}

// ---------------------------------------------------------------------------
// k_gather (R14): xp reads are bf16 (ubf on load); structure proven R13.
// Epilogue stores hi/lo bf16 A-tiles in k_node layout (proven R12).
// ---------------------------------------------------------------------------
__global__ __launch_bounds__(256) void k_gather(
    const unsigned short* __restrict__ xpB, const float* __restrict__ rbf,
    const float* __restrict__ packed, const int* __restrict__ rowptr,
    unsigned short* __restrict__ aggHi, unsigned short* __restrict__ aggLo,
    int N)
{
    int n = blockIdx.x * 4 + (threadIdx.x >> 6);
    if (n >= N) return;
    int p = threadIdx.x & 63;
    int beg = rowptr[n], end = rowptr[n + 1];

    float a0 = 0.f;
    float a1x = 0.f, a1y = 0.f, a1z = 0.f;
    float h0 = 0.f, h1 = 0.f, h2 = 0.f, h3 = 0.f, h4 = 0.f;

    for (int base = beg; base < end; base += 64) {
        int m = end - base;
        if (m > 64) m = 64;
        float4 w0 = {0.f, 0.f, 0.f, 0.f};
        float4 w1 = {0.f, 0.f, 0.f, 0.f};
        float4 w2 = {0.f, 0.f, 0.f, 0.f};
        if (base + p < end) {
            const float4* q = (const float4*)&packed[(size_t)(base + p) * 12];
            w0 = q[0]; w1 = q[1]; w2 = q[2];
        }
        int k = 0;
        for (; k + 7 < m; k += 8) {
            int e0 = RLi(w0.x, k),     e1 = RLi(w0.x, k + 1);
            int e2 = RLi(w0.x, k + 2), e3 = RLi(w0.x, k + 3);
            int e4 = RLi(w0.x, k + 4), e5 = RLi(w0.x, k + 5);
            int e6 = RLi(w0.x, k + 6), e7 = RLi(w0.x, k + 7);
            int j0 = RLi(w0.y, k),     j1 = RLi(w0.y, k + 1);
            int j2 = RLi(w0.y, k + 2), j3 = RLi(w0.y, k + 3);
            int j4 = RLi(w0.y, k + 4), j5 = RLi(w0.y, k + 5);
            int j6 = RLi(w0.y, k + 6), j7 = RLi(w0.y, k + 7);
            float x0 = ubf(xpB[(size_t)j0 * 64 + p]), r0 = rbf[(size_t)e0 * 64 + p];
            float x1 = ubf(xpB[(size_t)j1 * 64 + p]), r1 = rbf[(size_t)e1 * 64 + p];
            float x2 = ubf(xpB[(size_t)j2 * 64 + p]), r2 = rbf[(size_t)e2 * 64 + p];
            float x3 = ubf(xpB[(size_t)j3 * 64 + p]), r3 = rbf[(size_t)e3 * 64 + p];
            float x4 = ubf(xpB[(size_t)j4 * 64 + p]), r4 = rbf[(size_t)e4 * 64 + p];
            float x5 = ubf(xpB[(size_t)j5 * 64 + p]), r5 = rbf[(size_t)e5 * 64 + p];
            float x6 = ubf(xpB[(size_t)j6 * 64 + p]), r6 = rbf[(size_t)e6 * 64 + p];
            float x7 = ubf(xpB[(size_t)j7 * 64 + p]), r7 = rbf[(size_t)e7 * 64 + p];
            float f0 = RLf(w0.z, k),     f1 = RLf(w0.z, k + 1);
            float f2 = RLf(w0.z, k + 2), f3 = RLf(w0.z, k + 3);
            float f4 = RLf(w0.z, k + 4), f5 = RLf(w0.z, k + 5);
            float f6 = RLf(w0.z, k + 6), f7 = RLf(w0.z, k + 7);
            float v0 = x0 * r0 * f0, v1 = x1 * r1 * f1;
            float v2 = x2 * r2 * f2, v3 = x3 * r3 * f3;
            float v4 = x4 * r4 * f4, v5 = x5 * r5 * f5;
            float v6 = x6 * r6 * f6, v7 = x7 * r7 * f7;
            a0 += ((v0 + v1) + (v2 + v3)) + ((v4 + v5) + (v6 + v7));
            a1x += ((v0 * RLf(w0.w, k)     + v1 * RLf(w0.w, k + 1))
                  + (v2 * RLf(w0.w, k + 2) + v3 * RLf(w0.w, k + 3)))
                 + ((v4 * RLf(w0.w, k + 4) + v5 * RLf(w0.w, k + 5))
                  + (v6 * RLf(w0.w, k + 6) + v7 * RLf(w0.w, k + 7)));
            a1y += ((v0 * RLf(w1.x, k)     + v1 * RLf(w1.x, k + 1))
                  + (v2 * RLf(w1.x, k + 2) + v3 * RLf(w1.x, k + 3)))
                 + ((v4 * RLf(w1.x, k + 4) + v5 * RLf(w1.x, k + 5))
                  + (v6 * RLf(w1.x, k + 6) + v7 * RLf(w1.x, k + 7)));
            a1z += ((v0 * RLf(w1.y, k)     + v1 * RLf(w1.y, k + 1))
                  + (v2 * RLf(w1.y, k + 2) + v3 * RLf(w1.y, k + 3)))
                 + ((v4 * RLf(w1.y, k + 4) + v5 * RLf(w1.y, k + 5))
                  + (v6 * RLf(w1.y, k + 6) + v7 * RLf(w1.y, k + 7)));
            h0  += ((v0 * RLf(w1.z, k)     + v1 * RLf(w1.z, k + 1))
                  + (v2 * RLf(w1.z, k + 2) + v3 * RLf(w1.z, k + 3)))
                 + ((v4 * RLf(w1.z, k + 4) + v5 * RLf(w1.z, k + 5))
                  + (v6 * RLf(w1.z, k + 6) + v7 * RLf(w1.z, k + 7)));
            h1  += ((v0 * RLf(w1.w, k)     + v1 * RLf(w1.w, k + 1))
                  + (v2 * RLf(w1.w, k + 2) + v3 * RLf(w1.w, k + 3)))
                 + ((v4 * RLf(w1.w, k + 4) + v5 * RLf(w1.w, k + 5))
                  + (v6 * RLf(w1.w, k + 6) + v7 * RLf(w1.w, k + 7)));
            h2  += ((v0 * RLf(w2.x, k)     + v1 * RLf(w2.x, k + 1))
                  + (v2 * RLf(w2.x, k + 2) + v3 * RLf(w2.x, k + 3)))
                 + ((v4 * RLf(w2.x, k + 4) + v5 * RLf(w2.x, k + 5))
                  + (v6 * RLf(w2.x, k + 6) + v7 * RLf(w2.x, k + 7)));
            h3  += ((v0 * RLf(w2.y, k)     + v1 * RLf(w2.y, k + 1))
                  + (v2 * RLf(w2.y, k + 2) + v3 * RLf(w2.y, k + 3)))
                 + ((v4 * RLf(w2.y, k + 4) + v5 * RLf(w2.y, k + 5))
                  + (v6 * RLf(w2.y, k + 6) + v7 * RLf(w2.y, k + 7)));
            h4  += ((v0 * RLf(w2.z, k)     + v1 * RLf(w2.z, k + 1))
                  + (v2 * RLf(w2.z, k + 2) + v3 * RLf(w2.z, k + 3)))
                 + ((v4 * RLf(w2.z, k + 4) + v5 * RLf(w2.z, k + 5))
                  + (v6 * RLf(w2.z, k + 6) + v7 * RLf(w2.z, k + 7)));
        }
        for (; k + 3 < m; k += 4) {
            int e0 = RLi(w0.x, k),     e1 = RLi(w0.x, k + 1);
            int e2 = RLi(w0.x, k + 2), e3 = RLi(w0.x, k + 3);
            int j0 = RLi(w0.y, k),     j1 = RLi(w0.y, k + 1);
            int j2 = RLi(w0.y, k + 2), j3 = RLi(w0.y, k + 3);
            float x0 = ubf(xpB[(size_t)j0 * 64 + p]), r0 = rbf[(size_t)e0 * 64 + p];
            float x1 = ubf(xpB[(size_t)j1 * 64 + p]), r1 = rbf[(size_t)e1 * 64 + p];
            float x2 = ubf(xpB[(size_t)j2 * 64 + p]), r2 = rbf[(size_t)e2 * 64 + p];
            float x3 = ubf(xpB[(size_t)j3 * 64 + p]), r3 = rbf[(size_t)e3 * 64 + p];
            float f0 = RLf(w0.z, k),     f1 = RLf(w0.z, k + 1);
            float f2 = RLf(w0.z, k + 2), f3 = RLf(w0.z, k + 3);
            float v0 = x0 * r0 * f0, v1 = x1 * r1 * f1;
            float v2 = x2 * r2 * f2, v3 = x3 * r3 * f3;
            a0 += (v0 + v1) + (v2 + v3);
            a1x += v0 * RLf(w0.w, k)     + v1 * RLf(w0.w, k + 1)
                 + v2 * RLf(w0.w, k + 2) + v3 * RLf(w0.w, k + 3);
            a1y += v0 * RLf(w1.x, k)     + v1 * RLf(w1.x, k + 1)
                 + v2 * RLf(w1.x, k + 2) + v3 * RLf(w1.x, k + 3);
            a1z += v0 * RLf(w1.y, k)     + v1 * RLf(w1.y, k + 1)
                 + v2 * RLf(w1.y, k + 2) + v3 * RLf(w1.y, k + 3);
            h0  += v0 * RLf(w1.z, k)     + v1 * RLf(w1.z, k + 1)
                 + v2 * RLf(w1.z, k + 2) + v3 * RLf(w1.z, k + 3);
            h1  += v0 * RLf(w1.w, k)     + v1 * RLf(w1.w, k + 1)
                 + v2 * RLf(w1.w, k + 2) + v3 * RLf(w1.w, k + 3);
            h2  += v0 * RLf(w2.x, k)     + v1 * RLf(w2.x, k + 1)
                 + v2 * RLf(w2.x, k + 2) + v3 * RLf(w2.x, k + 3);
            h3  += v0 * RLf(w2.y, k)     + v1 * RLf(w2.y, k + 1)
                 + v2 * RLf(w2.y, k + 2) + v3 * RLf(w2.y, k + 3);
            h4  += v0 * RLf(w2.z, k)     + v1 * RLf(w2.z, k + 1)
                 + v2 * RLf(w2.z, k + 2) + v3 * RLf(w2.z, k + 3);
        }
        for (; k < m; k++) {
            int e0 = RLi(w0.x, k);
            int j0 = RLi(w0.y, k);
            float f0 = RLf(w0.z, k);
            float v0 = ubf(xpB[(size_t)j0 * 64 + p]) * rbf[(size_t)e0 * 64 + p] * f0;
            a0 += v0;
            a1x += v0 * RLf(w0.w, k);
            a1y += v0 * RLf(w1.x, k);
            a1z += v0 * RLf(w1.y, k);
            h0  += v0 * RLf(w1.z, k);
            h1  += v0 * RLf(w1.w, k);
            h2  += v0 * RLf(w2.x, k);
            h3  += v0 * RLf(w2.y, k);
            h4  += v0 * RLf(w2.z, k);
        }
    }

    // epilogue: A-tile values (x-multiplied), hi/lo bf16, in k_node layout
    float xv = ubf(xpB[(size_t)n * 64 + p]);
    float vals[9] = {xv * a0, xv * a1x, xv * a1y, xv * a1z,
                     xv * h0, xv * h1, xv * h2, xv * h3, xv * h4};
    size_t b9 = (size_t)(n >> 4) * 9216 + (size_t)(n & 15) * 64 + p;
#pragma unroll
    for (int m = 0; m < 9; m++) {
        unsigned short hh = f2bf(vals[m]);
        aggHi[b9 + m * 1024] = hh;
        aggLo[b9 + m * 1024] = f2bf(vals[m] - ubf(hh));
    }
}

// ---------------------------------------------------------------------------
// Stage C1 (proven R12): A-tiles pre-built in global; staging is uint4 copy.
// ---------------------------------------------------------------------------
__global__ __launch_bounds__(256, 3) void k_node(
    const unsigned short* __restrict__ aggHi, const unsigned short* __restrict__ aggLo,
    const unsigned short* __restrict__ Wu0h, const unsigned short* __restrict__ Wu0l,
    const unsigned short* __restrict__ Wu1h, const unsigned short* __restrict__ Wu1l,
    const unsigned short* __restrict__ Wuhh, const unsigned short* __restrict__ Wuhl,
    const float* __restrict__ bu0, unsigned short* __restrict__ node, int N)
{
    __shared__ __align__(16) unsigned short Ahi[9 * 16 * 72];
    __shared__ __align__(16) unsigned short Alo[9 * 16 * 72];

    int n0 = blockIdx.x * 16;
    int tid = threadIdx.x;
    int lane = tid & 63;
    int w = tid >> 6;          // wave -> col group
    int lcol = lane & 15;
    int quad = lane >> 4;
    int kq = quad * 8;

    // copy pre-built tiles: 144 rows x 64 shorts (=8 uint4) each, per array
    size_t gbase = (size_t)blockIdx.x * 9216;
    for (int t = tid; t < 1152; t += 256) {
        int row = t >> 3, c8 = t & 7;
        int n = n0 + (row & 15);
        uint4 v = {0u, 0u, 0u, 0u};
        if (n < N) v = *(const uint4*)&aggHi[gbase + (size_t)row * 64 + c8 * 8];
        *(uint4*)&Ahi[row * 72 + c8 * 8] = v;
    }
    for (int t = tid; t < 1152; t += 256) {
        int row = t >> 3, c8 = t & 7;
        int n = n0 + (row & 15);
        uint4 v = {0u, 0u, 0u, 0u};
        if (n < N) v = *(const uint4*)&aggLo[gbase + (size_t)row * 64 + c8 * 8];
        *(uint4*)&Alo[row * 72 + c8 * 8] = v;
    }
    __syncthreads();

    // ---- G0: l0 = a0 @ Wu0 + bu0 ----
    {
        bf16x8 bh[2][2], bl[2][2];
#pragma unroll
        for (int ks = 0; ks < 2; ks++)
#pragma unroll
            for (int t = 0; t < 2; t++) {
                size_t bi = ((size_t)((ks * 8 + w * 2 + t) * 64 + lane)) * 8;
                bh[ks][t] = *(const bf16x8*)&Wu0h[bi];
                bl[ks][t] = *(const bf16x8*)&Wu0l[bi];
            }
        f32x4 acc[2];
        acc[0] = (f32x4){0.f, 0.f, 0.f, 0.f};
        acc[1] = (f32x4){0.f, 0.f, 0.f, 0.f};
#pragma unroll
        for (int ks = 0; ks < 2; ks++) {
            bf16x8 ah = *(const bf16x8*)&Ahi[lcol * 72 + ks * 32 + kq];
            bf16x8 al = *(const bf16x8*)&Alo[lcol * 72 + ks * 32 + kq];
#pragma unroll
            for (int t = 0; t < 2; t++) {
                acc[t] = __builtin_amdgcn_mfma_f32_16x16x32_bf16(ah, bh[ks][t], acc[t], 0, 0, 0);
                acc[t] = __builtin_amdgcn_mfma_f32_16x16x32_bf16(ah, bl[ks][t], acc[t], 0, 0, 0);
                acc[t] = __builtin_amdgcn_mfma_f32_16x16x32_bf16(al, bh[ks][t], acc[t], 0, 0, 0);
            }
        }
#pragma unroll
        for (int t = 0; t < 2; t++) {
            int col = w * 32 + t * 16 + lcol;
            float bb = bu0[col];
#pragma unroll
            for (int q = 0; q < 4; q++) {
                int n = n0 + quad * 4 + q;
                if (n < N) node[(size_t)n * 384 + col] = f2bf(acc[t][q] + bb);
            }
        }
    }

    // ---- G1: l1 = sum_c ((a1_c @ Wu1))^2 ----
    {
        bf16x8 bh[2][2], bl[2][2];
#pragma unroll
        for (int ks = 0; ks < 2; ks++)
#pragma unroll
            for (int t = 0; t < 2; t++) {
                size_t bi = ((size_t)((ks * 8 + w * 2 + t) * 64 + lane)) * 8;
                bh[ks][t] = *(const bf16x8*)&Wu1h[bi];
                bl[ks][t] = *(const bf16x8*)&Wu1l[bi];
            }
        f32x4 S[2];
        S[0] = (f32x4){0.f, 0.f, 0.f, 0.f};
        S[1] = (f32x4){0.f, 0.f, 0.f, 0.f};
#pragma unroll
        for (int c = 0; c < 3; c++) {
            f32x4 d[2];
            d[0] = (f32x4){0.f, 0.f, 0.f, 0.f};
            d[1] = (f32x4){0.f, 0.f, 0.f, 0.f};
            int abase = (1 + c) * (16 * 72);
#pragma unroll
            for (int ks = 0; ks < 2; ks++) {
                bf16x8 ah = *(const bf16x8*)&Ahi[abase + lcol * 72 + ks * 32 + kq];
                bf16x8 al = *(const bf16x8*)&Alo[abase + lcol * 72 + ks * 32 + kq];
#pragma unroll
                for (int t = 0; t < 2; t++) {
                    d[t] = __builtin_amdgcn_mfma_f32_16x16x32_bf16(ah, bh[ks][t], d[t], 0, 0, 0);
                    d[t] = __builtin_amdgcn_mfma_f32_16x16x32_bf16(ah, bl[ks][t], d[t], 0, 0, 0);
                    d[t] = __builtin_amdgcn_mfma_f32_16x16x32_bf16(al, bh[ks][t], d[t], 0, 0, 0);
                }
            }
            S[0] += d[0] * d[0];
            S[1] += d[1] * d[1];
        }
#pragma unroll
        for (int t = 0; t < 2; t++) {
            int col = w * 32 + t * 16 + lcol;
#pragma unroll
            for (int q = 0; q < 4; q++) {
                int n = n0 + quad * 4 + q;
                if (n < N) node[(size_t)n * 384 + 128 + col] = f2bf(S[t][q]);
            }
        }
    }

    // ---- G2: lh = sum_c ((ah_c @ Wuh))^2 ----
    {
        bf16x8 bh[2][2], bl[2][2];
#pragma unroll
        for (int ks = 0; ks < 2; ks++)
#pragma unroll
            for (int t = 0; t < 2; t++) {
                size_t bi = ((size_t)((ks * 8 + w * 2 + t) * 64 + lane)) * 8;
                bh[ks][t] = *(const bf16x8*)&Wuhh[bi];
                bl[ks][t] = *(const bf16x8*)&Wuhl[bi];
            }
        f32x4 S[2];
        S[0] = (f32x4){0.f, 0.f, 0.f, 0.f};
        S[1] = (f32x4){0.f, 0.f, 0.f, 0.f};
#pragma unroll
        for (int c = 0; c < 5; c++) {
            f32x4 d[2];
            d[0] = (f32x4){0.f, 0.f, 0.f, 0.f};
            d[1] = (f32x4){0.f, 0.f, 0.f, 0.f};
            int abase = (4 + c) * (16 * 72);
#pragma unroll
            for (int ks = 0; ks < 2; ks++) {
                bf16x8 ah = *(const bf16x8*)&Ahi[abase + lcol * 72 + ks * 32 + kq];
                bf16x8 al = *(const bf16x8*)&Alo[abase + lcol * 72 + ks * 32 + kq];
#pragma unroll
                for (int t = 0; t < 2; t++) {
                    d[t] = __builtin_amdgcn_mfma_f32_16x16x32_bf16(ah, bh[ks][t], d[t], 0, 0, 0);
                    d[t] = __builtin_amdgcn_mfma_f32_16x16x32_bf16(ah, bl[ks][t], d[t], 0, 0, 0);
                    d[t] = __builtin_amdgcn_mfma_f32_16x16x32_bf16(al, bh[ks][t], d[t], 0, 0, 0);
                }
            }
            S[0] += d[0] * d[0];
            S[1] += d[1] * d[1];
        }
#pragma unroll
        for (int t = 0; t < 2; t++) {
            int col = w * 32 + t * 16 + lcol;
#pragma unroll
            for (int q = 0; q < 4; q++) {
                int n = n0 + quad * 4 + q;
                if (n < N) node[(size_t)n * 384 + 256 + col] = f2bf(S[t][q]);
            }
        }
    }
}

// ---------------------------------------------------------------------------
// Stage C2: bf16 MFMA fused GEMM1+LN+SiLU+GEMM2 (proven R13).
// ---------------------------------------------------------------------------
__global__ __launch_bounds__(256, 4) void k_final(
    const unsigned short* __restrict__ node, const unsigned short* __restrict__ Bsw1,
    const float* __restrict__ bn1, const float* __restrict__ lng,
    const float* __restrict__ lnb, const unsigned short* __restrict__ Bsw2,
    const float* __restrict__ bn2, const float* __restrict__ x,
    float* __restrict__ out, int N)
{
    __shared__ __align__(16) unsigned short Abf[32 * 392];   // GEMM1 A [32][384+8]; reused as GEMM2 A [32][256+8]
    __shared__ float red[32][33];
    __shared__ float red2[32][33];
    __shared__ float mstat[32][2];

    int n0 = blockIdx.x * 32;
    int tid = threadIdx.x;
    int lane = tid & 63;
    int w = tid >> 6;
    int rt = w & 1;
    int cg = w >> 1;
    int lcol = lane & 15;
    int quad = lane >> 4;
    int arow = rt * 16 + lcol;       // A-frag row this lane reads
    int kq = quad * 8;               // A/B-frag k sub-offset

    // ---- stage bf16 node tile -> Abf[32][392] (48 uint4 per row) ----
    for (int i = tid; i < 32 * 48; i += 256) {
        int r = i / 48, c8 = i - r * 48;
        int n = n0 + r;
        uint4 v = {0u, 0u, 0u, 0u};
        if (n < N) v = *(const uint4*)&node[(size_t)n * 384 + c8 * 8];
        *(uint4*)&Abf[r * 392 + c8 * 8] = v;
    }
    __syncthreads();

    // ---- GEMM1: T = node @ Wn1 ----
    f32x4 acc[8];
#pragma unroll
    for (int t = 0; t < 8; t++) acc[t] = (f32x4){0.f, 0.f, 0.f, 0.f};
    for (int ks = 0; ks < 12; ks++) {
        bf16x8 a = *(const bf16x8*)&Abf[arow * 392 + ks * 32 + kq];
        const bf16x8* bp =
            (const bf16x8*)&Bsw1[(size_t)(((ks * 16 + cg * 8) * 64) + lane) * 8];
#pragma unroll
        for (int t = 0; t < 8; t++)
            acc[t] = __builtin_amdgcn_mfma_f32_16x16x32_bf16(a, bp[t * 64], acc[t], 0, 0, 0);
    }

    // ---- per-row LN partials from accumulators ----
    float bias[8];
#pragma unroll
    for (int t = 0; t < 8; t++) bias[t] = bn1[cg * 128 + t * 16 + lcol];
#pragma unroll
    for (int q = 0; q < 4; q++) {
        float s = 0.f, s2 = 0.f;
#pragma unroll
        for (int t = 0; t < 8; t++) {
            float v = acc[t][q] + bias[t];
            s += v; s2 += v * v;
        }
        int row = rt * 16 + quad * 4 + q;
        red[row][cg * 16 + lcol] = s;
        red2[row][cg * 16 + lcol] = s2;
    }
    __syncthreads();
    {
        // parallel stats: 8 threads/row, 4 partials each, shfl tree
        int row = tid >> 3, g = tid & 7;
        float s = 0.f, s2 = 0.f;
#pragma unroll
        for (int u = 0; u < 4; u++) {
            s  += red[row][g * 4 + u];
            s2 += red2[row][g * 4 + u];
        }
        s  += __shfl_down(s, 4);  s2 += __shfl_down(s2, 4);
        s  += __shfl_down(s, 2);  s2 += __shfl_down(s2, 2);
        s  += __shfl_down(s, 1);  s2 += __shfl_down(s2, 1);
        if (g == 0) {
            float mn = s * (1.f / 256.f);
            float var = s2 * (1.f / 256.f) - mn * mn;
            mstat[row][0] = mn;
            mstat[row][1] = rsqrtf(var + 1e-5f);
        }
    }
    __syncthreads();

    // ---- LN + SiLU, write h as bf16 GEMM2 A-tile [32][264] ----
#pragma unroll
    for (int t = 0; t < 8; t++) {
        int col = cg * 128 + t * 16 + lcol;
        float gg = lng[col], bb = lnb[col];
#pragma unroll
        for (int q = 0; q < 4; q++) {
            int row = rt * 16 + quad * 4 + q;
            float z = (acc[t][q] + bias[t] - mstat[row][0]) * mstat[row][1] * gg + bb;
            float h = z / (1.f + __expf(-z));
            Abf[row * 264 + col] = f2bf(h);
        }
    }
    __syncthreads();

    // ---- GEMM2: out = h @ Wn2 + bn2 + x ----
    f32x4 o[8];
#pragma unroll
    for (int t = 0; t < 8; t++) o[t] = (f32x4){0.f, 0.f, 0.f, 0.f};
    for (int ks = 0; ks < 8; ks++) {
        bf16x8 a = *(const bf16x8*)&Abf[arow * 264 + ks * 32 + kq];
        const bf16x8* bp =
            (const bf16x8*)&Bsw2[(size_t)(((ks * 16 + cg * 8) * 64) + lane) * 8];
#pragma unroll
        for (int t = 0; t < 8; t++)
            o[t] = __builtin_amdgcn_mfma_f32_16x16x32_bf16(a, bp[t * 64], o[t], 0, 0, 0);
    }
#pragma unroll
    for (int t = 0; t < 8; t++) {
        int col = cg * 128 + t * 16 + lcol;
        float ob = bn2[col];
#pragma unroll
        for (int q = 0; q < 4; q++) {
            int row = rt * 16 + quad * 4 + q;
            int n = n0 + row;
            if (n < N)
                out[(size_t)n * 256 + col] = o[t][q] + ob + x[(size_t)n * 256 + col];
        }
    }
}

// ---------------------------------------------------------------------------
extern "C" void kernel_launch(void* const* d_in, const int* in_sizes, int n_in,
                              void* d_out, int out_size, void* d_ws, size_t ws_size,
                              hipStream_t stream)
{
    const float* x      = (const float*)d_in[0];
    const float* rbf    = (const float*)d_in[1];
    const float* factor = (const float*)d_in[2];
    const float* sph0   = (const float*)d_in[3];
    const float* sph1   = (const float*)d_in[4];
    const float* Wd     = (const float*)d_in[5];
    const float* bd     = (const float*)d_in[6];
    const float* Wu0    = (const float*)d_in[7];
    const float* bu0    = (const float*)d_in[8];
    const float* Wu1    = (const float*)d_in[9];
    const float* Wuh    = (const float*)d_in[10];
    const float* Wn1    = (const float*)d_in[11];
    const float* bn1    = (const float*)d_in[12];
    const float* lng    = (const float*)d_in[13];
    const float* lnb    = (const float*)d_in[14];
    const float* Wn2    = (const float*)d_in[15];
    const float* bn2    = (const float*)d_in[16];
    const int*   jidx   = (const int*)d_in[17];
    const int*   iidx   = (const int*)d_in[18];
    float* out = (float*)d_out;

    int N = in_sizes[0] / 256;
    int E = in_sizes[17];
    int nblk = (N + 15) / 16;

    float* ws   = (float*)d_ws;
    unsigned short* xpB = (unsigned short*)ws;         // [N,64] bf16 (N*32 floats)
    float* aggF = ws + (size_t)N * 32;                 // A-tile region: nblk*9216 floats
    unsigned short* aggHi = (unsigned short*)aggF;     // [nblk*9216] bf16
    unsigned short* aggLo = aggHi + (size_t)nblk * 9216;
    float* nodeF = aggF + (size_t)nblk * 9216;         // node region (N*384 f32 worth)
    unsigned short* nodeB = (unsigned short*)nodeF;    // bf16 node [N,384]
    // swizzled bf16 weights after the node region
    unsigned short* Bsw1 = (unsigned short*)(nodeF + (size_t)N * 384); // 12*16*64*8
    unsigned short* Bsw2 = Bsw1 + 12 * 16 * 64 * 8;                    // 8*16*64*8
    unsigned short* Wu0h_s = Bsw2 + 8 * 16 * 64 * 8;
    unsigned short* Wu0l_s = Wu0h_s + 64 * 128;
    unsigned short* Wu1h_s = Wu0l_s + 64 * 128;
    unsigned short* Wu1l_s = Wu1h_s + 64 * 128;
    unsigned short* Wuhh_s = Wu1l_s + 64 * 128;
    unsigned short* Wuhl_s = Wuhh_s + 64 * 128;
    unsigned short* Wdh_s  = Wuhl_s + 64 * 128;
    unsigned short* Wdl_s  = Wdh_s + 256 * 64;

    // CSR scratch + packed edge records aliased onto the node region (dead
    // before k_node writes node; k_gather fully consumes packed first).
    int* counts  = (int*)nodeF;              // [N+1]
    int* rowptr  = counts + (N + 1);         // [N+1]
    int* cursor  = rowptr + (N + 1);         // [N]
    float* packed = nodeF + 131072;          // [E,12] CSR-ordered edge records

    int nDown = (N + 31) / 32;
    int nScat = (E + 255) / 256;

    k_prep<<<dim3(125), dim3(256), 0, stream>>>(
        Wn1, Bsw1, Wn2, Bsw2, Wu0, Wu0h_s, Wu0l_s, Wu1, Wu1h_s, Wu1l_s,
        Wuh, Wuhh_s, Wuhl_s, Wd, Wdh_s, Wdl_s, counts, N);
    k_hist<<<dim3(nScat), dim3(256), 0, stream>>>(iidx, counts, E);
    k_scan<<<dim3(1), dim3(1024), 0, stream>>>(counts, rowptr, cursor, N);
    k_down_scatter<<<dim3(nDown + nScat), dim3(256), 0, stream>>>(
        x, Wdh_s, Wdl_s, bd, xpB, iidx, jidx, factor, sph0, sph1,
        cursor, packed, N, E, nDown);
    k_gather<<<dim3((N + 3) / 4), dim3(256), 0, stream>>>(
        xpB, rbf, packed, rowptr, aggHi, aggLo, N);
    k_node<<<dim3(nblk), dim3(256), 0, stream>>>(
        aggHi, aggLo, Wu0h_s, Wu0l_s, Wu1h_s, Wu1l_s, Wuhh_s, Wuhl_s,
        bu0, nodeB, N);
    k_final<<<dim3((N + 31) / 32), dim3(256), 0, stream>>>(
        nodeB, Bsw1, bn1, lng, lnb, Bsw2, bn2, x, out, N);
}